// Round 12
// baseline (195.309 us; speedup 1.0000x reference)
//
#include <hip/hip_runtime.h>
#include <hip/hip_bf16.h>
#include <math.h>

typedef unsigned short u16;
typedef __attribute__((ext_vector_type(8))) short s16x8;
typedef __attribute__((ext_vector_type(4))) float f32x4;

#define BB 2
#define LL 2048
#define DMODEL 1024
#define DI 2048
#define NH 32
#define HD 64
#define DS 128
#define NR 32
#define CH 64
#define NC 32
#define DIP 2432
#define NTOK (BB*LL)
#define PAW 384   // projAux width: cols 2048..2431 of proj
#define CVW 264   // per-chunk factor-table stride (floats)

__device__ __forceinline__ float bf2f(u16 u){ union{unsigned i; float f;} c; c.i=((unsigned)u)<<16; return c.f; }
__device__ __forceinline__ u16 f2bf(float f){ __hip_bfloat16 h=__float2bfloat16(f); return *reinterpret_cast<u16*>(&h); }
__device__ __forceinline__ float softplusf(float x){ return fmaxf(x,0.f) + log1pf(expf(-fabsf(x))); }

__device__ __forceinline__ void gl_lds16(const void* g, void* l){
  __builtin_amdgcn_global_load_lds((const __attribute__((address_space(1))) void*)g,
                                   (__attribute__((address_space(3))) void*)l, 16, 0, 0);
}

// swizzled [*][128] bf16 row (256B): 16B unit u at slot u^(r&7)
__device__ __forceinline__ s16x8 ldswz(const u16* base, int r, int kunit){
  return *(const s16x8*)&base[r*128 + ((kunit ^ (r&7))<<3)];
}
// element offset within swizzled [*][128] row
__device__ __forceinline__ int swze(int row, int n){
  return row*128 + ((((n>>3) ^ (row&7))<<3) | (n&7));
}
// swizzled [*][64] bf16 row (128B): unit u (0..7) at slot u^(r&7)
__device__ __forceinline__ s16x8 ldswz64(const u16* base, int r, int kunit){
  return *(const s16x8*)&base[r*64 + ((kunit ^ (r&7))<<3)];
}
__device__ __forceinline__ float ldswz64_s(const u16* base, int r, int n){
  return bf2f(base[r*64 + (((n>>3) ^ (r&7))<<3) + (n&7)]);
}
// plain stride-72 bf16 rows (144B, 16B-aligned fragment reads)
__device__ __forceinline__ s16x8 ld72(const u16* base, int r, int kelem){
  return *(const s16x8*)&base[r*72 + kelem];
}

// ---------------- cast fp32 -> bf16 ----------------
__global__ __launch_bounds__(256) void k_cast(const float* __restrict__ in, u16* __restrict__ out, int n){
  int i = (blockIdx.x*256 + threadIdx.x)*4;
  if (i < n){
    float4 v = *(const float4*)&in[i];
    ushort4 o; o.x=f2bf(v.x); o.y=f2bf(v.y); o.z=f2bf(v.z); o.w=f2bf(v.w);
    *(ushort4*)&out[i] = o;
  }
}

// ---------------- in-proj GEMM, 8-wave (512t) 128x128 tile, split epilogue, XCD swizzle ----------------
__global__ __launch_bounds__(512) void k_gemm_in(const u16* __restrict__ A,
                                                 const u16* __restrict__ Bm,
                                                 float* __restrict__ pAux,
                                                 u16* __restrict__ Xtg){
  __shared__ u16 lA[128*64];
  __shared__ u16 lB[128*64];
  int tid = threadIdx.x;
  int l = tid & 63, w = tid >> 6;          // 8 waves
  int nwg = gridDim.x*gridDim.y;
  int flat = blockIdx.y*gridDim.x + blockIdx.x;
  int cpx = nwg >> 3;
  int swz = (flat & 7)*cpx + (flat >> 3);
  int bx = swz % gridDim.x, by = swz / gridDim.x;
  int bm = by*128, bn = bx*128;
  int wr = w >> 2, wc = w & 3;             // 2x4 wave grid: 64 rows x 32 cols per wave
  const f32x4 vzero = {0.f,0.f,0.f,0.f};
  f32x4 acc[4][2];
  #pragma unroll
  for (int i=0;i<4;i++)
    #pragma unroll
    for (int j=0;j<2;j++) acc[i][j] = vzero;

  for (int kt=0; kt<DMODEL; kt+=64){
    __syncthreads();
    #pragma unroll
    for (int cc=0; cc<2; cc++){
      int s = w*2 + cc;
      int uu = s*64 + l;
      int r = uu >> 3, jl = uu & 7;
      int j = jl ^ (r & 7);
      gl_lds16(A  + (size_t)(bm+r)*DMODEL + kt + j*8, &lA[s*512]);
      gl_lds16(Bm + (size_t)(bn+r)*DMODEL + kt + j*8, &lB[s*512]);
    }
    __syncthreads();
    #pragma unroll
    for (int ks=0; ks<2; ks++){
      s16x8 af[4], bf[2];
      #pragma unroll
      for (int i=0;i<4;i++){
        int row = wr*64 + i*16 + (l&15);
        int j = ks*4 + (l>>4);
        af[i] = *(const s16x8*)&lA[row*64 + (j^(row&7))*8];
      }
      #pragma unroll
      for (int i=0;i<2;i++){
        int row = wc*32 + i*16 + (l&15);
        int j = ks*4 + (l>>4);
        bf[i] = *(const s16x8*)&lB[row*64 + (j^(row&7))*8];
      }
      #pragma unroll
      for (int i=0;i<4;i++)
        #pragma unroll
        for (int jj=0;jj<2;jj++)
          acc[i][jj] = __builtin_amdgcn_mfma_f32_16x16x32_bf16(af[i], bf[jj], acc[i][jj], 0,0,0);
    }
  }
  int col0 = bn + wc*32 + (l&15);
  int row0 = bm + wr*64 + (l>>4)*4;
  if (bn < DI){
    int h = (bn + wc*32) >> 6;
    int pbase = (wc & 1)*32 + (l&15);
    int b = bm >> 11;
    #pragma unroll
    for (int i=0;i<4;i++){
      int lbase = (bm & (LL-1)) + wr*64 + (l>>4)*4 + i*16;
      #pragma unroll
      for (int jj=0;jj<2;jj++){
        int p = pbase + jj*16;
        ushort4 o;
        o.x = f2bf(acc[i][jj][0]); o.y = f2bf(acc[i][jj][1]);
        o.z = f2bf(acc[i][jj][2]); o.w = f2bf(acc[i][jj][3]);
        *(ushort4*)&Xtg[((size_t)(b*NH + h)*HD + p)*LL + lbase] = o;
      }
    }
  } else {
    #pragma unroll
    for (int i=0;i<4;i++)
      #pragma unroll
      for (int jj=0;jj<2;jj++)
        #pragma unroll
        for (int q=0;q<4;q++)
          pAux[(size_t)(row0 + i*16 + q)*PAW + col0 + jj*16 - DI] = acc[i][jj][q];
  }
}

// ---------------- per-token prep (2 rows/block) ----------------
__global__ __launch_bounds__(256) void k_prep(const float* __restrict__ pAux,
                                              const float* __restrict__ dt_bias,
                                              const float* __restrict__ Bnw,
                                              const float* __restrict__ Cnw,
                                              float* __restrict__ Bnr, float* __restrict__ Cnr,
                                              float* __restrict__ DTg, float* __restrict__ lag,
                                              float* __restrict__ w1g, float* __restrict__ w2g){
  int tid = threadIdx.x;
  int r = tid >> 7, t = tid & 127;
  int row = blockIdx.x*2 + r;
  const float* pr = pAux + (size_t)row*PAW;
  float bv = pr[t], cv = pr[128+t];
  float sb = bv*bv, sc = cv*cv;
  for (int o=32;o;o>>=1){ sb += __shfl_down(sb,o); sc += __shfl_down(sc,o); }
  __shared__ float red[8];
  if ((tid&63)==0){ red[(tid>>6)*2]=sb; red[(tid>>6)*2+1]=sc; }
  __syncthreads();
  float ssb = red[r*4]+red[r*4+2], ssc = red[r*4+1]+red[r*4+3];
  float rb = rsqrtf(ssb/DS + 1e-5f), rc = rsqrtf(ssc/DS + 1e-5f);
  Bnr[(size_t)row*DS+t] = bv*rb*Bnw[t];
  Cnr[(size_t)row*DS+t] = cv*rc*Cnw[t];
  if (t < NH){
    int h = t;
    float Av = -softplusf(pr[288+h]); Av = fminf(Av, -1e-4f);
    float DT = softplusf(pr[256+h] + dt_bias[h]);
    float la = Av*DT;
    float lam = 1.f/(1.f+expf(-pr[320+h]));
    DTg[row*NH+h] = DT;
    lag[row*NH+h] = la;
    w1g[row*NH+h] = DT*lam;
    w2g[row*NH+h] = DT*(1.f-lam)*expf(la);
  }
}

// ---------------- Theta cumsum, 3-phase (64-thread blocks) ----------------
__global__ __launch_bounds__(64) void k_theta_part(const float* __restrict__ pAux, const float* __restrict__ DTg,
                                                   float* __restrict__ Spart){
  int blk = blockIdx.x*2 + (threadIdx.x>>5);
  int j = threadIdx.x & 31;
  int h = blk % NH; int z = (blk/NH)%NC; int b = blk/(NH*NC);
  float acc = 0.f;
  for (int i=0;i<CH;i++){
    int row = b*LL + z*CH + i;
    acc += DTg[row*NH+h] * pAux[(size_t)row*PAW + 352 + j];
  }
  Spart[(size_t)blk*NR + j] = acc;
}

__global__ void k_theta_scan(float* __restrict__ Spart){
  int idx = blockIdx.x*blockDim.x + threadIdx.x;
  int j = idx % NR; int h = (idx/NR)%NH; int b = idx/(NR*NH);
  float acc = 0.f;
  for (int z=0;z<NC;z++){
    size_t o = (size_t)((b*NC+z)*NH + h)*NR + j;
    float t = Spart[o]; Spart[o] = acc; acc += t;
  }
}

__global__ __launch_bounds__(64) void k_theta_full(const float* __restrict__ pAux, const float* __restrict__ DTg,
                                                   const float* __restrict__ Spart, float* __restrict__ Theta){
  int blk = blockIdx.x*2 + (threadIdx.x>>5);
  int j = threadIdx.x & 31;
  int h = blk % NH; int z = (blk/NH)%NC; int b = blk/(NH*NC);
  float acc = Spart[(size_t)blk*NR + j];
  for (int i=0;i<CH;i++){
    int row = b*LL + z*CH + i;
    acc += DTg[row*NH+h] * pAux[(size_t)row*PAW + 352 + j];
    Theta[((size_t)row*NH + h)*NR + j] = acc;
  }
}

// ---------------- k_acum: per-chunk scan factors ----------------
__global__ __launch_bounds__(256) void k_acum(const float* __restrict__ lag,
                                              const float* __restrict__ w1g,
                                              const float* __restrict__ w2g,
                                              float* __restrict__ CV,
                                              float* __restrict__ Acumg,
                                              float* __restrict__ cdg){
  int blk = blockIdx.x*4 + (threadIdx.x>>6);
  int l = threadIdx.x & 63;
  int h = blk & 31, z = (blk>>5)&31, b = blk>>10;
  int row = b*LL + z*CH + l;
  float la = lag[row*NH+h], w1 = w1g[row*NH+h], w2 = w2g[row*NH+h];
  float a = la;
  #pragma unroll
  for (int o=1;o<64;o<<=1){ float t = __shfl_up(a,o); a += (l>=o) ? t : 0.f; }
  float Acm = __shfl(a, 31);
  float Alast = __shfl(a, 63);
  float eA = expf(a - Acm);
  float emA = expf(Acm - a);
  float rfac = expf(Alast - a);
  float rw1 = rfac*w1, rw2 = rfac*w2;
  float rw1p = __shfl_up(rw1, 1);
  float* cv = CV + (size_t)blk*CVW;
  cv[l] = eA;
  cv[64 + l] = emA*w1;          // G1[sp=l+1]
  cv[128 + l] = emA*w2;         // G2[sp=l]
  cv[192 + l] = (l>0 ? rw1p : 0.f) + rw2;   // vw[l]
  if (l == 63){ cv[192+64] = rw1; cdg[blk] = expf(Alast); }
  Acumg[(size_t)blk*CH + l] = a;
}

// ---------------- k_ropeC: C-side rope only -> Cn (no LDS, no barriers) ----------------
__global__ __launch_bounds__(256) void k_ropeC(const float* __restrict__ Cnr,
                                               const float* __restrict__ Theta,
                                               const float* __restrict__ C_bias,
                                               u16* __restrict__ Cn){
  int blk = blockIdx.x; int h = blk&31, z=(blk>>5)&31, b=blk>>10;
  int l0 = z*CH; int tid = threadIdx.x;
  const float* cb = C_bias + h*DS;
  #pragma unroll
  for (int it=0; it<8; it++){
    int idx = it*256 + tid;
    int r = idx>>5, j = idx&31;
    int row = b*LL + l0 + r;
    const float* cr = Cnr + (size_t)row*DS;
    float th = Theta[((size_t)row*NH + h)*NR + j];
    float cs = cosf(th), sn = sinf(th);
    float c0 = cr[j]    + cb[j];
    float c1 = cr[j+32] + cb[j+32];
    float c2 = cr[j+64] + cb[j+64];
    float c3 = cr[j+96] + cb[j+96];
    float ocA = c0*cs - c1*sn, ocB = c0*sn + c1*cs;
    u16* cnp = Cn + ((size_t)row*NH + h)*DS;
    cnp[j]    = f2bf(ocA); cnp[j+32] = f2bf(ocB);
    cnp[j+64] = f2bf(c2);  cnp[j+96] = f2bf(c3);
  }
}

// ---------------- k_chunk_a (fused B-rope): rope-B -> CB -> Mc -> Yintra, U ----------------
__global__ __launch_bounds__(256) void k_chunk_a(
    const u16* __restrict__ Xtg, const float* __restrict__ Bnr,
    const u16* __restrict__ Cn, const float* __restrict__ Theta,
    const float* __restrict__ B_bias,
    const float* __restrict__ CV, const float* __restrict__ Dgl,
    u16* __restrict__ Yb, u16* __restrict__ Ugb){
  __shared__ u16 Bs[65*128];       // shifted B rows 0..64, swizzled (rope-computed)
  __shared__ u16 CsMc[64*128];     // Cs swizzled (gl_lds) -> Mc[64][72] overlay
  __shared__ u16 Bt[128*72];       // (B*vw)^T [n][k], k=0..63, ld72 rows
  __shared__ u16 Xt64[64*64];      // X^T [p][k]
  __shared__ u16 Bp[128], Xp[64];
  __shared__ float cvS[260];
  __shared__ float mc0s[64];
  int blk = blockIdx.x;
  int h = blk&31, z=(blk>>5)&31, b=blk>>10;
  int l0 = z*CH;
  int tid = threadIdx.x; int l = tid&63, w = tid>>6;
  size_t bh = (size_t)(b*NH + h);

  // ---- phase A: cv loads + gl_lds staging (Cs, Xt64) + Xp ----
  cvS[tid] = CV[(size_t)blk*CVW + tid];
  if (tid == 0) cvS[256] = CV[(size_t)blk*CVW + 256];
  if (tid >= 128 && tid < 192){
    int p = tid - 128;
    u16 v = 0;
    if (z > 0) v = Xtg[(bh*HD + p)*LL + l0 - 1];
    Xp[p] = v;
  }
  #pragma unroll
  for (int cc=0; cc<4; cc++){
    int c = w*4 + cc;
    int r = 4*c + (l>>4);
    gl_lds16(Cn + ((size_t)(b*LL+l0+r)*NH+h)*DS + (((l&15)^(r&7))<<3), &CsMc[4*c*128]);
  }
  #pragma unroll
  for (int cc=0; cc<2; cc++){
    int s = w*2 + cc;
    int uu = s*64 + l; int r = uu>>3, jl = uu&7, j = jl^(r&7);
    gl_lds16(Xtg + (bh*HD + r)*LL + l0 + j*8, &Xt64[s*512]);
  }
  __syncthreads();   // cvS (and Xp) visible

  // ---- phase B: rope-compute B-side -> Bs rows 1..64 + Bt; row 0 + Bp ----
  {
    const float* bb = B_bias + h*DS;
    #pragma unroll
    for (int it=0; it<8; it++){
      int idx = it*256 + tid;
      int r = idx>>5, j = idx&31;
      int row = b*LL + l0 + r;
      const float* br = Bnr + (size_t)row*DS;
      float th = Theta[((size_t)row*NH + h)*NR + j];
      float cs = cosf(th), sn = sinf(th);
      float b0 = br[j]    + bb[j];
      float b1 = br[j+32] + bb[j+32];
      float b2 = br[j+64] + bb[j+64];
      float b3 = br[j+96] + bb[j+96];
      float obA = b0*cs - b1*sn, obB = b0*sn + b1*cs;
      int rr = r + 1;
      Bs[swze(rr, j)]    = f2bf(obA);
      Bs[swze(rr, j+32)] = f2bf(obB);
      Bs[swze(rr, j+64)] = f2bf(b2);
      Bs[swze(rr, j+96)] = f2bf(b3);
      float vwr = cvS[192 + rr];
      Bt[j*72 + r]      = f2bf(obA*vwr);
      Bt[(j+32)*72 + r] = f2bf(obB*vwr);
      Bt[(j+64)*72 + r] = f2bf(b2*vwr);
      Bt[(j+96)*72 + r] = f2bf(b3*vwr);
    }
    if (tid < 32){
      int j = tid;
      float obA=0.f, obB=0.f, b2=0.f, b3=0.f;
      if (z > 0){
        int row = b*LL + l0 - 1;
        const float* br = Bnr + (size_t)row*DS;
        float th = Theta[((size_t)row*NH + h)*NR + j];
        float cs = cosf(th), sn = sinf(th);
        float b0 = br[j]    + bb[j];
        float b1 = br[j+32] + bb[j+32];
        b2 = br[j+64] + bb[j+64];
        b3 = br[j+96] + bb[j+96];
        obA = b0*cs - b1*sn; obB = b0*sn + b1*cs;
      }
      // row 0 swizzle is identity
      Bs[j]    = f2bf(obA); Bs[j+32] = f2bf(obB);
      Bs[j+64] = f2bf(b2);  Bs[j+96] = f2bf(b3);
      Bp[j]    = f2bf(obA); Bp[j+32] = f2bf(obB);
      Bp[j+64] = f2bf(b2);  Bp[j+96] = f2bf(b3);
    }
  }
  __syncthreads();   // Bs/Bt/Bp written; gl_lds (Cs, Xt64) drained

  // ---- phase 1: CB GEMM over Bs rows 1..64; mc0 matvec (Cs x Bs row0) ----
  const f32x4 vzero = {0.f,0.f,0.f,0.f};
  f32x4 acb[4];
  #pragma unroll
  for (int j=0;j<4;j++) acb[j] = vzero;
  #pragma unroll
  for (int ks=0; ks<4; ks++){
    s16x8 af = ldswz(CsMc, 16*w + (l&15), ks*4 + (l>>4));
    #pragma unroll
    for (int j=0;j<4;j++){
      s16x8 bfr = ldswz(Bs, 1 + 16*j + (l&15), ks*4 + (l>>4));
      acb[j] = __builtin_amdgcn_mfma_f32_16x16x32_bf16(af, bfr, acb[j], 0,0,0);
    }
  }
  {
    int t = tid>>2, part = tid&3;
    float s = 0.f;
    #pragma unroll
    for (int uu=0; uu<4; uu++){
      int u = part*4 + uu;
      s16x8 cr = *(const s16x8*)&CsMc[t*128 + ((u^(t&7))<<3)];
      s16x8 br = *(const s16x8*)&Bs[u<<3];   // row 0, identity swizzle
      #pragma unroll
      for (int e=0;e<8;e++) s += bf2f(cr[e])*bf2f(br[e]);
    }
    s += __shfl_xor(s, 1); s += __shfl_xor(s, 2);
    if (part == 0) mc0s[t] = s * cvS[t] * cvS[128];   // CB[t][0]*eA[t]*G2[0]
  }
  __syncthreads();

  // ---- phase 2: build Mc' (overlays Cs) ----
  #pragma unroll
  for (int j=0;j<4;j++){
    #pragma unroll
    for (int q=0;q<4;q++){
      int t = 16*w + (l>>4)*4 + q;
      int k = 16*j + (l&15);
      int sp = k + 1;
      float g = 0.f;
      if (sp <= t+1) g += cvS[63+sp];
      if (sp <= t)   g += cvS[128+sp];
      g *= cvS[t];
      CsMc[t*72 + k] = f2bf(acb[j][q] * g);
    }
  }
  __syncthreads();

  // ---- phase 3: Yintra = Mc' @ Xt64^T + mc0 x Xp + D*x; write Yb ----
  f32x4 ay[4];
  #pragma unroll
  for (int j=0;j<4;j++) ay[j] = vzero;
  #pragma unroll
  for (int ks=0; ks<2; ks++){
    s16x8 af = ld72(CsMc, 16*w + (l&15), ks*32 + (l>>4)*8);
    #pragma unroll
    for (int j=0;j<4;j++){
      s16x8 bfr = ldswz64(Xt64, 16*j + (l&15), ks*4 + (l>>4));
      ay[j] = __builtin_amdgcn_mfma_f32_16x16x32_bf16(af, bfr, ay[j], 0,0,0);
    }
  }
  {
    float Dh = Dgl[h];
    #pragma unroll
    for (int j=0;j<4;j++){
      #pragma unroll
      for (int q=0;q<4;q++){
        int t = 16*w + (l>>4)*4 + q;
        int p = 16*j + (l&15);
        float xval = ldswz64_s(Xt64, p, t);
        float yv = ay[j][q] + mc0s[t]*bf2f(Xp[p]) + Dh*xval;
        Yb[((size_t)(b*LL + l0 + t))*DI + h*HD + p] = f2bf(yv);
      }
    }
  }

  // ---- phase 4: U = Xt64 @ Bt^T (+ rank-1 sp=0 fixup); write Ugb bf16 ----
  f32x4 au[8];
  #pragma unroll
  for (int j=0;j<8;j++) au[j] = vzero;
  #pragma unroll
  for (int ks=0; ks<2; ks++){
    s16x8 af = ldswz64(Xt64, 16*w + (l&15), ks*4 + (l>>4));
    #pragma unroll
    for (int j=0;j<8;j++){
      s16x8 bfr = ld72(Bt, 16*j + (l&15), ks*32 + (l>>4)*8);
      au[j] = __builtin_amdgcn_mfma_f32_16x16x32_bf16(af, bfr, au[j], 0,0,0);
    }
  }
  {
    float vw0 = cvS[192];
    #pragma unroll
    for (int j=0;j<8;j++){
      #pragma unroll
      for (int q=0;q<4;q++){
        int p = 16*w + (l>>4)*4 + q;
        int n = 16*j + (l&15);
        float uv = au[j][q] + vw0*bf2f(Xp[p])*bf2f(Bp[n]);
        Ugb[(size_t)blk*(HD*DS) + p*DS + n] = f2bf(uv);
      }
    }
  }
}

// ---------------- inter-chunk state scan (bf16 in-place, vectorized) ----------------
__global__ __launch_bounds__(256) void k_scan(u16* __restrict__ Ugb, const float* __restrict__ cdg){
  int idx = blockIdx.x*256 + threadIdx.x;     // 65536 threads
  int pn8 = (idx & 1023)*8;
  int h  = (idx >> 10) & 31;
  int b  = idx >> 15;
  float hs[8];
  #pragma unroll
  for (int e=0;e<8;e++) hs[e] = 0.f;
  for (int z=0;z<NC;z++){
    size_t o = ((size_t)((b*NC+z)*NH) + h)*(HD*DS) + pn8;
    s16x8 v = *(s16x8*)&Ugb[o];
    float cd = cdg[(b*NC+z)*NH + h];
    s16x8 wv;
    #pragma unroll
    for (int e=0;e<8;e++){
      float tmp = bf2f((u16)v[e]);
      wv[e] = (short)f2bf(hs[e]);
      hs[e] = cd*hs[e] + tmp;
    }
    *(s16x8*)&Ugb[o] = wv;
  }
}

// ---------------- k_state: Ystate MFMA + Y RMW ----------------
__global__ __launch_bounds__(256) void k_state(
    const u16* __restrict__ Cn, const u16* __restrict__ Ugb,
    const float* __restrict__ Acumg, u16* __restrict__ Yb){
  __shared__ u16 Cs[64*128];
  __shared__ u16 Sb[64*128];
  __shared__ float eAs[64];
  int blk = blockIdx.x;
  int h = blk & 31, z = (blk>>5)&31, b = blk>>10;
  int l0 = z*CH;
  int tid = threadIdx.x;
  int l = tid & 63, w = tid >> 6;

  if (tid < 64) eAs[tid] = expf(Acumg[(size_t)blk*CH + tid]);
  #pragma unroll
  for (int cc=0; cc<4; cc++){
    int c = w*4 + cc;
    int r = 4*c + (l>>4);
    gl_lds16(Cn + ((size_t)(b*LL + l0 + r)*NH + h)*DS + (((l&15)^(r&7))<<3), &Cs[4*c*128]);
    gl_lds16(Ugb + (size_t)blk*(HD*DS) + (size_t)r*DS + (((l&15)^(r&7))<<3), &Sb[4*c*128]);
  }
  __syncthreads();

  f32x4 as[4];
  const f32x4 vzero = {0.f,0.f,0.f,0.f};
  #pragma unroll
  for (int j=0;j<4;j++) as[j] = vzero;
  #pragma unroll
  for (int ks=0; ks<4; ks++){
    s16x8 af = ldswz(Cs, 16*w + (l&15), ks*4 + (l>>4));
    #pragma unroll
    for (int j=0;j<4;j++){
      s16x8 bfr = ldswz(Sb, 16*j + (l&15), ks*4 + (l>>4));
      as[j] = __builtin_amdgcn_mfma_f32_16x16x32_bf16(af, bfr, as[j], 0,0,0);
    }
  }
  #pragma unroll
  for (int j=0;j<4;j++){
    #pragma unroll
    for (int q=0;q<4;q++){
      int t = 16*w + (l>>4)*4 + q;
      int p = 16*j + (l&15);
      size_t idx = ((size_t)(b*LL + l0 + t))*DI + h*HD + p;
      Yb[idx] = f2bf(bf2f(Yb[idx]) + eAs[t]*as[j][q]);
    }
  }
}

// ---------------- generic MFMA NT GEMM, 8-wave (512t), XCD swizzle (out-proj) ----------------
template<int N, int K>
__global__ __launch_bounds__(512) void k_mfma_nt(const u16* __restrict__ A,
                                                 const u16* __restrict__ Bm,
                                                 float* __restrict__ C){
  __shared__ u16 lA[128*64];
  __shared__ u16 lB[128*64];
  int tid = threadIdx.x;
  int l = tid & 63, w = tid >> 6;
  int nwg = gridDim.x*gridDim.y;
  int flat = blockIdx.y*gridDim.x + blockIdx.x;
  int cpx = nwg >> 3;
  int swz = (flat & 7)*cpx + (flat >> 3);
  int bx = swz % gridDim.x, by = swz / gridDim.x;
  int bm = by*128, bn = bx*128;
  int wr = w >> 2, wc = w & 3;
  const f32x4 vzero = {0.f,0.f,0.f,0.f};
  f32x4 acc[4][2];
  #pragma unroll
  for (int i=0;i<4;i++)
    #pragma unroll
    for (int j=0;j<2;j++) acc[i][j] = vzero;

  for (int kt=0; kt<K; kt+=64){
    __syncthreads();
    #pragma unroll
    for (int cc=0; cc<2; cc++){
      int s = w*2 + cc;
      int uu = s*64 + l;
      int r = uu >> 3, jl = uu & 7;
      int j = jl ^ (r & 7);
      gl_lds16(A  + (size_t)(bm+r)*K + kt + j*8, &lA[s*512]);
      gl_lds16(Bm + (size_t)(bn+r)*K + kt + j*8, &lB[s*512]);
    }
    __syncthreads();
    #pragma unroll
    for (int ks=0; ks<2; ks++){
      s16x8 af[4], bf[2];
      #pragma unroll
      for (int i=0;i<4;i++){
        int row = wr*64 + i*16 + (l&15);
        int j = ks*4 + (l>>4);
        af[i] = *(const s16x8*)&lA[row*64 + (j^(row&7))*8];
      }
      #pragma unroll
      for (int i=0;i<2;i++){
        int row = wc*32 + i*16 + (l&15);
        int j = ks*4 + (l>>4);
        bf[i] = *(const s16x8*)&lB[row*64 + (j^(row&7))*8];
      }
      #pragma unroll
      for (int i=0;i<4;i++)
        #pragma unroll
        for (int jj=0;jj<2;jj++)
          acc[i][jj] = __builtin_amdgcn_mfma_f32_16x16x32_bf16(af[i], bf[jj], acc[i][jj], 0,0,0);
    }
  }
  int col0 = bn + wc*32 + (l&15);
  int row0 = bm + wr*64 + (l>>4)*4;
  #pragma unroll
  for (int i=0;i<4;i++)
    #pragma unroll
    for (int jj=0;jj<2;jj++)
      #pragma unroll
      for (int q=0;q<4;q++)
        C[(size_t)(row0 + i*16 + q)*N + col0 + jj*16] = acc[i][jj][q];
}

// ---------------- workspace layout (bytes) ----------------
constexpr size_t OFF_PAUX  = 0;            // 6,291,456 ; later overlaid by Wout_bf
constexpr size_t OFF_XTG   = 6291456;      // 16,777,216
constexpr size_t OFF_BNR   = 23068672;     // 2,097,152
constexpr size_t OFF_CNR   = 25165824;     // 2,097,152
constexpr size_t OFF_DT    = 27262976;     // 524,288
constexpr size_t OFF_LA    = 27787264;     // 524,288
constexpr size_t OFF_W1    = 28311552;     // 524,288
constexpr size_t OFF_W2    = 28835840;     // 524,288
constexpr size_t OFF_SPART = 29360128;     // 262,144
constexpr size_t OFF_CV    = 29622272;     // 2,162,688
constexpr size_t OFF_ACUM  = 31784960;     // 524,288
constexpr size_t OFF_CD    = 32309248;     // 8,192
constexpr size_t OFF_THETA = 32317440;     // 16,777,216 (no longer overlaid — chunk_a reads Theta while writing Yb)
constexpr size_t OFF_Y     = 49094656;     // 16,777,216 (ex-Bn region; Bn deleted)
constexpr size_t OFF_CN    = 82649088;     // 33,554,432
constexpr size_t OFF_R1    = 149757952;    // u_bf+Win_bf -> Ugb(33.55M)
constexpr size_t OFF_UBF   = OFF_R1;
constexpr size_t OFF_WINBF = OFF_R1 + 16777216;
constexpr size_t OFF_UGB   = OFF_R1;
constexpr size_t OFF_WOUTBF= OFF_PAUX;
// total = 183,312,384 bytes (unchanged)

extern "C" void kernel_launch(void* const* d_in, const int* in_sizes, int n_in,
                              void* d_out, int out_size, void* d_ws, size_t ws_size,
                              hipStream_t stream) {
  const float* u       = (const float*)d_in[0];
  const float* W_in    = (const float*)d_in[1];
  const float* dt_bias = (const float*)d_in[2];
  const float* B_bias  = (const float*)d_in[3];
  const float* C_bias  = (const float*)d_in[4];
  const float* Bnw     = (const float*)d_in[5];
  const float* Cnw     = (const float*)d_in[6];
  const float* Dg      = (const float*)d_in[7];
  const float* W_out   = (const float*)d_in[8];
  float* out = (float*)d_out;
  char* ws = (char*)d_ws;

  float* pAux  = (float*)(ws + OFF_PAUX);
  u16*   Xtg   = (u16*)  (ws + OFF_XTG);
  float* Bnr   = (float*)(ws + OFF_BNR);
  float* Cnr   = (float*)(ws + OFF_CNR);
  float* DTg   = (float*)(ws + OFF_DT);
  float* lag   = (float*)(ws + OFF_LA);
  float* w1g   = (float*)(ws + OFF_W1);
  float* w2g   = (float*)(ws + OFF_W2);
  float* Spart = (float*)(ws + OFF_SPART);
  float* CVp   = (float*)(ws + OFF_CV);
  float* Acumg = (float*)(ws + OFF_ACUM);
  float* cdg   = (float*)(ws + OFF_CD);
  float* Theta = (float*)(ws + OFF_THETA);
  u16*   Yb    = (u16*)  (ws + OFF_Y);
  u16*   Cn    = (u16*)  (ws + OFF_CN);
  u16*   u_bf  = (u16*)  (ws + OFF_UBF);
  u16*   Win_bf= (u16*)  (ws + OFF_WINBF);
  u16*   Ugb   = (u16*)  (ws + OFF_UGB);
  u16*   Wout_bf=(u16*)  (ws + OFF_WOUTBF);

  k_cast<<<(NTOK*DMODEL)/1024, 256, 0, stream>>>(u, u_bf, NTOK*DMODEL);
  k_cast<<<(DIP*DMODEL)/1024, 256, 0, stream>>>(W_in, Win_bf, DIP*DMODEL);
  k_gemm_in<<<dim3(DIP/128, NTOK/128), 512, 0, stream>>>(u_bf, Win_bf, pAux, Xtg);

  k_prep      <<<NTOK/2, 256, 0, stream>>>(pAux, dt_bias, Bnw, Cnw, Bnr, Cnr, DTg, lag, w1g, w2g);
  k_theta_part<<<(BB*NC*NH)/2, 64, 0, stream>>>(pAux, DTg, Spart);
  k_theta_scan<<<(BB*NH*NR)/256, 256, 0, stream>>>(Spart);
  k_theta_full<<<(BB*NC*NH)/2, 64, 0, stream>>>(pAux, DTg, Spart, Theta);
  k_acum      <<<(BB*NC*NH)/4, 256, 0, stream>>>(lag, w1g, w2g, CVp, Acumg, cdg);
  k_ropeC     <<<BB*NC*NH, 256, 0, stream>>>(Cnr, Theta, C_bias, Cn);

  k_chunk_a<<<BB*NC*NH, 256, 0, stream>>>(Xtg, Bnr, Cn, Theta, B_bias, CVp, Dg, Yb, Ugb);
  k_scan   <<<(BB*NH*HD*DS)/(256*8), 256, 0, stream>>>(Ugb, cdg);
  k_state  <<<BB*NC*NH, 256, 0, stream>>>(Cn, Ugb, Acumg, Yb);

  k_cast<<<(DMODEL*DI)/1024, 256, 0, stream>>>(W_out, Wout_bf, DMODEL*DI);
  k_mfma_nt<DMODEL, DI><<<dim3(DMODEL/128, NTOK/128), 512, 0, stream>>>(Yb, Wout_bf, out);

  (void)in_sizes; (void)n_in; (void)out_size; (void)ws_size;
}

// Round 13
// 190.837 us; speedup vs baseline: 1.0234x; 1.0234x over previous
//
#include <hip/hip_runtime.h>
#include <hip/hip_bf16.h>
#include <math.h>

typedef unsigned short u16;
typedef __attribute__((ext_vector_type(8))) short s16x8;
typedef __attribute__((ext_vector_type(4))) float f32x4;

#define BB 2
#define LL 2048
#define DMODEL 1024
#define DI 2048
#define NH 32
#define HD 64
#define DS 128
#define NR 32
#define CH 64
#define NC 32
#define DIP 2432
#define NTOK (BB*LL)
#define PAW 384   // projAux width: cols 2048..2431 of proj
#define CVW 264   // per-chunk factor-table stride (floats)

__device__ __forceinline__ float bf2f(u16 u){ union{unsigned i; float f;} c; c.i=((unsigned)u)<<16; return c.f; }
__device__ __forceinline__ u16 f2bf(float f){ __hip_bfloat16 h=__float2bfloat16(f); return *reinterpret_cast<u16*>(&h); }
__device__ __forceinline__ float softplusf(float x){ return fmaxf(x,0.f) + log1pf(expf(-fabsf(x))); }

__device__ __forceinline__ void gl_lds16(const void* g, void* l){
  __builtin_amdgcn_global_load_lds((const __attribute__((address_space(1))) void*)g,
                                   (__attribute__((address_space(3))) void*)l, 16, 0, 0);
}

// swizzled [*][128] bf16 row (256B): 16B unit u at slot u^(r&7)
__device__ __forceinline__ s16x8 ldswz(const u16* base, int r, int kunit){
  return *(const s16x8*)&base[r*128 + ((kunit ^ (r&7))<<3)];
}
// swizzled [*][64] bf16 row (128B): unit u (0..7) at slot u^(r&7)
__device__ __forceinline__ s16x8 ldswz64(const u16* base, int r, int kunit){
  return *(const s16x8*)&base[r*64 + ((kunit ^ (r&7))<<3)];
}
__device__ __forceinline__ float ldswz64_s(const u16* base, int r, int n){
  return bf2f(base[r*64 + (((n>>3) ^ (r&7))<<3) + (n&7)]);
}
// plain stride-72 bf16 rows
__device__ __forceinline__ s16x8 ld72(const u16* base, int r, int kelem){
  return *(const s16x8*)&base[r*72 + kelem];
}

// ---------------- cast fp32 -> bf16 ----------------
__global__ __launch_bounds__(256) void k_cast(const float* __restrict__ in, u16* __restrict__ out, int n){
  int i = (blockIdx.x*256 + threadIdx.x)*4;
  if (i < n){
    float4 v = *(const float4*)&in[i];
    ushort4 o; o.x=f2bf(v.x); o.y=f2bf(v.y); o.z=f2bf(v.z); o.w=f2bf(v.w);
    *(ushort4*)&out[i] = o;
  }
}

// ---------------- in-proj GEMM, 8-wave (512t) 128x128 tile, split epilogue, XCD swizzle ----------------
__global__ __launch_bounds__(512) void k_gemm_in(const u16* __restrict__ A,
                                                 const u16* __restrict__ Bm,
                                                 float* __restrict__ pAux,
                                                 u16* __restrict__ Xtg){
  __shared__ u16 lA[128*64];
  __shared__ u16 lB[128*64];
  int tid = threadIdx.x;
  int l = tid & 63, w = tid >> 6;          // 8 waves
  int nwg = gridDim.x*gridDim.y;
  int flat = blockIdx.y*gridDim.x + blockIdx.x;
  int cpx = nwg >> 3;
  int swz = (flat & 7)*cpx + (flat >> 3);
  int bx = swz % gridDim.x, by = swz / gridDim.x;
  int bm = by*128, bn = bx*128;
  int wr = w >> 2, wc = w & 3;             // 2x4 wave grid: 64 rows x 32 cols per wave
  const f32x4 vzero = {0.f,0.f,0.f,0.f};
  f32x4 acc[4][2];
  #pragma unroll
  for (int i=0;i<4;i++)
    #pragma unroll
    for (int j=0;j<2;j++) acc[i][j] = vzero;

  for (int kt=0; kt<DMODEL; kt+=64){
    __syncthreads();
    #pragma unroll
    for (int cc=0; cc<2; cc++){
      int s = w*2 + cc;
      int uu = s*64 + l;
      int r = uu >> 3, jl = uu & 7;
      int j = jl ^ (r & 7);
      gl_lds16(A  + (size_t)(bm+r)*DMODEL + kt + j*8, &lA[s*512]);
      gl_lds16(Bm + (size_t)(bn+r)*DMODEL + kt + j*8, &lB[s*512]);
    }
    __syncthreads();
    #pragma unroll
    for (int ks=0; ks<2; ks++){
      s16x8 af[4], bf[2];
      #pragma unroll
      for (int i=0;i<4;i++){
        int row = wr*64 + i*16 + (l&15);
        int j = ks*4 + (l>>4);
        af[i] = *(const s16x8*)&lA[row*64 + (j^(row&7))*8];
      }
      #pragma unroll
      for (int i=0;i<2;i++){
        int row = wc*32 + i*16 + (l&15);
        int j = ks*4 + (l>>4);
        bf[i] = *(const s16x8*)&lB[row*64 + (j^(row&7))*8];
      }
      #pragma unroll
      for (int i=0;i<4;i++)
        #pragma unroll
        for (int jj=0;jj<2;jj++)
          acc[i][jj] = __builtin_amdgcn_mfma_f32_16x16x32_bf16(af[i], bf[jj], acc[i][jj], 0,0,0);
    }
  }
  int col0 = bn + wc*32 + (l&15);
  int row0 = bm + wr*64 + (l>>4)*4;
  if (bn < DI){
    int h = (bn + wc*32) >> 6;
    int pbase = (wc & 1)*32 + (l&15);
    int b = bm >> 11;
    #pragma unroll
    for (int i=0;i<4;i++){
      int lbase = (bm & (LL-1)) + wr*64 + (l>>4)*4 + i*16;
      #pragma unroll
      for (int jj=0;jj<2;jj++){
        int p = pbase + jj*16;
        ushort4 o;
        o.x = f2bf(acc[i][jj][0]); o.y = f2bf(acc[i][jj][1]);
        o.z = f2bf(acc[i][jj][2]); o.w = f2bf(acc[i][jj][3]);
        *(ushort4*)&Xtg[((size_t)(b*NH + h)*HD + p)*LL + lbase] = o;
      }
    }
  } else {
    #pragma unroll
    for (int i=0;i<4;i++)
      #pragma unroll
      for (int jj=0;jj<2;jj++)
        #pragma unroll
        for (int q=0;q<4;q++)
          pAux[(size_t)(row0 + i*16 + q)*PAW + col0 + jj*16 - DI] = acc[i][jj][q];
  }
}

// ---------------- per-token prep (2 rows/block) ----------------
__global__ __launch_bounds__(256) void k_prep(const float* __restrict__ pAux,
                                              const float* __restrict__ dt_bias,
                                              const float* __restrict__ Bnw,
                                              const float* __restrict__ Cnw,
                                              float* __restrict__ Bnr, float* __restrict__ Cnr,
                                              float* __restrict__ DTg, float* __restrict__ lag,
                                              float* __restrict__ w1g, float* __restrict__ w2g){
  int tid = threadIdx.x;
  int r = tid >> 7, t = tid & 127;
  int row = blockIdx.x*2 + r;
  const float* pr = pAux + (size_t)row*PAW;
  float bv = pr[t], cv = pr[128+t];
  float sb = bv*bv, sc = cv*cv;
  for (int o=32;o;o>>=1){ sb += __shfl_down(sb,o); sc += __shfl_down(sc,o); }
  __shared__ float red[8];
  if ((tid&63)==0){ red[(tid>>6)*2]=sb; red[(tid>>6)*2+1]=sc; }
  __syncthreads();
  float ssb = red[r*4]+red[r*4+2], ssc = red[r*4+1]+red[r*4+3];
  float rb = rsqrtf(ssb/DS + 1e-5f), rc = rsqrtf(ssc/DS + 1e-5f);
  Bnr[(size_t)row*DS+t] = bv*rb*Bnw[t];
  Cnr[(size_t)row*DS+t] = cv*rc*Cnw[t];
  if (t < NH){
    int h = t;
    float Av = -softplusf(pr[288+h]); Av = fminf(Av, -1e-4f);
    float DT = softplusf(pr[256+h] + dt_bias[h]);
    float la = Av*DT;
    float lam = 1.f/(1.f+expf(-pr[320+h]));
    DTg[row*NH+h] = DT;
    lag[row*NH+h] = la;
    w1g[row*NH+h] = DT*lam;
    w2g[row*NH+h] = DT*(1.f-lam)*expf(la);
  }
}

// ---------------- Theta cumsum, 3-phase (64-thread blocks) ----------------
__global__ __launch_bounds__(64) void k_theta_part(const float* __restrict__ pAux, const float* __restrict__ DTg,
                                                   float* __restrict__ Spart){
  int blk = blockIdx.x*2 + (threadIdx.x>>5);
  int j = threadIdx.x & 31;
  int h = blk % NH; int z = (blk/NH)%NC; int b = blk/(NH*NC);
  float acc = 0.f;
  for (int i=0;i<CH;i++){
    int row = b*LL + z*CH + i;
    acc += DTg[row*NH+h] * pAux[(size_t)row*PAW + 352 + j];
  }
  Spart[(size_t)blk*NR + j] = acc;
}

__global__ void k_theta_scan(float* __restrict__ Spart){
  int idx = blockIdx.x*blockDim.x + threadIdx.x;
  int j = idx % NR; int h = (idx/NR)%NH; int b = idx/(NR*NH);
  float acc = 0.f;
  for (int z=0;z<NC;z++){
    size_t o = (size_t)((b*NC+z)*NH + h)*NR + j;
    float t = Spart[o]; Spart[o] = acc; acc += t;
  }
}

__global__ __launch_bounds__(64) void k_theta_full(const float* __restrict__ pAux, const float* __restrict__ DTg,
                                                   const float* __restrict__ Spart, float* __restrict__ Theta){
  int blk = blockIdx.x*2 + (threadIdx.x>>5);
  int j = threadIdx.x & 31;
  int h = blk % NH; int z = (blk/NH)%NC; int b = blk/(NH*NC);
  float acc = Spart[(size_t)blk*NR + j];
  for (int i=0;i<CH;i++){
    int row = b*LL + z*CH + i;
    acc += DTg[row*NH+h] * pAux[(size_t)row*PAW + 352 + j];
    Theta[((size_t)row*NH + h)*NR + j] = acc;
  }
}

// ---------------- k_acum: per-chunk scan factors ----------------
__global__ __launch_bounds__(256) void k_acum(const float* __restrict__ lag,
                                              const float* __restrict__ w1g,
                                              const float* __restrict__ w2g,
                                              float* __restrict__ CV,
                                              float* __restrict__ Acumg,
                                              float* __restrict__ cdg){
  int blk = blockIdx.x*4 + (threadIdx.x>>6);
  int l = threadIdx.x & 63;
  int h = blk & 31, z = (blk>>5)&31, b = blk>>10;
  int row = b*LL + z*CH + l;
  float la = lag[row*NH+h], w1 = w1g[row*NH+h], w2 = w2g[row*NH+h];
  float a = la;
  #pragma unroll
  for (int o=1;o<64;o<<=1){ float t = __shfl_up(a,o); a += (l>=o) ? t : 0.f; }
  float Acm = __shfl(a, 31);
  float Alast = __shfl(a, 63);
  float eA = expf(a - Acm);
  float emA = expf(Acm - a);
  float rfac = expf(Alast - a);
  float rw1 = rfac*w1, rw2 = rfac*w2;
  float rw1p = __shfl_up(rw1, 1);
  float* cv = CV + (size_t)blk*CVW;
  cv[l] = eA;
  cv[64 + l] = emA*w1;          // G1[sp=l+1]
  cv[128 + l] = emA*w2;         // G2[sp=l]
  cv[192 + l] = (l>0 ? rw1p : 0.f) + rw2;   // vw[l]
  if (l == 63){ cv[192+64] = rw1; cdg[blk] = expf(Alast); }
  Acumg[(size_t)blk*CH + l] = a;
}

// ---------------- k_rope2 v3: rotation-pair tasks, trig inline, low LDS ----------------
__global__ __launch_bounds__(256) void k_rope2(const float* __restrict__ Bnr,
                                               const float* __restrict__ Cnr,
                                               const float* __restrict__ Theta,
                                               const float* __restrict__ B_bias,
                                               const float* __restrict__ C_bias,
                                               const float* __restrict__ CV,
                                               u16* __restrict__ Bn, u16* __restrict__ Cn,
                                               u16* __restrict__ BTw){
  __shared__ float vwS[65];
  __shared__ u16 BTt[128][68];
  int blk = blockIdx.x; int h = blk&31, z=(blk>>5)&31, b=blk>>10;
  int l0 = z*CH; int tid = threadIdx.x;
  if (tid < 65) vwS[tid] = CV[(size_t)blk*CVW + 192 + tid];
  __syncthreads();
  #pragma unroll
  for (int it=0; it<8; it++){
    int idx = it*256 + tid;
    int r = idx>>5, j = idx&31;      // r = 0..63, j = 0..31
    int row = b*LL + l0 + r;
    const float* br = Bnr + (size_t)row*DS;
    const float* cr = Cnr + (size_t)row*DS;
    const float* bb = B_bias + h*DS;
    const float* cb = C_bias + h*DS;
    float th = Theta[((size_t)row*NH + h)*NR + j];
    float cs = cosf(th), sn = sinf(th);
    float b0 = br[j]    + bb[j];
    float b1 = br[j+32] + bb[j+32];
    float b2 = br[j+64] + bb[j+64];
    float b3 = br[j+96] + bb[j+96];
    float c0 = cr[j]    + cb[j];
    float c1 = cr[j+32] + cb[j+32];
    float c2 = cr[j+64] + cb[j+64];
    float c3 = cr[j+96] + cb[j+96];
    float obA = b0*cs - b1*sn, obB = b0*sn + b1*cs;
    float ocA = c0*cs - c1*sn, ocB = c0*sn + c1*cs;
    u16* bnp = Bn + ((size_t)row*NH + h)*DS;
    u16* cnp = Cn + ((size_t)row*NH + h)*DS;
    bnp[j]    = f2bf(obA); bnp[j+32] = f2bf(obB);
    bnp[j+64] = f2bf(b2);  bnp[j+96] = f2bf(b3);
    cnp[j]    = f2bf(ocA); cnp[j+32] = f2bf(ocB);
    cnp[j+64] = f2bf(c2);  cnp[j+96] = f2bf(c3);
    float vwr = vwS[r+1];
    BTt[j][r]    = f2bf(obA*vwr);
    BTt[j+32][r] = f2bf(obB*vwr);
    BTt[j+64][r] = f2bf(b2*vwr);
    BTt[j+96][r] = f2bf(b3*vwr);
  }
  __syncthreads();
  for (int it=0; it<8; it++){
    int idx = it*256 + tid;
    int n = idx>>4, rg = (idx&15)*4;
    ushort4 o4;
    o4.x = BTt[n][rg];
    o4.y = BTt[n][rg+1];
    o4.z = BTt[n][rg+2];
    o4.w = BTt[n][rg+3];
    *(ushort4*)&BTw[((size_t)((b*NH+h)*DS) + n)*LL + l0 + rg] = o4;
  }
}

// ---------------- k_chunk_a: CB -> Mc -> Yintra(+fixups), U ----------------
__global__ __launch_bounds__(256) void k_chunk_a(
    const u16* __restrict__ Xtg, const u16* __restrict__ Bn,
    const u16* __restrict__ Cn, const u16* __restrict__ BTw,
    const float* __restrict__ CV, const float* __restrict__ Dgl,
    u16* __restrict__ Yb, u16* __restrict__ Ugb){
  __shared__ u16 BsBT[65*128];     // Bs rows 0..64 (CB); later BTw64 [128][64]
  __shared__ u16 CsMc[64*128];     // Cs swizzled -> Mc[64][72] overlay
  __shared__ u16 Xt64[64*64];      // X^T [p][k], k = s'-1
  __shared__ u16 Bp[128], Xp[64];
  __shared__ float cvS[260];
  __shared__ float mc0s[64];
  int blk = blockIdx.x;
  int h = blk&31, z=(blk>>5)&31, b=blk>>10;
  int l0 = z*CH;
  int tid = threadIdx.x; int l = tid&63, w = tid>>6;
  size_t bh = (size_t)(b*NH + h);

  // ---- phase 0: staging ----
  if (tid < 128){
    u16 v = 0;
    if (z > 0) v = Bn[((size_t)(b*LL+l0-1)*NH + h)*DS + tid];
    BsBT[tid] = v; Bp[tid] = v;
  } else if (tid < 192){
    int p = tid - 128;
    u16 v = 0;
    if (z > 0) v = Xtg[(bh*HD + p)*LL + l0 - 1];
    Xp[p] = v;
  }
  cvS[tid] = CV[(size_t)blk*CVW + tid];
  if (tid == 0) cvS[256] = CV[(size_t)blk*CVW + 256];
  #pragma unroll
  for (int cc=0; cc<4; cc++){
    int c = w*4 + cc;
    { int r = 1 + 4*c + (l>>4);
      gl_lds16(Bn + ((size_t)(b*LL+l0+r-1)*NH+h)*DS + (((l&15)^(r&7))<<3), &BsBT[(1+4*c)*128]); }
    { int r = 4*c + (l>>4);
      gl_lds16(Cn + ((size_t)(b*LL+l0+r)*NH+h)*DS + (((l&15)^(r&7))<<3), &CsMc[4*c*128]); }
  }
  #pragma unroll
  for (int cc=0; cc<2; cc++){
    int s = w*2 + cc;
    int uu = s*64 + l; int r = uu>>3, jl = uu&7, j = jl^(r&7);
    gl_lds16(Xtg + (bh*HD + r)*LL + l0 + j*8, &Xt64[s*512]);
  }
  __syncthreads();

  // ---- phase 1: CB GEMM over Bs rows 1..64; mc0 matvec (Cs x Bs row0) ----
  const f32x4 vzero = {0.f,0.f,0.f,0.f};
  f32x4 acb[4];
  #pragma unroll
  for (int j=0;j<4;j++) acb[j] = vzero;
  #pragma unroll
  for (int ks=0; ks<4; ks++){
    s16x8 af = ldswz(CsMc, 16*w + (l&15), ks*4 + (l>>4));
    #pragma unroll
    for (int j=0;j<4;j++){
      s16x8 bfr = ldswz(BsBT, 1 + 16*j + (l&15), ks*4 + (l>>4));
      acb[j] = __builtin_amdgcn_mfma_f32_16x16x32_bf16(af, bfr, acb[j], 0,0,0);
    }
  }
  {
    int t = tid>>2, part = tid&3;
    float s = 0.f;
    #pragma unroll
    for (int uu=0; uu<4; uu++){
      int u = part*4 + uu;
      s16x8 cr = *(const s16x8*)&CsMc[t*128 + ((u^(t&7))<<3)];
      s16x8 br = *(const s16x8*)&BsBT[u<<3];   // row 0, identity swizzle
      #pragma unroll
      for (int e=0;e<8;e++) s += bf2f(cr[e])*bf2f(br[e]);
    }
    s += __shfl_xor(s, 1); s += __shfl_xor(s, 2);
    if (part == 0) mc0s[t] = s * cvS[t] * cvS[128];   // CB[t][0]*eA[t]*G2[0]
  }
  __syncthreads();

  // ---- phase 2: issue BTw64 staging (overlays Bs); build Mc' ----
  #pragma unroll
  for (int cc=0; cc<4; cc++){
    int c = w*4 + cc;
    int uu = c*64 + l; int r = uu>>3, jl = uu&7, j = jl^(r&7);
    gl_lds16(BTw + (bh*DS + r)*LL + l0 + j*8, &BsBT[c*512]);
  }
  #pragma unroll
  for (int j=0;j<4;j++){
    #pragma unroll
    for (int q=0;q<4;q++){
      int t = 16*w + (l>>4)*4 + q;
      int k = 16*j + (l&15);
      int sp = k + 1;
      float g = 0.f;
      if (sp <= t+1) g += cvS[63+sp];
      if (sp <= t)   g += cvS[128+sp];
      g *= cvS[t];
      CsMc[t*72 + k] = f2bf(acb[j][q] * g);
    }
  }
  __syncthreads();

  // ---- phase 3: Yintra = Mc' @ Xt64^T + mc0 x Xp + D*x; write Yb ----
  f32x4 ay[4];
  #pragma unroll
  for (int j=0;j<4;j++) ay[j] = vzero;
  #pragma unroll
  for (int ks=0; ks<2; ks++){
    s16x8 af = ld72(CsMc, 16*w + (l&15), ks*32 + (l>>4)*8);
    #pragma unroll
    for (int j=0;j<4;j++){
      s16x8 bfr = ldswz64(Xt64, 16*j + (l&15), ks*4 + (l>>4));
      ay[j] = __builtin_amdgcn_mfma_f32_16x16x32_bf16(af, bfr, ay[j], 0,0,0);
    }
  }
  {
    float Dh = Dgl[h];
    #pragma unroll
    for (int j=0;j<4;j++){
      #pragma unroll
      for (int q=0;q<4;q++){
        int t = 16*w + (l>>4)*4 + q;
        int p = 16*j + (l&15);
        float xval = ldswz64_s(Xt64, p, t);
        float yv = ay[j][q] + mc0s[t]*bf2f(Xp[p]) + Dh*xval;
        Yb[((size_t)(b*LL + l0 + t))*DI + h*HD + p] = f2bf(yv);
      }
    }
  }

  // ---- phase 4: U = Xt64 @ BTw64^T (+ rank-1 sp=0 fixup); write Ugb bf16 ----
  f32x4 au[8];
  #pragma unroll
  for (int j=0;j<8;j++) au[j] = vzero;
  #pragma unroll
  for (int ks=0; ks<2; ks++){
    s16x8 af = ldswz64(Xt64, 16*w + (l&15), ks*4 + (l>>4));
    #pragma unroll
    for (int j=0;j<8;j++){
      s16x8 bfr = ldswz64(BsBT, 16*j + (l&15), ks*4 + (l>>4));
      au[j] = __builtin_amdgcn_mfma_f32_16x16x32_bf16(af, bfr, au[j], 0,0,0);
    }
  }
  {
    float vw0 = cvS[192];
    #pragma unroll
    for (int j=0;j<8;j++){
      #pragma unroll
      for (int q=0;q<4;q++){
        int p = 16*w + (l>>4)*4 + q;
        int n = 16*j + (l&15);
        float uv = au[j][q] + vw0*bf2f(Xp[p])*bf2f(Bp[n]);
        Ugb[(size_t)blk*(HD*DS) + p*DS + n] = f2bf(uv);
      }
    }
  }
}

// ---------------- inter-chunk state scan (bf16 in-place, vectorized s16x8) ----------------
__global__ __launch_bounds__(256) void k_scan(u16* __restrict__ Ugb, const float* __restrict__ cdg){
  int idx = blockIdx.x*256 + threadIdx.x;     // 65536 threads
  int pn8 = (idx & 1023)*8;
  int h  = (idx >> 10) & 31;
  int b  = idx >> 15;
  float hs[8];
  #pragma unroll
  for (int e=0;e<8;e++) hs[e] = 0.f;
  for (int z=0;z<NC;z++){
    size_t o = ((size_t)((b*NC+z)*NH) + h)*(HD*DS) + pn8;
    s16x8 v = *(s16x8*)&Ugb[o];
    float cd = cdg[(b*NC+z)*NH + h];
    s16x8 wv;
    #pragma unroll
    for (int e=0;e<8;e++){
      float tmp = bf2f((u16)v[e]);
      wv[e] = (short)f2bf(hs[e]);
      hs[e] = cd*hs[e] + tmp;
    }
    *(s16x8*)&Ugb[o] = wv;
  }
}

// ---------------- k_state: Ystate MFMA + Y RMW ----------------
__global__ __launch_bounds__(256) void k_state(
    const u16* __restrict__ Cn, const u16* __restrict__ Ugb,
    const float* __restrict__ Acumg, u16* __restrict__ Yb){
  __shared__ u16 Cs[64*128];
  __shared__ u16 Sb[64*128];
  __shared__ float eAs[64];
  int blk = blockIdx.x;
  int h = blk & 31, z = (blk>>5)&31, b = blk>>10;
  int l0 = z*CH;
  int tid = threadIdx.x;
  int l = tid & 63, w = tid >> 6;

  if (tid < 64) eAs[tid] = expf(Acumg[(size_t)blk*CH + tid]);
  #pragma unroll
  for (int cc=0; cc<4; cc++){
    int c = w*4 + cc;
    int r = 4*c + (l>>4);
    gl_lds16(Cn + ((size_t)(b*LL + l0 + r)*NH + h)*DS + (((l&15)^(r&7))<<3), &Cs[4*c*128]);
    gl_lds16(Ugb + (size_t)blk*(HD*DS) + (size_t)r*DS + (((l&15)^(r&7))<<3), &Sb[4*c*128]);
  }
  __syncthreads();

  f32x4 as[4];
  const f32x4 vzero = {0.f,0.f,0.f,0.f};
  #pragma unroll
  for (int j=0;j<4;j++) as[j] = vzero;
  #pragma unroll
  for (int ks=0; ks<4; ks++){
    s16x8 af = ldswz(Cs, 16*w + (l&15), ks*4 + (l>>4));
    #pragma unroll
    for (int j=0;j<4;j++){
      s16x8 bfr = ldswz(Sb, 16*j + (l&15), ks*4 + (l>>4));
      as[j] = __builtin_amdgcn_mfma_f32_16x16x32_bf16(af, bfr, as[j], 0,0,0);
    }
  }
  #pragma unroll
  for (int j=0;j<4;j++){
    #pragma unroll
    for (int q=0;q<4;q++){
      int t = 16*w + (l>>4)*4 + q;
      int p = 16*j + (l&15);
      size_t idx = ((size_t)(b*LL + l0 + t))*DI + h*HD + p;
      Yb[idx] = f2bf(bf2f(Yb[idx]) + eAs[t]*as[j][q]);
    }
  }
}

// ---------------- generic MFMA NT GEMM, 8-wave (512t), XCD swizzle (out-proj) ----------------
template<int N, int K>
__global__ __launch_bounds__(512) void k_mfma_nt(const u16* __restrict__ A,
                                                 const u16* __restrict__ Bm,
                                                 float* __restrict__ C){
  __shared__ u16 lA[128*64];
  __shared__ u16 lB[128*64];
  int tid = threadIdx.x;
  int l = tid & 63, w = tid >> 6;
  int nwg = gridDim.x*gridDim.y;
  int flat = blockIdx.y*gridDim.x + blockIdx.x;
  int cpx = nwg >> 3;
  int swz = (flat & 7)*cpx + (flat >> 3);
  int bx = swz % gridDim.x, by = swz / gridDim.x;
  int bm = by*128, bn = bx*128;
  int wr = w >> 2, wc = w & 3;
  const f32x4 vzero = {0.f,0.f,0.f,0.f};
  f32x4 acc[4][2];
  #pragma unroll
  for (int i=0;i<4;i++)
    #pragma unroll
    for (int j=0;j<2;j++) acc[i][j] = vzero;

  for (int kt=0; kt<K; kt+=64){
    __syncthreads();
    #pragma unroll
    for (int cc=0; cc<2; cc++){
      int s = w*2 + cc;
      int uu = s*64 + l;
      int r = uu >> 3, jl = uu & 7;
      int j = jl ^ (r & 7);
      gl_lds16(A  + (size_t)(bm+r)*K + kt + j*8, &lA[s*512]);
      gl_lds16(Bm + (size_t)(bn+r)*K + kt + j*8, &lB[s*512]);
    }
    __syncthreads();
    #pragma unroll
    for (int ks=0; ks<2; ks++){
      s16x8 af[4], bf[2];
      #pragma unroll
      for (int i=0;i<4;i++){
        int row = wr*64 + i*16 + (l&15);
        int j = ks*4 + (l>>4);
        af[i] = *(const s16x8*)&lA[row*64 + (j^(row&7))*8];
      }
      #pragma unroll
      for (int i=0;i<2;i++){
        int row = wc*32 + i*16 + (l&15);
        int j = ks*4 + (l>>4);
        bf[i] = *(const s16x8*)&lB[row*64 + (j^(row&7))*8];
      }
      #pragma unroll
      for (int i=0;i<4;i++)
        #pragma unroll
        for (int jj=0;jj<2;jj++)
          acc[i][jj] = __builtin_amdgcn_mfma_f32_16x16x32_bf16(af[i], bf[jj], acc[i][jj], 0,0,0);
    }
  }
  int col0 = bn + wc*32 + (l&15);
  int row0 = bm + wr*64 + (l>>4)*4;
  #pragma unroll
  for (int i=0;i<4;i++)
    #pragma unroll
    for (int jj=0;jj<2;jj++)
      #pragma unroll
      for (int q=0;q<4;q++)
        C[(size_t)(row0 + i*16 + q)*N + col0 + jj*16] = acc[i][jj][q];
}

// ---------------- workspace layout (bytes) ----------------
constexpr size_t OFF_PAUX  = 0;            // 6,291,456 ; later overlaid by Wout_bf
constexpr size_t OFF_XTG   = 6291456;      // 16,777,216
constexpr size_t OFF_BNR   = 23068672;     // 2,097,152
constexpr size_t OFF_CNR   = 25165824;     // 2,097,152
constexpr size_t OFF_DT    = 27262976;     // 524,288
constexpr size_t OFF_LA    = 27787264;     // 524,288
constexpr size_t OFF_W1    = 28311552;     // 524,288
constexpr size_t OFF_W2    = 28835840;     // 524,288
constexpr size_t OFF_SPART = 29360128;     // 262,144
constexpr size_t OFF_CV    = 29622272;     // 2,162,688
constexpr size_t OFF_ACUM  = 31784960;     // 524,288
constexpr size_t OFF_CD    = 32309248;     // 8,192
constexpr size_t OFF_THETA = 32317440;     // 16,777,216 ; overlaid by Yb
constexpr size_t OFF_Y     = OFF_THETA;
constexpr size_t OFF_BN    = 49094656;     // 33,554,432
constexpr size_t OFF_CN    = 82649088;     // 33,554,432
constexpr size_t OFF_BTW   = 116203520;    // 33,554,432
constexpr size_t OFF_R1    = 149757952;    // u_bf+Win_bf -> Ugb(33.55M)
constexpr size_t OFF_UBF   = OFF_R1;
constexpr size_t OFF_WINBF = OFF_R1 + 16777216;
constexpr size_t OFF_UGB   = OFF_R1;
constexpr size_t OFF_WOUTBF= OFF_PAUX;
// total = 183,312,384 bytes

extern "C" void kernel_launch(void* const* d_in, const int* in_sizes, int n_in,
                              void* d_out, int out_size, void* d_ws, size_t ws_size,
                              hipStream_t stream) {
  const float* u       = (const float*)d_in[0];
  const float* W_in    = (const float*)d_in[1];
  const float* dt_bias = (const float*)d_in[2];
  const float* B_bias  = (const float*)d_in[3];
  const float* C_bias  = (const float*)d_in[4];
  const float* Bnw     = (const float*)d_in[5];
  const float* Cnw     = (const float*)d_in[6];
  const float* Dg      = (const float*)d_in[7];
  const float* W_out   = (const float*)d_in[8];
  float* out = (float*)d_out;
  char* ws = (char*)d_ws;

  float* pAux  = (float*)(ws + OFF_PAUX);
  u16*   Xtg   = (u16*)  (ws + OFF_XTG);
  float* Bnr   = (float*)(ws + OFF_BNR);
  float* Cnr   = (float*)(ws + OFF_CNR);
  float* DTg   = (float*)(ws + OFF_DT);
  float* lag   = (float*)(ws + OFF_LA);
  float* w1g   = (float*)(ws + OFF_W1);
  float* w2g   = (float*)(ws + OFF_W2);
  float* Spart = (float*)(ws + OFF_SPART);
  float* CVp   = (float*)(ws + OFF_CV);
  float* Acumg = (float*)(ws + OFF_ACUM);
  float* cdg   = (float*)(ws + OFF_CD);
  float* Theta = (float*)(ws + OFF_THETA);
  u16*   Yb    = (u16*)  (ws + OFF_Y);
  u16*   Bn    = (u16*)  (ws + OFF_BN);
  u16*   Cn    = (u16*)  (ws + OFF_CN);
  u16*   BTw   = (u16*)  (ws + OFF_BTW);
  u16*   u_bf  = (u16*)  (ws + OFF_UBF);
  u16*   Win_bf= (u16*)  (ws + OFF_WINBF);
  u16*   Ugb   = (u16*)  (ws + OFF_UGB);
  u16*   Wout_bf=(u16*)  (ws + OFF_WOUTBF);

  k_cast<<<(NTOK*DMODEL)/1024, 256, 0, stream>>>(u, u_bf, NTOK*DMODEL);
  k_cast<<<(DIP*DMODEL)/1024, 256, 0, stream>>>(W_in, Win_bf, DIP*DMODEL);
  k_gemm_in<<<dim3(DIP/128, NTOK/128), 512, 0, stream>>>(u_bf, Win_bf, pAux, Xtg);

  k_prep      <<<NTOK/2, 256, 0, stream>>>(pAux, dt_bias, Bnw, Cnw, Bnr, Cnr, DTg, lag, w1g, w2g);
  k_theta_part<<<(BB*NC*NH)/2, 64, 0, stream>>>(pAux, DTg, Spart);
  k_theta_scan<<<(BB*NH*NR)/256, 256, 0, stream>>>(Spart);
  k_theta_full<<<(BB*NC*NH)/2, 64, 0, stream>>>(pAux, DTg, Spart, Theta);
  k_acum      <<<(BB*NC*NH)/4, 256, 0, stream>>>(lag, w1g, w2g, CVp, Acumg, cdg);
  k_rope2     <<<BB*NC*NH, 256, 0, stream>>>(Bnr, Cnr, Theta, B_bias, C_bias, CVp, Bn, Cn, BTw);

  k_chunk_a<<<BB*NC*NH, 256, 0, stream>>>(Xtg, Bn, Cn, BTw, CVp, Dg, Yb, Ugb);
  k_scan   <<<(BB*NH*HD*DS)/(256*8), 256, 0, stream>>>(Ugb, cdg);
  k_state  <<<BB*NC*NH, 256, 0, stream>>>(Cn, Ugb, Acumg, Yb);

  k_cast<<<(DMODEL*DI)/1024, 256, 0, stream>>>(W_out, Wout_bf, DMODEL*DI);
  k_mfma_nt<DMODEL, DI><<<dim3(DMODEL/128, NTOK/128), 512, 0, stream>>>(Yb, Wout_bf, out);

  (void)in_sizes; (void)n_in; (void)out_size; (void)ws_size;
}

// Round 14
// 182.830 us; speedup vs baseline: 1.0683x; 1.0438x over previous
//
#include <hip/hip_runtime.h>
#include <hip/hip_bf16.h>
#include <math.h>

typedef unsigned short u16;
typedef __attribute__((ext_vector_type(8))) short s16x8;
typedef __attribute__((ext_vector_type(4))) float f32x4;

#define BB 2
#define LL 2048
#define DMODEL 1024
#define DI 2048
#define NH 32
#define HD 64
#define DS 128
#define NR 32
#define CH 64
#define NC 32
#define DIP 2432
#define NTOK (BB*LL)
#define PAW 384   // projAux width: cols 2048..2431 of proj
#define CVW 264   // per-chunk factor-table stride (floats)

__device__ __forceinline__ float bf2f(u16 u){ union{unsigned i; float f;} c; c.i=((unsigned)u)<<16; return c.f; }
__device__ __forceinline__ u16 f2bf(float f){ __hip_bfloat16 h=__float2bfloat16(f); return *reinterpret_cast<u16*>(&h); }
__device__ __forceinline__ float softplusf(float x){ return fmaxf(x,0.f) + log1pf(expf(-fabsf(x))); }

__device__ __forceinline__ void gl_lds16(const void* g, void* l){
  __builtin_amdgcn_global_load_lds((const __attribute__((address_space(1))) void*)g,
                                   (__attribute__((address_space(3))) void*)l, 16, 0, 0);
}

// swizzled [*][128] bf16 row (256B): 16B unit u at slot u^(r&7)
__device__ __forceinline__ s16x8 ldswz(const u16* base, int r, int kunit){
  return *(const s16x8*)&base[r*128 + ((kunit ^ (r&7))<<3)];
}
// swizzled [*][64] bf16 row (128B): unit u (0..7) at slot u^(r&7)
__device__ __forceinline__ s16x8 ldswz64(const u16* base, int r, int kunit){
  return *(const s16x8*)&base[r*64 + ((kunit ^ (r&7))<<3)];
}
__device__ __forceinline__ float ldswz64_s(const u16* base, int r, int n){
  return bf2f(base[r*64 + (((n>>3) ^ (r&7))<<3) + (n&7)]);
}
// plain stride-72 bf16 rows
__device__ __forceinline__ s16x8 ld72(const u16* base, int r, int kelem){
  return *(const s16x8*)&base[r*72 + kelem];
}

// ---------------- merged cast fp32 -> bf16 (u, W_in, W_out in one launch) ----------------
#define CQ1 ((NTOK*DMODEL)/4)
#define CQ2 ((DIP*DMODEL)/4)
#define CQ3 ((DMODEL*DI)/4)
__global__ __launch_bounds__(256) void k_cast3(const float* __restrict__ u, const float* __restrict__ Wi,
                                               const float* __restrict__ Wo,
                                               u16* __restrict__ ub, u16* __restrict__ wib,
                                               u16* __restrict__ wob){
  int i = blockIdx.x*256 + threadIdx.x;
  const float* src; u16* dst; int q;
  if (i < CQ1){ src = u; dst = ub; q = i; }
  else if (i < CQ1+CQ2){ src = Wi; dst = wib; q = i - CQ1; }
  else if (i < CQ1+CQ2+CQ3){ src = Wo; dst = wob; q = i - CQ1 - CQ2; }
  else return;
  float4 v = *(const float4*)&src[(size_t)q*4];
  ushort4 o; o.x=f2bf(v.x); o.y=f2bf(v.y); o.z=f2bf(v.z); o.w=f2bf(v.w);
  *(ushort4*)&dst[(size_t)q*4] = o;
}

// ---------------- in-proj GEMM, 8-wave (512t) 128x128 tile, split epilogue, XCD swizzle ----------------
__global__ __launch_bounds__(512) void k_gemm_in(const u16* __restrict__ A,
                                                 const u16* __restrict__ Bm,
                                                 float* __restrict__ pAux,
                                                 u16* __restrict__ Xtg){
  __shared__ u16 lA[128*64];
  __shared__ u16 lB[128*64];
  int tid = threadIdx.x;
  int l = tid & 63, w = tid >> 6;          // 8 waves
  int nwg = gridDim.x*gridDim.y;
  int flat = blockIdx.y*gridDim.x + blockIdx.x;
  int cpx = nwg >> 3;
  int swz = (flat & 7)*cpx + (flat >> 3);
  int bx = swz % gridDim.x, by = swz / gridDim.x;
  int bm = by*128, bn = bx*128;
  int wr = w >> 2, wc = w & 3;             // 2x4 wave grid: 64 rows x 32 cols per wave
  const f32x4 vzero = {0.f,0.f,0.f,0.f};
  f32x4 acc[4][2];
  #pragma unroll
  for (int i=0;i<4;i++)
    #pragma unroll
    for (int j=0;j<2;j++) acc[i][j] = vzero;

  for (int kt=0; kt<DMODEL; kt+=64){
    __syncthreads();
    #pragma unroll
    for (int cc=0; cc<2; cc++){
      int s = w*2 + cc;
      int uu = s*64 + l;
      int r = uu >> 3, jl = uu & 7;
      int j = jl ^ (r & 7);
      gl_lds16(A  + (size_t)(bm+r)*DMODEL + kt + j*8, &lA[s*512]);
      gl_lds16(Bm + (size_t)(bn+r)*DMODEL + kt + j*8, &lB[s*512]);
    }
    __syncthreads();
    #pragma unroll
    for (int ks=0; ks<2; ks++){
      s16x8 af[4], bf[2];
      #pragma unroll
      for (int i=0;i<4;i++){
        int row = wr*64 + i*16 + (l&15);
        int j = ks*4 + (l>>4);
        af[i] = *(const s16x8*)&lA[row*64 + (j^(row&7))*8];
      }
      #pragma unroll
      for (int i=0;i<2;i++){
        int row = wc*32 + i*16 + (l&15);
        int j = ks*4 + (l>>4);
        bf[i] = *(const s16x8*)&lB[row*64 + (j^(row&7))*8];
      }
      #pragma unroll
      for (int i=0;i<4;i++)
        #pragma unroll
        for (int jj=0;jj<2;jj++)
          acc[i][jj] = __builtin_amdgcn_mfma_f32_16x16x32_bf16(af[i], bf[jj], acc[i][jj], 0,0,0);
    }
  }
  int col0 = bn + wc*32 + (l&15);
  int row0 = bm + wr*64 + (l>>4)*4;
  if (bn < DI){
    int h = (bn + wc*32) >> 6;
    int pbase = (wc & 1)*32 + (l&15);
    int b = bm >> 11;
    #pragma unroll
    for (int i=0;i<4;i++){
      int lbase = (bm & (LL-1)) + wr*64 + (l>>4)*4 + i*16;
      #pragma unroll
      for (int jj=0;jj<2;jj++){
        int p = pbase + jj*16;
        ushort4 o;
        o.x = f2bf(acc[i][jj][0]); o.y = f2bf(acc[i][jj][1]);
        o.z = f2bf(acc[i][jj][2]); o.w = f2bf(acc[i][jj][3]);
        *(ushort4*)&Xtg[((size_t)(b*NH + h)*HD + p)*LL + lbase] = o;
      }
    }
  } else {
    #pragma unroll
    for (int i=0;i<4;i++)
      #pragma unroll
      for (int jj=0;jj<2;jj++)
        #pragma unroll
        for (int q=0;q<4;q++)
          pAux[(size_t)(row0 + i*16 + q)*PAW + col0 + jj*16 - DI] = acc[i][jj][q];
  }
}

// ---------------- per-token prep (2 rows/block) ----------------
__global__ __launch_bounds__(256) void k_prep(const float* __restrict__ pAux,
                                              const float* __restrict__ dt_bias,
                                              const float* __restrict__ Bnw,
                                              const float* __restrict__ Cnw,
                                              float* __restrict__ Bnr, float* __restrict__ Cnr,
                                              float* __restrict__ DTg, float* __restrict__ lag,
                                              float* __restrict__ w1g, float* __restrict__ w2g){
  int tid = threadIdx.x;
  int r = tid >> 7, t = tid & 127;
  int row = blockIdx.x*2 + r;
  const float* pr = pAux + (size_t)row*PAW;
  float bv = pr[t], cv = pr[128+t];
  float sb = bv*bv, sc = cv*cv;
  for (int o=32;o;o>>=1){ sb += __shfl_down(sb,o); sc += __shfl_down(sc,o); }
  __shared__ float red[8];
  if ((tid&63)==0){ red[(tid>>6)*2]=sb; red[(tid>>6)*2+1]=sc; }
  __syncthreads();
  float ssb = red[r*4]+red[r*4+2], ssc = red[r*4+1]+red[r*4+3];
  float rb = rsqrtf(ssb/DS + 1e-5f), rc = rsqrtf(ssc/DS + 1e-5f);
  Bnr[(size_t)row*DS+t] = bv*rb*Bnw[t];
  Cnr[(size_t)row*DS+t] = cv*rc*Cnw[t];
  if (t < NH){
    int h = t;
    float Av = -softplusf(pr[288+h]); Av = fminf(Av, -1e-4f);
    float DT = softplusf(pr[256+h] + dt_bias[h]);
    float la = Av*DT;
    float lam = 1.f/(1.f+expf(-pr[320+h]));
    DTg[row*NH+h] = DT;
    lag[row*NH+h] = la;
    w1g[row*NH+h] = DT*lam;
    w2g[row*NH+h] = DT*(1.f-lam)*expf(la);
  }
}

// ---------------- Theta cumsum, 3-phase (64-thread blocks) ----------------
__global__ __launch_bounds__(64) void k_theta_part(const float* __restrict__ pAux, const float* __restrict__ DTg,
                                                   float* __restrict__ Spart){
  int blk = blockIdx.x*2 + (threadIdx.x>>5);
  int j = threadIdx.x & 31;
  int h = blk % NH; int z = (blk/NH)%NC; int b = blk/(NH*NC);
  float acc = 0.f;
  for (int i=0;i<CH;i++){
    int row = b*LL + z*CH + i;
    acc += DTg[row*NH+h] * pAux[(size_t)row*PAW + 352 + j];
  }
  Spart[(size_t)blk*NR + j] = acc;
}

__global__ void k_theta_scan(float* __restrict__ Spart){
  int idx = blockIdx.x*blockDim.x + threadIdx.x;
  int j = idx % NR; int h = (idx/NR)%NH; int b = idx/(NR*NH);
  float acc = 0.f;
  for (int z=0;z<NC;z++){
    size_t o = (size_t)((b*NC+z)*NH + h)*NR + j;
    float t = Spart[o]; Spart[o] = acc; acc += t;
  }
}

__global__ __launch_bounds__(64) void k_theta_full(const float* __restrict__ pAux, const float* __restrict__ DTg,
                                                   const float* __restrict__ Spart, float* __restrict__ Theta){
  int blk = blockIdx.x*2 + (threadIdx.x>>5);
  int j = threadIdx.x & 31;
  int h = blk % NH; int z = (blk/NH)%NC; int b = blk/(NH*NC);
  float acc = Spart[(size_t)blk*NR + j];
  for (int i=0;i<CH;i++){
    int row = b*LL + z*CH + i;
    acc += DTg[row*NH+h] * pAux[(size_t)row*PAW + 352 + j];
    Theta[((size_t)row*NH + h)*NR + j] = acc;
  }
}

// ---------------- k_acum: per-chunk scan factors ----------------
__global__ __launch_bounds__(256) void k_acum(const float* __restrict__ lag,
                                              const float* __restrict__ w1g,
                                              const float* __restrict__ w2g,
                                              float* __restrict__ CV,
                                              float* __restrict__ Acumg,
                                              float* __restrict__ cdg){
  int blk = blockIdx.x*4 + (threadIdx.x>>6);
  int l = threadIdx.x & 63;
  int h = blk & 31, z = (blk>>5)&31, b = blk>>10;
  int row = b*LL + z*CH + l;
  float la = lag[row*NH+h], w1 = w1g[row*NH+h], w2 = w2g[row*NH+h];
  float a = la;
  #pragma unroll
  for (int o=1;o<64;o<<=1){ float t = __shfl_up(a,o); a += (l>=o) ? t : 0.f; }
  float Acm = __shfl(a, 31);
  float Alast = __shfl(a, 63);
  float eA = expf(a - Acm);
  float emA = expf(Acm - a);
  float rfac = expf(Alast - a);
  float rw1 = rfac*w1, rw2 = rfac*w2;
  float rw1p = __shfl_up(rw1, 1);
  float* cv = CV + (size_t)blk*CVW;
  cv[l] = eA;
  cv[64 + l] = emA*w1;          // G1[sp=l+1]
  cv[128 + l] = emA*w2;         // G2[sp=l]
  cv[192 + l] = (l>0 ? rw1p : 0.f) + rw2;   // vw[l]
  if (l == 63){ cv[192+64] = rw1; cdg[blk] = expf(Alast); }
  Acumg[(size_t)blk*CH + l] = a;
}

// ---------------- k_rope2 v3: rotation-pair tasks, trig inline, low LDS ----------------
__global__ __launch_bounds__(256) void k_rope2(const float* __restrict__ Bnr,
                                               const float* __restrict__ Cnr,
                                               const float* __restrict__ Theta,
                                               const float* __restrict__ B_bias,
                                               const float* __restrict__ C_bias,
                                               const float* __restrict__ CV,
                                               u16* __restrict__ Bn, u16* __restrict__ Cn,
                                               u16* __restrict__ BTw){
  __shared__ float vwS[65];
  __shared__ u16 BTt[128][68];
  int blk = blockIdx.x; int h = blk&31, z=(blk>>5)&31, b=blk>>10;
  int l0 = z*CH; int tid = threadIdx.x;
  if (tid < 65) vwS[tid] = CV[(size_t)blk*CVW + 192 + tid];
  __syncthreads();
  #pragma unroll
  for (int it=0; it<8; it++){
    int idx = it*256 + tid;
    int r = idx>>5, j = idx&31;
    int row = b*LL + l0 + r;
    const float* br = Bnr + (size_t)row*DS;
    const float* cr = Cnr + (size_t)row*DS;
    const float* bb = B_bias + h*DS;
    const float* cb = C_bias + h*DS;
    float th = Theta[((size_t)row*NH + h)*NR + j];
    float cs = cosf(th), sn = sinf(th);
    float b0 = br[j]    + bb[j];
    float b1 = br[j+32] + bb[j+32];
    float b2 = br[j+64] + bb[j+64];
    float b3 = br[j+96] + bb[j+96];
    float c0 = cr[j]    + cb[j];
    float c1 = cr[j+32] + cb[j+32];
    float c2 = cr[j+64] + cb[j+64];
    float c3 = cr[j+96] + cb[j+96];
    float obA = b0*cs - b1*sn, obB = b0*sn + b1*cs;
    float ocA = c0*cs - c1*sn, ocB = c0*sn + c1*cs;
    u16* bnp = Bn + ((size_t)row*NH + h)*DS;
    u16* cnp = Cn + ((size_t)row*NH + h)*DS;
    bnp[j]    = f2bf(obA); bnp[j+32] = f2bf(obB);
    bnp[j+64] = f2bf(b2);  bnp[j+96] = f2bf(b3);
    cnp[j]    = f2bf(ocA); cnp[j+32] = f2bf(ocB);
    cnp[j+64] = f2bf(c2);  cnp[j+96] = f2bf(c3);
    float vwr = vwS[r+1];
    BTt[j][r]    = f2bf(obA*vwr);
    BTt[j+32][r] = f2bf(obB*vwr);
    BTt[j+64][r] = f2bf(b2*vwr);
    BTt[j+96][r] = f2bf(b3*vwr);
  }
  __syncthreads();
  for (int it=0; it<8; it++){
    int idx = it*256 + tid;
    int n = idx>>4, rg = (idx&15)*4;
    ushort4 o4;
    o4.x = BTt[n][rg];
    o4.y = BTt[n][rg+1];
    o4.z = BTt[n][rg+2];
    o4.w = BTt[n][rg+3];
    *(ushort4*)&BTw[((size_t)((b*NH+h)*DS) + n)*LL + l0 + rg] = o4;
  }
}

// ---------------- k_chunk_a: 8-wave (512t) CB -> Mc -> Yintra(+fixups), U ----------------
__global__ __launch_bounds__(512) void k_chunk_a(
    const u16* __restrict__ Xtg, const u16* __restrict__ Bn,
    const u16* __restrict__ Cn, const u16* __restrict__ BTw,
    const float* __restrict__ CV, const float* __restrict__ Dgl,
    u16* __restrict__ Yb, u16* __restrict__ Ugb){
  __shared__ u16 BsBT[65*128];     // Bs rows 0..64 (CB); later BTw64 [128][64]
  __shared__ u16 CsMc[64*128];     // Cs swizzled -> Mc[64][72] overlay
  __shared__ u16 Xt64[64*64];      // X^T [p][k], k = s'-1
  __shared__ u16 Bp[128], Xp[64];
  __shared__ float cvS[260];
  __shared__ float mc0s[64];
  int blk = blockIdx.x;
  int h = blk&31, z=(blk>>5)&31, b=blk>>10;
  int l0 = z*CH;
  int tid = threadIdx.x; int l = tid&63, w = tid>>6;    // 8 waves
  int wA = w >> 1, wB = w & 1;
  size_t bh = (size_t)(b*NH + h);

  // ---- phase 0: staging ----
  if (tid < 128){
    u16 v = 0;
    if (z > 0) v = Bn[((size_t)(b*LL+l0-1)*NH + h)*DS + tid];
    BsBT[tid] = v; Bp[tid] = v;
  } else if (tid < 192){
    int p = tid - 128;
    u16 v = 0;
    if (z > 0) v = Xtg[(bh*HD + p)*LL + l0 - 1];
    Xp[p] = v;
  }
  if (tid < 257) cvS[tid] = CV[(size_t)blk*CVW + tid];
  #pragma unroll
  for (int cc=0; cc<2; cc++){
    int c = w*2 + cc;
    { int r = 1 + 4*c + (l>>4);
      gl_lds16(Bn + ((size_t)(b*LL+l0+r-1)*NH+h)*DS + (((l&15)^(r&7))<<3), &BsBT[(1+4*c)*128]); }
    { int r = 4*c + (l>>4);
      gl_lds16(Cn + ((size_t)(b*LL+l0+r)*NH+h)*DS + (((l&15)^(r&7))<<3), &CsMc[4*c*128]); }
  }
  {
    int uu = w*64 + l; int r = uu>>3, jl = uu&7, j = jl^(r&7);
    gl_lds16(Xtg + (bh*HD + r)*LL + l0 + j*8, &Xt64[w*512]);
  }
  __syncthreads();

  // ---- phase 1: CB GEMM over Bs rows 1..64 (2 tiles/wave); mc0 matvec ----
  const f32x4 vzero = {0.f,0.f,0.f,0.f};
  f32x4 acb[2];
  #pragma unroll
  for (int j=0;j<2;j++) acb[j] = vzero;
  #pragma unroll
  for (int ks=0; ks<4; ks++){
    s16x8 af = ldswz(CsMc, 16*wA + (l&15), ks*4 + (l>>4));
    #pragma unroll
    for (int j=0;j<2;j++){
      s16x8 bfr = ldswz(BsBT, 1 + 16*(wB*2+j) + (l&15), ks*4 + (l>>4));
      acb[j] = __builtin_amdgcn_mfma_f32_16x16x32_bf16(af, bfr, acb[j], 0,0,0);
    }
  }
  {
    int t = tid>>3, part = tid&7;
    float s = 0.f;
    #pragma unroll
    for (int uu=0; uu<2; uu++){
      int u = part*2 + uu;
      s16x8 cr = *(const s16x8*)&CsMc[t*128 + ((u^(t&7))<<3)];
      s16x8 br = *(const s16x8*)&BsBT[u<<3];   // row 0, identity swizzle
      #pragma unroll
      for (int e=0;e<8;e++) s += bf2f(cr[e])*bf2f(br[e]);
    }
    s += __shfl_xor(s, 1); s += __shfl_xor(s, 2); s += __shfl_xor(s, 4);
    if (part == 0) mc0s[t] = s * cvS[t] * cvS[128];   // CB[t][0]*eA[t]*G2[0]
  }
  __syncthreads();

  // ---- phase 2: issue BTw64 staging (overlays Bs); build Mc' ----
  #pragma unroll
  for (int cc=0; cc<2; cc++){
    int c = w*2 + cc;
    int uu = c*64 + l; int r = uu>>3, jl = uu&7, j = jl^(r&7);
    gl_lds16(BTw + (bh*DS + r)*LL + l0 + j*8, &BsBT[c*512]);
  }
  #pragma unroll
  for (int j=0;j<2;j++){
    #pragma unroll
    for (int q=0;q<4;q++){
      int t = 16*wA + (l>>4)*4 + q;
      int k = 16*(wB*2+j) + (l&15);
      int sp = k + 1;
      float g = 0.f;
      if (sp <= t+1) g += cvS[63+sp];
      if (sp <= t)   g += cvS[128+sp];
      g *= cvS[t];
      CsMc[t*72 + k] = f2bf(acb[j][q] * g);
    }
  }
  __syncthreads();

  // ---- phase 3: Yintra = Mc' @ Xt64^T + mc0 x Xp + D*x (2 tiles/wave); write Yb ----
  f32x4 ay[2];
  #pragma unroll
  for (int j=0;j<2;j++) ay[j] = vzero;
  #pragma unroll
  for (int ks=0; ks<2; ks++){
    s16x8 af = ld72(CsMc, 16*wA + (l&15), ks*32 + (l>>4)*8);
    #pragma unroll
    for (int j=0;j<2;j++){
      s16x8 bfr = ldswz64(Xt64, 16*(wB*2+j) + (l&15), ks*4 + (l>>4));
      ay[j] = __builtin_amdgcn_mfma_f32_16x16x32_bf16(af, bfr, ay[j], 0,0,0);
    }
  }
  {
    float Dh = Dgl[h];
    #pragma unroll
    for (int j=0;j<2;j++){
      #pragma unroll
      for (int q=0;q<4;q++){
        int t = 16*wA + (l>>4)*4 + q;
        int p = 16*(wB*2+j) + (l&15);
        float xval = ldswz64_s(Xt64, p, t);
        float yv = ay[j][q] + mc0s[t]*bf2f(Xp[p]) + Dh*xval;
        Yb[((size_t)(b*LL + l0 + t))*DI + h*HD + p] = f2bf(yv);
      }
    }
  }

  // ---- phase 4: U = Xt64 @ BTw64^T (4 tiles/wave, + rank-1 sp=0 fixup); write Ugb ----
  f32x4 au[4];
  #pragma unroll
  for (int j=0;j<4;j++) au[j] = vzero;
  #pragma unroll
  for (int ks=0; ks<2; ks++){
    s16x8 af = ldswz64(Xt64, 16*wA + (l&15), ks*4 + (l>>4));
    #pragma unroll
    for (int j=0;j<4;j++){
      s16x8 bfr = ldswz64(BsBT, 16*(wB*4+j) + (l&15), ks*4 + (l>>4));
      au[j] = __builtin_amdgcn_mfma_f32_16x16x32_bf16(af, bfr, au[j], 0,0,0);
    }
  }
  {
    float vw0 = cvS[192];
    #pragma unroll
    for (int j=0;j<4;j++){
      #pragma unroll
      for (int q=0;q<4;q++){
        int p = 16*wA + (l>>4)*4 + q;
        int n = 16*(wB*4+j) + (l&15);
        float uv = au[j][q] + vw0*bf2f(Xp[p])*bf2f(Bp[n]);
        Ugb[(size_t)blk*(HD*DS) + p*DS + n] = f2bf(uv);
      }
    }
  }
}

// ---------------- inter-chunk state scan (bf16 in-place, vectorized s16x8) ----------------
__global__ __launch_bounds__(256) void k_scan(u16* __restrict__ Ugb, const float* __restrict__ cdg){
  int idx = blockIdx.x*256 + threadIdx.x;     // 65536 threads
  int pn8 = (idx & 1023)*8;
  int h  = (idx >> 10) & 31;
  int b  = idx >> 15;
  float hs[8];
  #pragma unroll
  for (int e=0;e<8;e++) hs[e] = 0.f;
  for (int z=0;z<NC;z++){
    size_t o = ((size_t)((b*NC+z)*NH) + h)*(HD*DS) + pn8;
    s16x8 v = *(s16x8*)&Ugb[o];
    float cd = cdg[(b*NC+z)*NH + h];
    s16x8 wv;
    #pragma unroll
    for (int e=0;e<8;e++){
      float tmp = bf2f((u16)v[e]);
      wv[e] = (short)f2bf(hs[e]);
      hs[e] = cd*hs[e] + tmp;
    }
    *(s16x8*)&Ugb[o] = wv;
  }
}

// ---------------- k_state: 8-wave (512t) Ystate MFMA + Y RMW ----------------
__global__ __launch_bounds__(512) void k_state(
    const u16* __restrict__ Cn, const u16* __restrict__ Ugb,
    const float* __restrict__ Acumg, u16* __restrict__ Yb){
  __shared__ u16 Cs[64*128];
  __shared__ u16 Sb[64*128];
  __shared__ float eAs[64];
  int blk = blockIdx.x;
  int h = blk & 31, z = (blk>>5)&31, b = blk>>10;
  int l0 = z*CH;
  int tid = threadIdx.x;
  int l = tid & 63, w = tid >> 6;   // 8 waves
  int wA = w >> 1, wB = w & 1;

  if (tid < 64) eAs[tid] = expf(Acumg[(size_t)blk*CH + tid]);
  #pragma unroll
  for (int cc=0; cc<2; cc++){
    int c = w*2 + cc;
    int r = 4*c + (l>>4);
    gl_lds16(Cn + ((size_t)(b*LL + l0 + r)*NH + h)*DS + (((l&15)^(r&7))<<3), &Cs[4*c*128]);
    gl_lds16(Ugb + (size_t)blk*(HD*DS) + (size_t)r*DS + (((l&15)^(r&7))<<3), &Sb[4*c*128]);
  }
  __syncthreads();

  f32x4 as[2];
  const f32x4 vzero = {0.f,0.f,0.f,0.f};
  #pragma unroll
  for (int j=0;j<2;j++) as[j] = vzero;
  #pragma unroll
  for (int ks=0; ks<4; ks++){
    s16x8 af = ldswz(Cs, 16*wA + (l&15), ks*4 + (l>>4));
    #pragma unroll
    for (int j=0;j<2;j++){
      s16x8 bfr = ldswz(Sb, 16*(wB*2+j) + (l&15), ks*4 + (l>>4));
      as[j] = __builtin_amdgcn_mfma_f32_16x16x32_bf16(af, bfr, as[j], 0,0,0);
    }
  }
  #pragma unroll
  for (int j=0;j<2;j++){
    #pragma unroll
    for (int q=0;q<4;q++){
      int t = 16*wA + (l>>4)*4 + q;
      int p = 16*(wB*2+j) + (l&15);
      size_t idx = ((size_t)(b*LL + l0 + t))*DI + h*HD + p;
      Yb[idx] = f2bf(bf2f(Yb[idx]) + eAs[t]*as[j][q]);
    }
  }
}

// ---------------- generic MFMA NT GEMM, 8-wave (512t), XCD swizzle (out-proj) ----------------
template<int N, int K>
__global__ __launch_bounds__(512) void k_mfma_nt(const u16* __restrict__ A,
                                                 const u16* __restrict__ Bm,
                                                 float* __restrict__ C){
  __shared__ u16 lA[128*64];
  __shared__ u16 lB[128*64];
  int tid = threadIdx.x;
  int l = tid & 63, w = tid >> 6;
  int nwg = gridDim.x*gridDim.y;
  int flat = blockIdx.y*gridDim.x + blockIdx.x;
  int cpx = nwg >> 3;
  int swz = (flat & 7)*cpx + (flat >> 3);
  int bx = swz % gridDim.x, by = swz / gridDim.x;
  int bm = by*128, bn = bx*128;
  int wr = w >> 2, wc = w & 3;
  const f32x4 vzero = {0.f,0.f,0.f,0.f};
  f32x4 acc[4][2];
  #pragma unroll
  for (int i=0;i<4;i++)
    #pragma unroll
    for (int j=0;j<2;j++) acc[i][j] = vzero;

  for (int kt=0; kt<K; kt+=64){
    __syncthreads();
    #pragma unroll
    for (int cc=0; cc<2; cc++){
      int s = w*2 + cc;
      int uu = s*64 + l;
      int r = uu >> 3, jl = uu & 7;
      int j = jl ^ (r & 7);
      gl_lds16(A  + (size_t)(bm+r)*K + kt + j*8, &lA[s*512]);
      gl_lds16(Bm + (size_t)(bn+r)*K + kt + j*8, &lB[s*512]);
    }
    __syncthreads();
    #pragma unroll
    for (int ks=0; ks<2; ks++){
      s16x8 af[4], bf[2];
      #pragma unroll
      for (int i=0;i<4;i++){
        int row = wr*64 + i*16 + (l&15);
        int j = ks*4 + (l>>4);
        af[i] = *(const s16x8*)&lA[row*64 + (j^(row&7))*8];
      }
      #pragma unroll
      for (int i=0;i<2;i++){
        int row = wc*32 + i*16 + (l&15);
        int j = ks*4 + (l>>4);
        bf[i] = *(const s16x8*)&lB[row*64 + (j^(row&7))*8];
      }
      #pragma unroll
      for (int i=0;i<4;i++)
        #pragma unroll
        for (int jj=0;jj<2;jj++)
          acc[i][jj] = __builtin_amdgcn_mfma_f32_16x16x32_bf16(af[i], bf[jj], acc[i][jj], 0,0,0);
    }
  }
  int col0 = bn + wc*32 + (l&15);
  int row0 = bm + wr*64 + (l>>4)*4;
  #pragma unroll
  for (int i=0;i<4;i++)
    #pragma unroll
    for (int jj=0;jj<2;jj++)
      #pragma unroll
      for (int q=0;q<4;q++)
        C[(size_t)(row0 + i*16 + q)*N + col0 + jj*16] = acc[i][jj][q];
}

// ---------------- workspace layout (bytes) ----------------
constexpr size_t OFF_PAUX  = 0;            // 6,291,456
constexpr size_t OFF_XTG   = 6291456;      // 16,777,216
constexpr size_t OFF_BNR   = 23068672;     // 2,097,152
constexpr size_t OFF_CNR   = 25165824;     // 2,097,152
constexpr size_t OFF_DT    = 27262976;     // 524,288
constexpr size_t OFF_LA    = 27787264;     // 524,288
constexpr size_t OFF_W1    = 28311552;     // 524,288
constexpr size_t OFF_W2    = 28835840;     // 524,288
constexpr size_t OFF_SPART = 29360128;     // 262,144
constexpr size_t OFF_CV    = 29622272;     // 2,162,688
constexpr size_t OFF_ACUM  = 31784960;     // 524,288
constexpr size_t OFF_CD    = 32309248;     // 8,192
constexpr size_t OFF_THETA = 32317440;     // 16,777,216 ; overlaid by Yb
constexpr size_t OFF_Y     = OFF_THETA;
constexpr size_t OFF_BN    = 49094656;     // 33,554,432
constexpr size_t OFF_CN    = 82649088;     // 33,554,432
constexpr size_t OFF_BTW   = 116203520;    // 33,554,432
constexpr size_t OFF_R1    = 149757952;    // u_bf+Win_bf -> Ugb(33.55M)
constexpr size_t OFF_UBF   = OFF_R1;
constexpr size_t OFF_WINBF = OFF_R1 + 16777216;
constexpr size_t OFF_UGB   = OFF_R1;
constexpr size_t OFF_WOUTBF= 183312384;    // 4,194,304 (own region now)
// total = 187,506,688 bytes

extern "C" void kernel_launch(void* const* d_in, const int* in_sizes, int n_in,
                              void* d_out, int out_size, void* d_ws, size_t ws_size,
                              hipStream_t stream) {
  const float* u       = (const float*)d_in[0];
  const float* W_in    = (const float*)d_in[1];
  const float* dt_bias = (const float*)d_in[2];
  const float* B_bias  = (const float*)d_in[3];
  const float* C_bias  = (const float*)d_in[4];
  const float* Bnw     = (const float*)d_in[5];
  const float* Cnw     = (const float*)d_in[6];
  const float* Dg      = (const float*)d_in[7];
  const float* W_out   = (const float*)d_in[8];
  float* out = (float*)d_out;
  char* ws = (char*)d_ws;

  float* pAux  = (float*)(ws + OFF_PAUX);
  u16*   Xtg   = (u16*)  (ws + OFF_XTG);
  float* Bnr   = (float*)(ws + OFF_BNR);
  float* Cnr   = (float*)(ws + OFF_CNR);
  float* DTg   = (float*)(ws + OFF_DT);
  float* lag   = (float*)(ws + OFF_LA);
  float* w1g   = (float*)(ws + OFF_W1);
  float* w2g   = (float*)(ws + OFF_W2);
  float* Spart = (float*)(ws + OFF_SPART);
  float* CVp   = (float*)(ws + OFF_CV);
  float* Acumg = (float*)(ws + OFF_ACUM);
  float* cdg   = (float*)(ws + OFF_CD);
  float* Theta = (float*)(ws + OFF_THETA);
  u16*   Yb    = (u16*)  (ws + OFF_Y);
  u16*   Bn    = (u16*)  (ws + OFF_BN);
  u16*   Cn    = (u16*)  (ws + OFF_CN);
  u16*   BTw   = (u16*)  (ws + OFF_BTW);
  u16*   u_bf  = (u16*)  (ws + OFF_UBF);
  u16*   Win_bf= (u16*)  (ws + OFF_WINBF);
  u16*   Ugb   = (u16*)  (ws + OFF_UGB);
  u16*   Wout_bf=(u16*)  (ws + OFF_WOUTBF);

  k_cast3<<<(CQ1+CQ2+CQ3+255)/256, 256, 0, stream>>>(u, W_in, W_out, u_bf, Win_bf, Wout_bf);
  k_gemm_in<<<dim3(DIP/128, NTOK/128), 512, 0, stream>>>(u_bf, Win_bf, pAux, Xtg);

  k_prep      <<<NTOK/2, 256, 0, stream>>>(pAux, dt_bias, Bnw, Cnw, Bnr, Cnr, DTg, lag, w1g, w2g);
  k_theta_part<<<(BB*NC*NH)/2, 64, 0, stream>>>(pAux, DTg, Spart);
  k_theta_scan<<<(BB*NH*NR)/256, 256, 0, stream>>>(Spart);
  k_theta_full<<<(BB*NC*NH)/2, 64, 0, stream>>>(pAux, DTg, Spart, Theta);
  k_acum      <<<(BB*NC*NH)/4, 256, 0, stream>>>(lag, w1g, w2g, CVp, Acumg, cdg);
  k_rope2     <<<BB*NC*NH, 256, 0, stream>>>(Bnr, Cnr, Theta, B_bias, C_bias, CVp, Bn, Cn, BTw);

  k_chunk_a<<<BB*NC*NH, 512, 0, stream>>>(Xtg, Bn, Cn, BTw, CVp, Dg, Yb, Ugb);
  k_scan   <<<(BB*NH*HD*DS)/(256*8), 256, 0, stream>>>(Ugb, cdg);
  k_state  <<<BB*NC*NH, 512, 0, stream>>>(Cn, Ugb, Acumg, Yb);

  k_mfma_nt<DMODEL, DI><<<dim3(DMODEL/128, NTOK/128), 512, 0, stream>>>(Yb, Wout_bf, out);

  (void)in_sizes; (void)n_in; (void)out_size; (void)ws_size;
}

// Round 15
// 179.114 us; speedup vs baseline: 1.0904x; 1.0207x over previous
//
#include <hip/hip_runtime.h>
#include <hip/hip_bf16.h>
#include <math.h>

typedef unsigned short u16;
typedef __attribute__((ext_vector_type(8))) short s16x8;
typedef __attribute__((ext_vector_type(4))) float f32x4;

#define BB 2
#define LL 2048
#define DMODEL 1024
#define DI 2048
#define NH 32
#define HD 64
#define DS 128
#define NR 32
#define CH 64
#define NC 32
#define DIP 2432
#define NTOK (BB*LL)
#define PAW 384   // projAux width: cols 2048..2431 of proj
#define CVW 264   // per-chunk factor-table stride (floats)

__device__ __forceinline__ float bf2f(u16 u){ union{unsigned i; float f;} c; c.i=((unsigned)u)<<16; return c.f; }
__device__ __forceinline__ u16 f2bf(float f){ __hip_bfloat16 h=__float2bfloat16(f); return *reinterpret_cast<u16*>(&h); }
__device__ __forceinline__ float softplusf(float x){ return fmaxf(x,0.f) + log1pf(expf(-fabsf(x))); }

__device__ __forceinline__ void gl_lds16(const void* g, void* l){
  __builtin_amdgcn_global_load_lds((const __attribute__((address_space(1))) void*)g,
                                   (__attribute__((address_space(3))) void*)l, 16, 0, 0);
}

// swizzled [*][128] bf16 row (256B): 16B unit u at slot u^(r&7)
__device__ __forceinline__ s16x8 ldswz(const u16* base, int r, int kunit){
  return *(const s16x8*)&base[r*128 + ((kunit ^ (r&7))<<3)];
}
// swizzled [*][64] bf16 row (128B): unit u (0..7) at slot u^(r&7)
__device__ __forceinline__ s16x8 ldswz64(const u16* base, int r, int kunit){
  return *(const s16x8*)&base[r*64 + ((kunit ^ (r&7))<<3)];
}
__device__ __forceinline__ float ldswz64_s(const u16* base, int r, int n){
  return bf2f(base[r*64 + (((n>>3) ^ (r&7))<<3) + (n&7)]);
}
// plain stride-72 bf16 rows
__device__ __forceinline__ s16x8 ld72(const u16* base, int r, int kelem){
  return *(const s16x8*)&base[r*72 + kelem];
}

// ---------------- merged cast fp32 -> bf16 (u, W_in, W_out in one launch) ----------------
#define CQ1 ((NTOK*DMODEL)/4)
#define CQ2 ((DIP*DMODEL)/4)
#define CQ3 ((DMODEL*DI)/4)
__global__ __launch_bounds__(256) void k_cast3(const float* __restrict__ u, const float* __restrict__ Wi,
                                               const float* __restrict__ Wo,
                                               u16* __restrict__ ub, u16* __restrict__ wib,
                                               u16* __restrict__ wob){
  int i = blockIdx.x*256 + threadIdx.x;
  const float* src; u16* dst; int q;
  if (i < CQ1){ src = u; dst = ub; q = i; }
  else if (i < CQ1+CQ2){ src = Wi; dst = wib; q = i - CQ1; }
  else if (i < CQ1+CQ2+CQ3){ src = Wo; dst = wob; q = i - CQ1 - CQ2; }
  else return;
  float4 v = *(const float4*)&src[(size_t)q*4];
  ushort4 o; o.x=f2bf(v.x); o.y=f2bf(v.y); o.z=f2bf(v.z); o.w=f2bf(v.w);
  *(ushort4*)&dst[(size_t)q*4] = o;
}

// ---------------- in-proj GEMM, 8-wave (512t) 128x128 tile, split epilogue, XCD swizzle ----------------
__global__ __launch_bounds__(512) void k_gemm_in(const u16* __restrict__ A,
                                                 const u16* __restrict__ Bm,
                                                 float* __restrict__ pAux,
                                                 u16* __restrict__ Xtg){
  __shared__ u16 lA[128*64];
  __shared__ u16 lB[128*64];
  int tid = threadIdx.x;
  int l = tid & 63, w = tid >> 6;          // 8 waves
  int nwg = gridDim.x*gridDim.y;
  int flat = blockIdx.y*gridDim.x + blockIdx.x;
  int cpx = nwg >> 3;
  int swz = (flat & 7)*cpx + (flat >> 3);
  int bx = swz % gridDim.x, by = swz / gridDim.x;
  int bm = by*128, bn = bx*128;
  int wr = w >> 2, wc = w & 3;             // 2x4 wave grid: 64 rows x 32 cols per wave
  const f32x4 vzero = {0.f,0.f,0.f,0.f};
  f32x4 acc[4][2];
  #pragma unroll
  for (int i=0;i<4;i++)
    #pragma unroll
    for (int j=0;j<2;j++) acc[i][j] = vzero;

  for (int kt=0; kt<DMODEL; kt+=64){
    __syncthreads();
    #pragma unroll
    for (int cc=0; cc<2; cc++){
      int s = w*2 + cc;
      int uu = s*64 + l;
      int r = uu >> 3, jl = uu & 7;
      int j = jl ^ (r & 7);
      gl_lds16(A  + (size_t)(bm+r)*DMODEL + kt + j*8, &lA[s*512]);
      gl_lds16(Bm + (size_t)(bn+r)*DMODEL + kt + j*8, &lB[s*512]);
    }
    __syncthreads();
    #pragma unroll
    for (int ks=0; ks<2; ks++){
      s16x8 af[4], bf[2];
      #pragma unroll
      for (int i=0;i<4;i++){
        int row = wr*64 + i*16 + (l&15);
        int j = ks*4 + (l>>4);
        af[i] = *(const s16x8*)&lA[row*64 + (j^(row&7))*8];
      }
      #pragma unroll
      for (int i=0;i<2;i++){
        int row = wc*32 + i*16 + (l&15);
        int j = ks*4 + (l>>4);
        bf[i] = *(const s16x8*)&lB[row*64 + (j^(row&7))*8];
      }
      #pragma unroll
      for (int i=0;i<4;i++)
        #pragma unroll
        for (int jj=0;jj<2;jj++)
          acc[i][jj] = __builtin_amdgcn_mfma_f32_16x16x32_bf16(af[i], bf[jj], acc[i][jj], 0,0,0);
    }
  }
  int col0 = bn + wc*32 + (l&15);
  int row0 = bm + wr*64 + (l>>4)*4;
  if (bn < DI){
    int h = (bn + wc*32) >> 6;
    int pbase = (wc & 1)*32 + (l&15);
    int b = bm >> 11;
    #pragma unroll
    for (int i=0;i<4;i++){
      int lbase = (bm & (LL-1)) + wr*64 + (l>>4)*4 + i*16;
      #pragma unroll
      for (int jj=0;jj<2;jj++){
        int p = pbase + jj*16;
        ushort4 o;
        o.x = f2bf(acc[i][jj][0]); o.y = f2bf(acc[i][jj][1]);
        o.z = f2bf(acc[i][jj][2]); o.w = f2bf(acc[i][jj][3]);
        *(ushort4*)&Xtg[((size_t)(b*NH + h)*HD + p)*LL + lbase] = o;
      }
    }
  } else {
    #pragma unroll
    for (int i=0;i<4;i++)
      #pragma unroll
      for (int jj=0;jj<2;jj++)
        #pragma unroll
        for (int q=0;q<4;q++)
          pAux[(size_t)(row0 + i*16 + q)*PAW + col0 + jj*16 - DI] = acc[i][jj][q];
  }
}

// ---------------- per-token prep (2 rows/block) ----------------
__global__ __launch_bounds__(256) void k_prep(const float* __restrict__ pAux,
                                              const float* __restrict__ dt_bias,
                                              const float* __restrict__ Bnw,
                                              const float* __restrict__ Cnw,
                                              float* __restrict__ Bnr, float* __restrict__ Cnr,
                                              float* __restrict__ DTg, float* __restrict__ lag,
                                              float* __restrict__ w1g, float* __restrict__ w2g){
  int tid = threadIdx.x;
  int r = tid >> 7, t = tid & 127;
  int row = blockIdx.x*2 + r;
  const float* pr = pAux + (size_t)row*PAW;
  float bv = pr[t], cv = pr[128+t];
  float sb = bv*bv, sc = cv*cv;
  for (int o=32;o;o>>=1){ sb += __shfl_down(sb,o); sc += __shfl_down(sc,o); }
  __shared__ float red[8];
  if ((tid&63)==0){ red[(tid>>6)*2]=sb; red[(tid>>6)*2+1]=sc; }
  __syncthreads();
  float ssb = red[r*4]+red[r*4+2], ssc = red[r*4+1]+red[r*4+3];
  float rb = rsqrtf(ssb/DS + 1e-5f), rc = rsqrtf(ssc/DS + 1e-5f);
  Bnr[(size_t)row*DS+t] = bv*rb*Bnw[t];
  Cnr[(size_t)row*DS+t] = cv*rc*Cnw[t];
  if (t < NH){
    int h = t;
    float Av = -softplusf(pr[288+h]); Av = fminf(Av, -1e-4f);
    float DT = softplusf(pr[256+h] + dt_bias[h]);
    float la = Av*DT;
    float lam = 1.f/(1.f+expf(-pr[320+h]));
    DTg[row*NH+h] = DT;
    lag[row*NH+h] = la;
    w1g[row*NH+h] = DT*lam;
    w2g[row*NH+h] = DT*(1.f-lam)*expf(la);
  }
}

// ---------------- Theta cumsum, 3-phase (64-thread blocks) ----------------
__global__ __launch_bounds__(64) void k_theta_part(const float* __restrict__ pAux, const float* __restrict__ DTg,
                                                   float* __restrict__ Spart){
  int blk = blockIdx.x*2 + (threadIdx.x>>5);
  int j = threadIdx.x & 31;
  int h = blk % NH; int z = (blk/NH)%NC; int b = blk/(NH*NC);
  float acc = 0.f;
  for (int i=0;i<CH;i++){
    int row = b*LL + z*CH + i;
    acc += DTg[row*NH+h] * pAux[(size_t)row*PAW + 352 + j];
  }
  Spart[(size_t)blk*NR + j] = acc;
}

__global__ void k_theta_scan(float* __restrict__ Spart){
  int idx = blockIdx.x*blockDim.x + threadIdx.x;
  int j = idx % NR; int h = (idx/NR)%NH; int b = idx/(NR*NH);
  float acc = 0.f;
  for (int z=0;z<NC;z++){
    size_t o = (size_t)((b*NC+z)*NH + h)*NR + j;
    float t = Spart[o]; Spart[o] = acc; acc += t;
  }
}

__global__ __launch_bounds__(64) void k_theta_full(const float* __restrict__ pAux, const float* __restrict__ DTg,
                                                   const float* __restrict__ Spart, float* __restrict__ Theta){
  int blk = blockIdx.x*2 + (threadIdx.x>>5);
  int j = threadIdx.x & 31;
  int h = blk % NH; int z = (blk/NH)%NC; int b = blk/(NH*NC);
  float acc = Spart[(size_t)blk*NR + j];
  for (int i=0;i<CH;i++){
    int row = b*LL + z*CH + i;
    acc += DTg[row*NH+h] * pAux[(size_t)row*PAW + 352 + j];
    Theta[((size_t)row*NH + h)*NR + j] = acc;
  }
}

// ---------------- k_acum: per-chunk scan factors ----------------
__global__ __launch_bounds__(256) void k_acum(const float* __restrict__ lag,
                                              const float* __restrict__ w1g,
                                              const float* __restrict__ w2g,
                                              float* __restrict__ CV,
                                              float* __restrict__ Acumg,
                                              float* __restrict__ cdg){
  int blk = blockIdx.x*4 + (threadIdx.x>>6);
  int l = threadIdx.x & 63;
  int h = blk & 31, z = (blk>>5)&31, b = blk>>10;
  int row = b*LL + z*CH + l;
  float la = lag[row*NH+h], w1 = w1g[row*NH+h], w2 = w2g[row*NH+h];
  float a = la;
  #pragma unroll
  for (int o=1;o<64;o<<=1){ float t = __shfl_up(a,o); a += (l>=o) ? t : 0.f; }
  float Acm = __shfl(a, 31);
  float Alast = __shfl(a, 63);
  float eA = expf(a - Acm);
  float emA = expf(Acm - a);
  float rfac = expf(Alast - a);
  float rw1 = rfac*w1, rw2 = rfac*w2;
  float rw1p = __shfl_up(rw1, 1);
  float* cv = CV + (size_t)blk*CVW;
  cv[l] = eA;
  cv[64 + l] = emA*w1;          // G1[sp=l+1]
  cv[128 + l] = emA*w2;         // G2[sp=l]
  cv[192 + l] = (l>0 ? rw1p : 0.f) + rw2;   // vw[l]
  if (l == 63){ cv[192+64] = rw1; cdg[blk] = expf(Alast); }
  Acumg[(size_t)blk*CH + l] = a;
}

// ---------------- k_rope2 v4: Bn/Cn only (no BTw, no LDS transpose) ----------------
__global__ __launch_bounds__(256) void k_rope2(const float* __restrict__ Bnr,
                                               const float* __restrict__ Cnr,
                                               const float* __restrict__ Theta,
                                               const float* __restrict__ B_bias,
                                               const float* __restrict__ C_bias,
                                               u16* __restrict__ Bn, u16* __restrict__ Cn){
  int blk = blockIdx.x; int h = blk&31, z=(blk>>5)&31, b=blk>>10;
  int l0 = z*CH; int tid = threadIdx.x;
  const float* bb = B_bias + h*DS;
  const float* cb = C_bias + h*DS;
  #pragma unroll
  for (int it=0; it<8; it++){
    int idx = it*256 + tid;
    int r = idx>>5, j = idx&31;      // r = 0..63, j = 0..31
    int row = b*LL + l0 + r;
    const float* br = Bnr + (size_t)row*DS;
    const float* cr = Cnr + (size_t)row*DS;
    float th = Theta[((size_t)row*NH + h)*NR + j];
    float cs = cosf(th), sn = sinf(th);
    float b0 = br[j]    + bb[j];
    float b1 = br[j+32] + bb[j+32];
    float b2 = br[j+64] + bb[j+64];
    float b3 = br[j+96] + bb[j+96];
    float c0 = cr[j]    + cb[j];
    float c1 = cr[j+32] + cb[j+32];
    float c2 = cr[j+64] + cb[j+64];
    float c3 = cr[j+96] + cb[j+96];
    float obA = b0*cs - b1*sn, obB = b0*sn + b1*cs;
    float ocA = c0*cs - c1*sn, ocB = c0*sn + c1*cs;
    u16* bnp = Bn + ((size_t)row*NH + h)*DS;
    u16* cnp = Cn + ((size_t)row*NH + h)*DS;
    bnp[j]    = f2bf(obA); bnp[j+32] = f2bf(obB);
    bnp[j+64] = f2bf(b2);  bnp[j+96] = f2bf(b3);
    cnp[j]    = f2bf(ocA); cnp[j+32] = f2bf(ocB);
    cnp[j+64] = f2bf(c2);  cnp[j+96] = f2bf(c3);
  }
}

// ---------------- k_chunk_a: 8-wave (512t) CB -> Mc + Bt(in-LDS transpose) -> Yintra, U ----------------
__global__ __launch_bounds__(512) void k_chunk_a(
    const u16* __restrict__ Xtg, const u16* __restrict__ Bn,
    const u16* __restrict__ Cn,
    const float* __restrict__ CV, const float* __restrict__ Dgl,
    u16* __restrict__ Yb, u16* __restrict__ Ugb){
  __shared__ u16 BsBT[65*128];     // Bs rows 0..64 (CB); rows 0..63 later overlaid by Bt [128][64] swz64
  __shared__ u16 CsMc[64*128];     // Cs swizzled -> Mc[64][72] overlay
  __shared__ u16 Xt64[64*64];      // X^T [p][k], k = s'-1
  __shared__ u16 Bp[128], Xp[64];
  __shared__ float cvS[260];
  __shared__ float mc0s[64];
  int blk = blockIdx.x;
  int h = blk&31, z=(blk>>5)&31, b=blk>>10;
  int l0 = z*CH;
  int tid = threadIdx.x; int l = tid&63, w = tid>>6;    // 8 waves
  int wA = w >> 1, wB = w & 1;
  size_t bh = (size_t)(b*NH + h);

  // ---- phase 0: staging ----
  if (tid < 128){
    u16 v = 0;
    if (z > 0) v = Bn[((size_t)(b*LL+l0-1)*NH + h)*DS + tid];
    BsBT[tid] = v; Bp[tid] = v;
  } else if (tid < 192){
    int p = tid - 128;
    u16 v = 0;
    if (z > 0) v = Xtg[(bh*HD + p)*LL + l0 - 1];
    Xp[p] = v;
  }
  if (tid < 257) cvS[tid] = CV[(size_t)blk*CVW + tid];
  #pragma unroll
  for (int cc=0; cc<2; cc++){
    int c = w*2 + cc;
    { int r = 1 + 4*c + (l>>4);
      gl_lds16(Bn + ((size_t)(b*LL+l0+r-1)*NH+h)*DS + (((l&15)^(r&7))<<3), &BsBT[(1+4*c)*128]); }
    { int r = 4*c + (l>>4);
      gl_lds16(Cn + ((size_t)(b*LL+l0+r)*NH+h)*DS + (((l&15)^(r&7))<<3), &CsMc[4*c*128]); }
  }
  {
    int uu = w*64 + l; int r = uu>>3, jl = uu&7, j = jl^(r&7);
    gl_lds16(Xtg + (bh*HD + r)*LL + l0 + j*8, &Xt64[w*512]);
  }
  __syncthreads();

  // ---- phase 1: CB GEMM over Bs rows 1..64 (2 tiles/wave); mc0 matvec ----
  const f32x4 vzero = {0.f,0.f,0.f,0.f};
  f32x4 acb[2];
  #pragma unroll
  for (int j=0;j<2;j++) acb[j] = vzero;
  #pragma unroll
  for (int ks=0; ks<4; ks++){
    s16x8 af = ldswz(CsMc, 16*wA + (l&15), ks*4 + (l>>4));
    #pragma unroll
    for (int j=0;j<2;j++){
      s16x8 bfr = ldswz(BsBT, 1 + 16*(wB*2+j) + (l&15), ks*4 + (l>>4));
      acb[j] = __builtin_amdgcn_mfma_f32_16x16x32_bf16(af, bfr, acb[j], 0,0,0);
    }
  }
  {
    int t = tid>>3, part = tid&7;
    float s = 0.f;
    #pragma unroll
    for (int uu=0; uu<2; uu++){
      int u = part*2 + uu;
      s16x8 cr = *(const s16x8*)&CsMc[t*128 + ((u^(t&7))<<3)];
      s16x8 br = *(const s16x8*)&BsBT[u<<3];   // row 0, identity swizzle
      #pragma unroll
      for (int e=0;e<8;e++) s += bf2f(cr[e])*bf2f(br[e]);
    }
    s += __shfl_xor(s, 1); s += __shfl_xor(s, 2); s += __shfl_xor(s, 4);
    if (part == 0) mc0s[t] = s * cvS[t] * cvS[128];   // CB[t][0]*eA[t]*G2[0]
  }
  __syncthreads();

  // ---- phase 2a: transpose-source reads (Bs rows 1..64 -> regs) + build Mc' ----
  u16 tv[16];
  #pragma unroll
  for (int it=0; it<16; it++){
    int i = it*512 + tid;         // 0..8191
    int n = i & 127, k = i >> 7;  // k = 0..63
    int r = k + 1;
    tv[it] = BsBT[r*128 + ((((n>>3) ^ (r&7))<<3) | (n&7))];
  }
  #pragma unroll
  for (int j=0;j<2;j++){
    #pragma unroll
    for (int q=0;q<4;q++){
      int t = 16*wA + (l>>4)*4 + q;
      int k = 16*(wB*2+j) + (l&15);
      int sp = k + 1;
      float g = 0.f;
      if (sp <= t+1) g += cvS[63+sp];
      if (sp <= t)   g += cvS[128+sp];
      g *= cvS[t];
      CsMc[t*72 + k] = f2bf(acb[j][q] * g);
    }
  }
  __syncthreads();

  // ---- phase 2b: Bt writes (overlay Bs rows 0..63): Bt[n][k] = Bs[k+1][n]*vw[k+1], swz64 layout ----
  #pragma unroll
  for (int it=0; it<16; it++){
    int i = it*512 + tid;
    int n = i & 127, k = i >> 7;
    float v = bf2f(tv[it]) * cvS[192 + k + 1];
    BsBT[n*64 + ((((k>>3) ^ (n&7))<<3) | (k&7))] = f2bf(v);
  }
  __syncthreads();

  // ---- phase 3: Yintra = Mc' @ Xt64^T + mc0 x Xp + D*x (2 tiles/wave); write Yb ----
  f32x4 ay[2];
  #pragma unroll
  for (int j=0;j<2;j++) ay[j] = vzero;
  #pragma unroll
  for (int ks=0; ks<2; ks++){
    s16x8 af = ld72(CsMc, 16*wA + (l&15), ks*32 + (l>>4)*8);
    #pragma unroll
    for (int j=0;j<2;j++){
      s16x8 bfr = ldswz64(Xt64, 16*(wB*2+j) + (l&15), ks*4 + (l>>4));
      ay[j] = __builtin_amdgcn_mfma_f32_16x16x32_bf16(af, bfr, ay[j], 0,0,0);
    }
  }
  {
    float Dh = Dgl[h];
    #pragma unroll
    for (int j=0;j<2;j++){
      #pragma unroll
      for (int q=0;q<4;q++){
        int t = 16*wA + (l>>4)*4 + q;
        int p = 16*(wB*2+j) + (l&15);
        float xval = ldswz64_s(Xt64, p, t);
        float yv = ay[j][q] + mc0s[t]*bf2f(Xp[p]) + Dh*xval;
        Yb[((size_t)(b*LL + l0 + t))*DI + h*HD + p] = f2bf(yv);
      }
    }
  }

  // ---- phase 4: U = Xt64 @ Bt^T (4 tiles/wave, + rank-1 sp=0 fixup); write Ugb ----
  f32x4 au[4];
  #pragma unroll
  for (int j=0;j<4;j++) au[j] = vzero;
  #pragma unroll
  for (int ks=0; ks<2; ks++){
    s16x8 af = ldswz64(Xt64, 16*wA + (l&15), ks*4 + (l>>4));
    #pragma unroll
    for (int j=0;j<4;j++){
      s16x8 bfr = ldswz64(BsBT, 16*(wB*4+j) + (l&15), ks*4 + (l>>4));
      au[j] = __builtin_amdgcn_mfma_f32_16x16x32_bf16(af, bfr, au[j], 0,0,0);
    }
  }
  {
    float vw0 = cvS[192];
    #pragma unroll
    for (int j=0;j<4;j++){
      #pragma unroll
      for (int q=0;q<4;q++){
        int p = 16*wA + (l>>4)*4 + q;
        int n = 16*(wB*4+j) + (l&15);
        float uv = au[j][q] + vw0*bf2f(Xp[p])*bf2f(Bp[n]);
        Ugb[(size_t)blk*(HD*DS) + p*DS + n] = f2bf(uv);
      }
    }
  }
}

// ---------------- inter-chunk state scan (bf16 in-place, vectorized s16x8) ----------------
__global__ __launch_bounds__(256) void k_scan(u16* __restrict__ Ugb, const float* __restrict__ cdg){
  int idx = blockIdx.x*256 + threadIdx.x;     // 65536 threads
  int pn8 = (idx & 1023)*8;
  int h  = (idx >> 10) & 31;
  int b  = idx >> 15;
  float hs[8];
  #pragma unroll
  for (int e=0;e<8;e++) hs[e] = 0.f;
  for (int z=0;z<NC;z++){
    size_t o = ((size_t)((b*NC+z)*NH) + h)*(HD*DS) + pn8;
    s16x8 v = *(s16x8*)&Ugb[o];
    float cd = cdg[(b*NC+z)*NH + h];
    s16x8 wv;
    #pragma unroll
    for (int e=0;e<8;e++){
      float tmp = bf2f((u16)v[e]);
      wv[e] = (short)f2bf(hs[e]);
      hs[e] = cd*hs[e] + tmp;
    }
    *(s16x8*)&Ugb[o] = wv;
  }
}

// ---------------- k_state: 8-wave (512t) Ystate MFMA + Y RMW ----------------
__global__ __launch_bounds__(512) void k_state(
    const u16* __restrict__ Cn, const u16* __restrict__ Ugb,
    const float* __restrict__ Acumg, u16* __restrict__ Yb){
  __shared__ u16 Cs[64*128];
  __shared__ u16 Sb[64*128];
  __shared__ float eAs[64];
  int blk = blockIdx.x;
  int h = blk & 31, z = (blk>>5)&31, b = blk>>10;
  int l0 = z*CH;
  int tid = threadIdx.x;
  int l = tid & 63, w = tid >> 6;   // 8 waves
  int wA = w >> 1, wB = w & 1;

  if (tid < 64) eAs[tid] = expf(Acumg[(size_t)blk*CH + tid]);
  #pragma unroll
  for (int cc=0; cc<2; cc++){
    int c = w*2 + cc;
    int r = 4*c + (l>>4);
    gl_lds16(Cn + ((size_t)(b*LL + l0 + r)*NH + h)*DS + (((l&15)^(r&7))<<3), &Cs[4*c*128]);
    gl_lds16(Ugb + (size_t)blk*(HD*DS) + (size_t)r*DS + (((l&15)^(r&7))<<3), &Sb[4*c*128]);
  }
  __syncthreads();

  f32x4 as[2];
  const f32x4 vzero = {0.f,0.f,0.f,0.f};
  #pragma unroll
  for (int j=0;j<2;j++) as[j] = vzero;
  #pragma unroll
  for (int ks=0; ks<4; ks++){
    s16x8 af = ldswz(Cs, 16*wA + (l&15), ks*4 + (l>>4));
    #pragma unroll
    for (int j=0;j<2;j++){
      s16x8 bfr = ldswz(Sb, 16*(wB*2+j) + (l&15), ks*4 + (l>>4));
      as[j] = __builtin_amdgcn_mfma_f32_16x16x32_bf16(af, bfr, as[j], 0,0,0);
    }
  }
  #pragma unroll
  for (int j=0;j<2;j++){
    #pragma unroll
    for (int q=0;q<4;q++){
      int t = 16*wA + (l>>4)*4 + q;
      int p = 16*(wB*2+j) + (l&15);
      size_t idx = ((size_t)(b*LL + l0 + t))*DI + h*HD + p;
      Yb[idx] = f2bf(bf2f(Yb[idx]) + eAs[t]*as[j][q]);
    }
  }
}

// ---------------- generic MFMA NT GEMM, 8-wave (512t), XCD swizzle (out-proj) ----------------
template<int N, int K>
__global__ __launch_bounds__(512) void k_mfma_nt(const u16* __restrict__ A,
                                                 const u16* __restrict__ Bm,
                                                 float* __restrict__ C){
  __shared__ u16 lA[128*64];
  __shared__ u16 lB[128*64];
  int tid = threadIdx.x;
  int l = tid & 63, w = tid >> 6;
  int nwg = gridDim.x*gridDim.y;
  int flat = blockIdx.y*gridDim.x + blockIdx.x;
  int cpx = nwg >> 3;
  int swz = (flat & 7)*cpx + (flat >> 3);
  int bx = swz % gridDim.x, by = swz / gridDim.x;
  int bm = by*128, bn = bx*128;
  int wr = w >> 2, wc = w & 3;
  const f32x4 vzero = {0.f,0.f,0.f,0.f};
  f32x4 acc[4][2];
  #pragma unroll
  for (int i=0;i<4;i++)
    #pragma unroll
    for (int j=0;j<2;j++) acc[i][j] = vzero;

  for (int kt=0; kt<K; kt+=64){
    __syncthreads();
    #pragma unroll
    for (int cc=0; cc<2; cc++){
      int s = w*2 + cc;
      int uu = s*64 + l;
      int r = uu >> 3, jl = uu & 7;
      int j = jl ^ (r & 7);
      gl_lds16(A  + (size_t)(bm+r)*K + kt + j*8, &lA[s*512]);
      gl_lds16(Bm + (size_t)(bn+r)*K + kt + j*8, &lB[s*512]);
    }
    __syncthreads();
    #pragma unroll
    for (int ks=0; ks<2; ks++){
      s16x8 af[4], bf[2];
      #pragma unroll
      for (int i=0;i<4;i++){
        int row = wr*64 + i*16 + (l&15);
        int j = ks*4 + (l>>4);
        af[i] = *(const s16x8*)&lA[row*64 + (j^(row&7))*8];
      }
      #pragma unroll
      for (int i=0;i<2;i++){
        int row = wc*32 + i*16 + (l&15);
        int j = ks*4 + (l>>4);
        bf[i] = *(const s16x8*)&lB[row*64 + (j^(row&7))*8];
      }
      #pragma unroll
      for (int i=0;i<4;i++)
        #pragma unroll
        for (int jj=0;jj<2;jj++)
          acc[i][jj] = __builtin_amdgcn_mfma_f32_16x16x32_bf16(af[i], bf[jj], acc[i][jj], 0,0,0);
    }
  }
  int col0 = bn + wc*32 + (l&15);
  int row0 = bm + wr*64 + (l>>4)*4;
  #pragma unroll
  for (int i=0;i<4;i++)
    #pragma unroll
    for (int jj=0;jj<2;jj++)
      #pragma unroll
      for (int q=0;q<4;q++)
        C[(size_t)(row0 + i*16 + q)*N + col0 + jj*16] = acc[i][jj][q];
}

// ---------------- workspace layout (bytes) ----------------
constexpr size_t OFF_PAUX  = 0;            // 6,291,456
constexpr size_t OFF_XTG   = 6291456;      // 16,777,216
constexpr size_t OFF_BNR   = 23068672;     // 2,097,152
constexpr size_t OFF_CNR   = 25165824;     // 2,097,152
constexpr size_t OFF_DT    = 27262976;     // 524,288
constexpr size_t OFF_LA    = 27787264;     // 524,288
constexpr size_t OFF_W1    = 28311552;     // 524,288
constexpr size_t OFF_W2    = 28835840;     // 524,288
constexpr size_t OFF_SPART = 29360128;     // 262,144
constexpr size_t OFF_CV    = 29622272;     // 2,162,688
constexpr size_t OFF_ACUM  = 31784960;     // 524,288
constexpr size_t OFF_CD    = 32309248;     // 8,192
constexpr size_t OFF_THETA = 32317440;     // 16,777,216 ; overlaid by Yb
constexpr size_t OFF_Y     = OFF_THETA;
constexpr size_t OFF_BN    = 49094656;     // 33,554,432
constexpr size_t OFF_CN    = 82649088;     // 33,554,432
constexpr size_t OFF_R1    = 149757952;    // u_bf+Win_bf -> Ugb(33.55M)
constexpr size_t OFF_UBF   = OFF_R1;
constexpr size_t OFF_WINBF = OFF_R1 + 16777216;
constexpr size_t OFF_UGB   = OFF_R1;
constexpr size_t OFF_WOUTBF= 183312384;    // 4,194,304
// total = 187,506,688 bytes

extern "C" void kernel_launch(void* const* d_in, const int* in_sizes, int n_in,
                              void* d_out, int out_size, void* d_ws, size_t ws_size,
                              hipStream_t stream) {
  const float* u       = (const float*)d_in[0];
  const float* W_in    = (const float*)d_in[1];
  const float* dt_bias = (const float*)d_in[2];
  const float* B_bias  = (const float*)d_in[3];
  const float* C_bias  = (const float*)d_in[4];
  const float* Bnw     = (const float*)d_in[5];
  const float* Cnw     = (const float*)d_in[6];
  const float* Dg      = (const float*)d_in[7];
  const float* W_out   = (const float*)d_in[8];
  float* out = (float*)d_out;
  char* ws = (char*)d_ws;

  float* pAux  = (float*)(ws + OFF_PAUX);
  u16*   Xtg   = (u16*)  (ws + OFF_XTG);
  float* Bnr   = (float*)(ws + OFF_BNR);
  float* Cnr   = (float*)(ws + OFF_CNR);
  float* DTg   = (float*)(ws + OFF_DT);
  float* lag   = (float*)(ws + OFF_LA);
  float* w1g   = (float*)(ws + OFF_W1);
  float* w2g   = (float*)(ws + OFF_W2);
  float* Spart = (float*)(ws + OFF_SPART);
  float* CVp   = (float*)(ws + OFF_CV);
  float* Acumg = (float*)(ws + OFF_ACUM);
  float* cdg   = (float*)(ws + OFF_CD);
  float* Theta = (float*)(ws + OFF_THETA);
  u16*   Yb    = (u16*)  (ws + OFF_Y);
  u16*   Bn    = (u16*)  (ws + OFF_BN);
  u16*   Cn    = (u16*)  (ws + OFF_CN);
  u16*   u_bf  = (u16*)  (ws + OFF_UBF);
  u16*   Win_bf= (u16*)  (ws + OFF_WINBF);
  u16*   Ugb   = (u16*)  (ws + OFF_UGB);
  u16*   Wout_bf=(u16*)  (ws + OFF_WOUTBF);

  k_cast3<<<(CQ1+CQ2+CQ3+255)/256, 256, 0, stream>>>(u, W_in, W_out, u_bf, Win_bf, Wout_bf);
  k_gemm_in<<<dim3(DIP/128, NTOK/128), 512, 0, stream>>>(u_bf, Win_bf, pAux, Xtg);

  k_prep      <<<NTOK/2, 256, 0, stream>>>(pAux, dt_bias, Bnw, Cnw, Bnr, Cnr, DTg, lag, w1g, w2g);
  k_theta_part<<<(BB*NC*NH)/2, 64, 0, stream>>>(pAux, DTg, Spart);
  k_theta_scan<<<(BB*NH*NR)/256, 256, 0, stream>>>(Spart);
  k_theta_full<<<(BB*NC*NH)/2, 64, 0, stream>>>(pAux, DTg, Spart, Theta);
  k_acum      <<<(BB*NC*NH)/4, 256, 0, stream>>>(lag, w1g, w2g, CVp, Acumg, cdg);
  k_rope2     <<<BB*NC*NH, 256, 0, stream>>>(Bnr, Cnr, Theta, B_bias, C_bias, Bn, Cn);

  k_chunk_a<<<BB*NC*NH, 512, 0, stream>>>(Xtg, Bn, Cn, CVp, Dg, Yb, Ugb);
  k_scan   <<<(BB*NH*HD*DS)/(256*8), 256, 0, stream>>>(Ugb, cdg);
  k_state  <<<BB*NC*NH, 512, 0, stream>>>(Cn, Ugb, Acumg, Yb);

  k_mfma_nt<DMODEL, DI><<<dim3(DMODEL/128, NTOK/128), 512, 0, stream>>>(Yb, Wout_bf, out);

  (void)in_sizes; (void)n_in; (void)out_size; (void)ws_size;
}

// Round 16
// 166.933 us; speedup vs baseline: 1.1700x; 1.0730x over previous
//
#include <hip/hip_runtime.h>
#include <hip/hip_bf16.h>
#include <math.h>

typedef unsigned short u16;
typedef __attribute__((ext_vector_type(8))) short s16x8;
typedef __attribute__((ext_vector_type(4))) float f32x4;

#define BB 2
#define LL 2048
#define DMODEL 1024
#define DI 2048
#define NH 32
#define HD 64
#define DS 128
#define NR 32
#define CH 64
#define NC 32
#define DIP 2432
#define NTOK (BB*LL)
#define PAW 384   // projAux width: cols 2048..2431 of proj
#define CVW 264   // per-chunk factor-table stride (floats)

__device__ __forceinline__ float bf2f(u16 u){ union{unsigned i; float f;} c; c.i=((unsigned)u)<<16; return c.f; }
__device__ __forceinline__ u16 f2bf(float f){ __hip_bfloat16 h=__float2bfloat16(f); return *reinterpret_cast<u16*>(&h); }
__device__ __forceinline__ float softplusf(float x){ return fmaxf(x,0.f) + log1pf(expf(-fabsf(x))); }

__device__ __forceinline__ void gl_lds16(const void* g, void* l){
  __builtin_amdgcn_global_load_lds((const __attribute__((address_space(1))) void*)g,
                                   (__attribute__((address_space(3))) void*)l, 16, 0, 0);
}

// swizzled [*][128] bf16 row (256B): 16B unit u at slot u^(r&7)
__device__ __forceinline__ s16x8 ldswz(const u16* base, int r, int kunit){
  return *(const s16x8*)&base[r*128 + ((kunit ^ (r&7))<<3)];
}
// swizzled [*][64] bf16 row (128B): unit u (0..7) at slot u^(r&7)
__device__ __forceinline__ s16x8 ldswz64(const u16* base, int r, int kunit){
  return *(const s16x8*)&base[r*64 + ((kunit ^ (r&7))<<3)];
}
__device__ __forceinline__ float ldswz64_s(const u16* base, int r, int n){
  return bf2f(base[r*64 + (((n>>3) ^ (r&7))<<3) + (n&7)]);
}
// plain stride-72 bf16 rows
__device__ __forceinline__ s16x8 ld72(const u16* base, int r, int kelem){
  return *(const s16x8*)&base[r*72 + kelem];
}

// ---------------- merged cast fp32 -> bf16 (u, W_in, W_out in one launch) ----------------
#define CQ1 ((NTOK*DMODEL)/4)
#define CQ2 ((DIP*DMODEL)/4)
#define CQ3 ((DMODEL*DI)/4)
__global__ __launch_bounds__(256) void k_cast3(const float* __restrict__ u, const float* __restrict__ Wi,
                                               const float* __restrict__ Wo,
                                               u16* __restrict__ ub, u16* __restrict__ wib,
                                               u16* __restrict__ wob){
  int i = blockIdx.x*256 + threadIdx.x;
  const float* src; u16* dst; int q;
  if (i < CQ1){ src = u; dst = ub; q = i; }
  else if (i < CQ1+CQ2){ src = Wi; dst = wib; q = i - CQ1; }
  else if (i < CQ1+CQ2+CQ3){ src = Wo; dst = wob; q = i - CQ1 - CQ2; }
  else return;
  float4 v = *(const float4*)&src[(size_t)q*4];
  ushort4 o; o.x=f2bf(v.x); o.y=f2bf(v.y); o.z=f2bf(v.z); o.w=f2bf(v.w);
  *(ushort4*)&dst[(size_t)q*4] = o;
}

// ---------------- in-proj GEMM, 8-wave (512t) 128x128 tile, split epilogue, XCD swizzle ----------------
__global__ __launch_bounds__(512) void k_gemm_in(const u16* __restrict__ A,
                                                 const u16* __restrict__ Bm,
                                                 float* __restrict__ pAux,
                                                 u16* __restrict__ Xtg){
  __shared__ u16 lA[128*64];
  __shared__ u16 lB[128*64];
  int tid = threadIdx.x;
  int l = tid & 63, w = tid >> 6;          // 8 waves
  int nwg = gridDim.x*gridDim.y;
  int flat = blockIdx.y*gridDim.x + blockIdx.x;
  int cpx = nwg >> 3;
  int swz = (flat & 7)*cpx + (flat >> 3);
  int bx = swz % gridDim.x, by = swz / gridDim.x;
  int bm = by*128, bn = bx*128;
  int wr = w >> 2, wc = w & 3;             // 2x4 wave grid: 64 rows x 32 cols per wave
  const f32x4 vzero = {0.f,0.f,0.f,0.f};
  f32x4 acc[4][2];
  #pragma unroll
  for (int i=0;i<4;i++)
    #pragma unroll
    for (int j=0;j<2;j++) acc[i][j] = vzero;

  for (int kt=0; kt<DMODEL; kt+=64){
    __syncthreads();
    #pragma unroll
    for (int cc=0; cc<2; cc++){
      int s = w*2 + cc;
      int uu = s*64 + l;
      int r = uu >> 3, jl = uu & 7;
      int j = jl ^ (r & 7);
      gl_lds16(A  + (size_t)(bm+r)*DMODEL + kt + j*8, &lA[s*512]);
      gl_lds16(Bm + (size_t)(bn+r)*DMODEL + kt + j*8, &lB[s*512]);
    }
    __syncthreads();
    #pragma unroll
    for (int ks=0; ks<2; ks++){
      s16x8 af[4], bf[2];
      #pragma unroll
      for (int i=0;i<4;i++){
        int row = wr*64 + i*16 + (l&15);
        int j = ks*4 + (l>>4);
        af[i] = *(const s16x8*)&lA[row*64 + (j^(row&7))*8];
      }
      #pragma unroll
      for (int i=0;i<2;i++){
        int row = wc*32 + i*16 + (l&15);
        int j = ks*4 + (l>>4);
        bf[i] = *(const s16x8*)&lB[row*64 + (j^(row&7))*8];
      }
      #pragma unroll
      for (int i=0;i<4;i++)
        #pragma unroll
        for (int jj=0;jj<2;jj++)
          acc[i][jj] = __builtin_amdgcn_mfma_f32_16x16x32_bf16(af[i], bf[jj], acc[i][jj], 0,0,0);
    }
  }
  int col0 = bn + wc*32 + (l&15);
  int row0 = bm + wr*64 + (l>>4)*4;
  if (bn < DI){
    int h = (bn + wc*32) >> 6;
    int pbase = (wc & 1)*32 + (l&15);
    int b = bm >> 11;
    #pragma unroll
    for (int i=0;i<4;i++){
      int lbase = (bm & (LL-1)) + wr*64 + (l>>4)*4 + i*16;
      #pragma unroll
      for (int jj=0;jj<2;jj++){
        int p = pbase + jj*16;
        ushort4 o;
        o.x = f2bf(acc[i][jj][0]); o.y = f2bf(acc[i][jj][1]);
        o.z = f2bf(acc[i][jj][2]); o.w = f2bf(acc[i][jj][3]);
        *(ushort4*)&Xtg[((size_t)(b*NH + h)*HD + p)*LL + lbase] = o;
      }
    }
  } else {
    #pragma unroll
    for (int i=0;i<4;i++)
      #pragma unroll
      for (int jj=0;jj<2;jj++)
        #pragma unroll
        for (int q=0;q<4;q++)
          pAux[(size_t)(row0 + i*16 + q)*PAW + col0 + jj*16 - DI] = acc[i][jj][q];
  }
}

// ---------------- per-token prep (2 rows/block) ----------------
__global__ __launch_bounds__(256) void k_prep(const float* __restrict__ pAux,
                                              const float* __restrict__ dt_bias,
                                              const float* __restrict__ Bnw,
                                              const float* __restrict__ Cnw,
                                              float* __restrict__ Bnr, float* __restrict__ Cnr,
                                              float* __restrict__ DTg, float* __restrict__ lag,
                                              float* __restrict__ w1g, float* __restrict__ w2g){
  int tid = threadIdx.x;
  int r = tid >> 7, t = tid & 127;
  int row = blockIdx.x*2 + r;
  const float* pr = pAux + (size_t)row*PAW;
  float bv = pr[t], cv = pr[128+t];
  float sb = bv*bv, sc = cv*cv;
  for (int o=32;o;o>>=1){ sb += __shfl_down(sb,o); sc += __shfl_down(sc,o); }
  __shared__ float red[8];
  if ((tid&63)==0){ red[(tid>>6)*2]=sb; red[(tid>>6)*2+1]=sc; }
  __syncthreads();
  float ssb = red[r*4]+red[r*4+2], ssc = red[r*4+1]+red[r*4+3];
  float rb = rsqrtf(ssb/DS + 1e-5f), rc = rsqrtf(ssc/DS + 1e-5f);
  Bnr[(size_t)row*DS+t] = bv*rb*Bnw[t];
  Cnr[(size_t)row*DS+t] = cv*rc*Cnw[t];
  if (t < NH){
    int h = t;
    float Av = -softplusf(pr[288+h]); Av = fminf(Av, -1e-4f);
    float DT = softplusf(pr[256+h] + dt_bias[h]);
    float la = Av*DT;
    float lam = 1.f/(1.f+expf(-pr[320+h]));
    DTg[row*NH+h] = DT;
    lag[row*NH+h] = la;
    w1g[row*NH+h] = DT*lam;
    w2g[row*NH+h] = DT*(1.f-lam)*expf(la);
  }
}

// ---------------- Theta partials + cross-chunk scan (Spart becomes exclusive prefix) ----------------
__global__ __launch_bounds__(64) void k_theta_part(const float* __restrict__ pAux, const float* __restrict__ DTg,
                                                   float* __restrict__ Spart){
  int blk = blockIdx.x*2 + (threadIdx.x>>5);
  int j = threadIdx.x & 31;
  int h = blk % NH; int z = (blk/NH)%NC; int b = blk/(NH*NC);
  float acc = 0.f;
  for (int i=0;i<CH;i++){
    int row = b*LL + z*CH + i;
    acc += DTg[row*NH+h] * pAux[(size_t)row*PAW + 352 + j];
  }
  Spart[(size_t)blk*NR + j] = acc;
}

__global__ void k_theta_scan(float* __restrict__ Spart){
  int idx = blockIdx.x*blockDim.x + threadIdx.x;
  int j = idx % NR; int h = (idx/NR)%NH; int b = idx/(NR*NH);
  float acc = 0.f;
  for (int z=0;z<NC;z++){
    size_t o = (size_t)((b*NC+z)*NH + h)*NR + j;
    float t = Spart[o]; Spart[o] = acc; acc += t;
  }
}

// ---------------- k_acum: per-chunk scan factors ----------------
__global__ __launch_bounds__(256) void k_acum(const float* __restrict__ lag,
                                              const float* __restrict__ w1g,
                                              const float* __restrict__ w2g,
                                              float* __restrict__ CV,
                                              float* __restrict__ Acumg,
                                              float* __restrict__ cdg){
  int blk = blockIdx.x*4 + (threadIdx.x>>6);
  int l = threadIdx.x & 63;
  int h = blk & 31, z = (blk>>5)&31, b = blk>>10;
  int row = b*LL + z*CH + l;
  float la = lag[row*NH+h], w1 = w1g[row*NH+h], w2 = w2g[row*NH+h];
  float a = la;
  #pragma unroll
  for (int o=1;o<64;o<<=1){ float t = __shfl_up(a,o); a += (l>=o) ? t : 0.f; }
  float Acm = __shfl(a, 31);
  float Alast = __shfl(a, 63);
  float eA = expf(a - Acm);
  float emA = expf(Acm - a);
  float rfac = expf(Alast - a);
  float rw1 = rfac*w1, rw2 = rfac*w2;
  float rw1p = __shfl_up(rw1, 1);
  float* cv = CV + (size_t)blk*CVW;
  cv[l] = eA;
  cv[64 + l] = emA*w1;          // G1[sp=l+1]
  cv[128 + l] = emA*w2;         // G2[sp=l]
  cv[192 + l] = (l>0 ? rw1p : 0.f) + rw2;   // vw[l]
  if (l == 63){ cv[192+64] = rw1; cdg[blk] = expf(Alast); }
  Acumg[(size_t)blk*CH + l] = a;
}

// ---------------- k_rope2 v5: fused Theta scan + rope -> Bn/Cn ----------------
// wave w computes theta columns j = w*8..w*8+7 via lane-l (row) shuffle scan into thS;
// then the v4 rotation-pair main loop reads thS instead of global Theta.
__global__ __launch_bounds__(256) void k_rope2(const float* __restrict__ Bnr,
                                               const float* __restrict__ Cnr,
                                               const float* __restrict__ pAux,
                                               const float* __restrict__ DTg,
                                               const float* __restrict__ Spart,
                                               const float* __restrict__ B_bias,
                                               const float* __restrict__ C_bias,
                                               u16* __restrict__ Bn, u16* __restrict__ Cn){
  __shared__ float thS[64][33];
  int blk = blockIdx.x; int h = blk&31, z=(blk>>5)&31, b=blk>>10;
  int l0 = z*CH; int tid = threadIdx.x;
  int l = tid & 63, w = tid >> 6;          // 4 waves
  {
    int row = b*LL + l0 + l;
    float dt = DTg[row*NH + h];
    int j0 = w*8;
    float4 a0 = *(const float4*)&pAux[(size_t)row*PAW + 352 + j0];
    float4 a1 = *(const float4*)&pAux[(size_t)row*PAW + 352 + j0 + 4];
    float v[8] = {dt*a0.x, dt*a0.y, dt*a0.z, dt*a0.w, dt*a1.x, dt*a1.y, dt*a1.z, dt*a1.w};
    #pragma unroll
    for (int e=0;e<8;e++){
      float s = v[e];
      #pragma unroll
      for (int o=1;o<64;o<<=1){ float t = __shfl_up(s,o); s += (l>=o) ? t : 0.f; }
      thS[l][j0+e] = s + Spart[(size_t)blk*NR + j0 + e];
    }
  }
  __syncthreads();
  const float* bb = B_bias + h*DS;
  const float* cb = C_bias + h*DS;
  #pragma unroll
  for (int it=0; it<8; it++){
    int idx = it*256 + tid;
    int r = idx>>5, j = idx&31;      // r = 0..63, j = 0..31
    int row = b*LL + l0 + r;
    const float* br = Bnr + (size_t)row*DS;
    const float* cr = Cnr + (size_t)row*DS;
    float th = thS[r][j];
    float cs = cosf(th), sn = sinf(th);
    float b0 = br[j]    + bb[j];
    float b1 = br[j+32] + bb[j+32];
    float b2 = br[j+64] + bb[j+64];
    float b3 = br[j+96] + bb[j+96];
    float c0 = cr[j]    + cb[j];
    float c1 = cr[j+32] + cb[j+32];
    float c2 = cr[j+64] + cb[j+64];
    float c3 = cr[j+96] + cb[j+96];
    float obA = b0*cs - b1*sn, obB = b0*sn + b1*cs;
    float ocA = c0*cs - c1*sn, ocB = c0*sn + c1*cs;
    u16* bnp = Bn + ((size_t)row*NH + h)*DS;
    u16* cnp = Cn + ((size_t)row*NH + h)*DS;
    bnp[j]    = f2bf(obA); bnp[j+32] = f2bf(obB);
    bnp[j+64] = f2bf(b2);  bnp[j+96] = f2bf(b3);
    cnp[j]    = f2bf(ocA); cnp[j+32] = f2bf(ocB);
    cnp[j+64] = f2bf(c2);  cnp[j+96] = f2bf(c3);
  }
}

// ---------------- k_chunk_a: 8-wave (512t) CB -> Mc + Bt(in-LDS transpose) -> Yintra, U ----------------
__global__ __launch_bounds__(512) void k_chunk_a(
    const u16* __restrict__ Xtg, const u16* __restrict__ Bn,
    const u16* __restrict__ Cn,
    const float* __restrict__ CV, const float* __restrict__ Dgl,
    u16* __restrict__ Yb, u16* __restrict__ Ugb){
  __shared__ u16 BsBT[65*128];     // Bs rows 0..64 (CB); rows 0..63 later overlaid by Bt [128][64] swz64
  __shared__ u16 CsMc[64*128];     // Cs swizzled -> Mc[64][72] overlay
  __shared__ u16 Xt64[64*64];      // X^T [p][k], k = s'-1
  __shared__ u16 Bp[128], Xp[64];
  __shared__ float cvS[260];
  __shared__ float mc0s[64];
  int blk = blockIdx.x;
  int h = blk&31, z=(blk>>5)&31, b=blk>>10;
  int l0 = z*CH;
  int tid = threadIdx.x; int l = tid&63, w = tid>>6;    // 8 waves
  int wA = w >> 1, wB = w & 1;
  size_t bh = (size_t)(b*NH + h);

  // ---- phase 0: staging ----
  if (tid < 128){
    u16 v = 0;
    if (z > 0) v = Bn[((size_t)(b*LL+l0-1)*NH + h)*DS + tid];
    BsBT[tid] = v; Bp[tid] = v;
  } else if (tid < 192){
    int p = tid - 128;
    u16 v = 0;
    if (z > 0) v = Xtg[(bh*HD + p)*LL + l0 - 1];
    Xp[p] = v;
  }
  if (tid < 257) cvS[tid] = CV[(size_t)blk*CVW + tid];
  #pragma unroll
  for (int cc=0; cc<2; cc++){
    int c = w*2 + cc;
    { int r = 1 + 4*c + (l>>4);
      gl_lds16(Bn + ((size_t)(b*LL+l0+r-1)*NH+h)*DS + (((l&15)^(r&7))<<3), &BsBT[(1+4*c)*128]); }
    { int r = 4*c + (l>>4);
      gl_lds16(Cn + ((size_t)(b*LL+l0+r)*NH+h)*DS + (((l&15)^(r&7))<<3), &CsMc[4*c*128]); }
  }
  {
    int uu = w*64 + l; int r = uu>>3, jl = uu&7, j = jl^(r&7);
    gl_lds16(Xtg + (bh*HD + r)*LL + l0 + j*8, &Xt64[w*512]);
  }
  __syncthreads();

  // ---- phase 1: CB GEMM over Bs rows 1..64 (2 tiles/wave); mc0 matvec ----
  const f32x4 vzero = {0.f,0.f,0.f,0.f};
  f32x4 acb[2];
  #pragma unroll
  for (int j=0;j<2;j++) acb[j] = vzero;
  #pragma unroll
  for (int ks=0; ks<4; ks++){
    s16x8 af = ldswz(CsMc, 16*wA + (l&15), ks*4 + (l>>4));
    #pragma unroll
    for (int j=0;j<2;j++){
      s16x8 bfr = ldswz(BsBT, 1 + 16*(wB*2+j) + (l&15), ks*4 + (l>>4));
      acb[j] = __builtin_amdgcn_mfma_f32_16x16x32_bf16(af, bfr, acb[j], 0,0,0);
    }
  }
  {
    int t = tid>>3, part = tid&7;
    float s = 0.f;
    #pragma unroll
    for (int uu=0; uu<2; uu++){
      int u = part*2 + uu;
      s16x8 cr = *(const s16x8*)&CsMc[t*128 + ((u^(t&7))<<3)];
      s16x8 br = *(const s16x8*)&BsBT[u<<3];   // row 0, identity swizzle
      #pragma unroll
      for (int e=0;e<8;e++) s += bf2f(cr[e])*bf2f(br[e]);
    }
    s += __shfl_xor(s, 1); s += __shfl_xor(s, 2); s += __shfl_xor(s, 4);
    if (part == 0) mc0s[t] = s * cvS[t] * cvS[128];   // CB[t][0]*eA[t]*G2[0]
  }
  __syncthreads();

  // ---- phase 2a: transpose-source reads (Bs rows 1..64 -> regs) + build Mc' ----
  u16 tv[16];
  #pragma unroll
  for (int it=0; it<16; it++){
    int i = it*512 + tid;         // 0..8191
    int n = i & 127, k = i >> 7;  // k = 0..63
    int r = k + 1;
    tv[it] = BsBT[r*128 + ((((n>>3) ^ (r&7))<<3) | (n&7))];
  }
  #pragma unroll
  for (int j=0;j<2;j++){
    #pragma unroll
    for (int q=0;q<4;q++){
      int t = 16*wA + (l>>4)*4 + q;
      int k = 16*(wB*2+j) + (l&15);
      int sp = k + 1;
      float g = 0.f;
      if (sp <= t+1) g += cvS[63+sp];
      if (sp <= t)   g += cvS[128+sp];
      g *= cvS[t];
      CsMc[t*72 + k] = f2bf(acb[j][q] * g);
    }
  }
  __syncthreads();

  // ---- phase 2b: Bt writes (overlay Bs rows 0..63): Bt[n][k] = Bs[k+1][n]*vw[k+1], swz64 layout ----
  #pragma unroll
  for (int it=0; it<16; it++){
    int i = it*512 + tid;
    int n = i & 127, k = i >> 7;
    float v = bf2f(tv[it]) * cvS[192 + k + 1];
    BsBT[n*64 + ((((k>>3) ^ (n&7))<<3) | (k&7))] = f2bf(v);
  }
  __syncthreads();

  // ---- phase 3: Yintra = Mc' @ Xt64^T + mc0 x Xp + D*x (2 tiles/wave); write Yb ----
  f32x4 ay[2];
  #pragma unroll
  for (int j=0;j<2;j++) ay[j] = vzero;
  #pragma unroll
  for (int ks=0; ks<2; ks++){
    s16x8 af = ld72(CsMc, 16*wA + (l&15), ks*32 + (l>>4)*8);
    #pragma unroll
    for (int j=0;j<2;j++){
      s16x8 bfr = ldswz64(Xt64, 16*(wB*2+j) + (l&15), ks*4 + (l>>4));
      ay[j] = __builtin_amdgcn_mfma_f32_16x16x32_bf16(af, bfr, ay[j], 0,0,0);
    }
  }
  {
    float Dh = Dgl[h];
    #pragma unroll
    for (int j=0;j<2;j++){
      #pragma unroll
      for (int q=0;q<4;q++){
        int t = 16*wA + (l>>4)*4 + q;
        int p = 16*(wB*2+j) + (l&15);
        float xval = ldswz64_s(Xt64, p, t);
        float yv = ay[j][q] + mc0s[t]*bf2f(Xp[p]) + Dh*xval;
        Yb[((size_t)(b*LL + l0 + t))*DI + h*HD + p] = f2bf(yv);
      }
    }
  }

  // ---- phase 4: U = Xt64 @ Bt^T (4 tiles/wave, + rank-1 sp=0 fixup); write Ugb ----
  f32x4 au[4];
  #pragma unroll
  for (int j=0;j<4;j++) au[j] = vzero;
  #pragma unroll
  for (int ks=0; ks<2; ks++){
    s16x8 af = ldswz64(Xt64, 16*wA + (l&15), ks*4 + (l>>4));
    #pragma unroll
    for (int j=0;j<4;j++){
      s16x8 bfr = ldswz64(BsBT, 16*(wB*4+j) + (l&15), ks*4 + (l>>4));
      au[j] = __builtin_amdgcn_mfma_f32_16x16x32_bf16(af, bfr, au[j], 0,0,0);
    }
  }
  {
    float vw0 = cvS[192];
    #pragma unroll
    for (int j=0;j<4;j++){
      #pragma unroll
      for (int q=0;q<4;q++){
        int p = 16*wA + (l>>4)*4 + q;
        int n = 16*(wB*4+j) + (l&15);
        float uv = au[j][q] + vw0*bf2f(Xp[p])*bf2f(Bp[n]);
        Ugb[(size_t)blk*(HD*DS) + p*DS + n] = f2bf(uv);
      }
    }
  }
}

// ---------------- inter-chunk state scan (bf16 in-place, vectorized s16x8) ----------------
__global__ __launch_bounds__(256) void k_scan(u16* __restrict__ Ugb, const float* __restrict__ cdg){
  int idx = blockIdx.x*256 + threadIdx.x;     // 65536 threads
  int pn8 = (idx & 1023)*8;
  int h  = (idx >> 10) & 31;
  int b  = idx >> 15;
  float hs[8];
  #pragma unroll
  for (int e=0;e<8;e++) hs[e] = 0.f;
  for (int z=0;z<NC;z++){
    size_t o = ((size_t)((b*NC+z)*NH) + h)*(HD*DS) + pn8;
    s16x8 v = *(s16x8*)&Ugb[o];
    float cd = cdg[(b*NC+z)*NH + h];
    s16x8 wv;
    #pragma unroll
    for (int e=0;e<8;e++){
      float tmp = bf2f((u16)v[e]);
      wv[e] = (short)f2bf(hs[e]);
      hs[e] = cd*hs[e] + tmp;
    }
    *(s16x8*)&Ugb[o] = wv;
  }
}

// ---------------- k_state: 8-wave (512t) Ystate MFMA + Y RMW ----------------
__global__ __launch_bounds__(512) void k_state(
    const u16* __restrict__ Cn, const u16* __restrict__ Ugb,
    const float* __restrict__ Acumg, u16* __restrict__ Yb){
  __shared__ u16 Cs[64*128];
  __shared__ u16 Sb[64*128];
  __shared__ float eAs[64];
  int blk = blockIdx.x;
  int h = blk & 31, z = (blk>>5)&31, b = blk>>10;
  int l0 = z*CH;
  int tid = threadIdx.x;
  int l = tid & 63, w = tid >> 6;   // 8 waves
  int wA = w >> 1, wB = w & 1;

  if (tid < 64) eAs[tid] = expf(Acumg[(size_t)blk*CH + tid]);
  #pragma unroll
  for (int cc=0; cc<2; cc++){
    int c = w*2 + cc;
    int r = 4*c + (l>>4);
    gl_lds16(Cn + ((size_t)(b*LL + l0 + r)*NH + h)*DS + (((l&15)^(r&7))<<3), &Cs[4*c*128]);
    gl_lds16(Ugb + (size_t)blk*(HD*DS) + (size_t)r*DS + (((l&15)^(r&7))<<3), &Sb[4*c*128]);
  }
  __syncthreads();

  f32x4 as[2];
  const f32x4 vzero = {0.f,0.f,0.f,0.f};
  #pragma unroll
  for (int j=0;j<2;j++) as[j] = vzero;
  #pragma unroll
  for (int ks=0; ks<4; ks++){
    s16x8 af = ldswz(Cs, 16*wA + (l&15), ks*4 + (l>>4));
    #pragma unroll
    for (int j=0;j<2;j++){
      s16x8 bfr = ldswz(Sb, 16*(wB*2+j) + (l&15), ks*4 + (l>>4));
      as[j] = __builtin_amdgcn_mfma_f32_16x16x32_bf16(af, bfr, as[j], 0,0,0);
    }
  }
  #pragma unroll
  for (int j=0;j<2;j++){
    #pragma unroll
    for (int q=0;q<4;q++){
      int t = 16*wA + (l>>4)*4 + q;
      int p = 16*(wB*2+j) + (l&15);
      size_t idx = ((size_t)(b*LL + l0 + t))*DI + h*HD + p;
      Yb[idx] = f2bf(bf2f(Yb[idx]) + eAs[t]*as[j][q]);
    }
  }
}

// ---------------- out-proj GEMM: 128x64 tile, 8-wave (512t), XCD swizzle ----------------
template<int N, int K>
__global__ __launch_bounds__(512) void k_mfma_nt64(const u16* __restrict__ A,
                                                   const u16* __restrict__ Bm,
                                                   float* __restrict__ C){
  __shared__ u16 lA[128*64];
  __shared__ u16 lB[64*64];
  int tid = threadIdx.x;
  int l = tid & 63, w = tid >> 6;          // 8 waves
  int nwg = gridDim.x*gridDim.y;           // 512, divisible by 8
  int flat = blockIdx.y*gridDim.x + blockIdx.x;
  int cpx = nwg >> 3;
  int swz = (flat & 7)*cpx + (flat >> 3);
  int bx = swz % gridDim.x, by = swz / gridDim.x;
  int bm = by*128, bn = bx*64;
  int wr = w >> 1, wc = w & 1;             // 4x2 wave grid: 32 rows x 32 cols per wave
  const f32x4 vzero = {0.f,0.f,0.f,0.f};
  f32x4 acc[2][2];
  #pragma unroll
  for (int i=0;i<2;i++)
    #pragma unroll
    for (int j=0;j<2;j++) acc[i][j] = vzero;

  for (int kt=0; kt<K; kt+=64){
    __syncthreads();
    // A: 16 units (s=0..15), 2 per wave; B: 8 units (s=0..7), 1 per wave
    #pragma unroll
    for (int cc=0; cc<2; cc++){
      int s = w*2 + cc;
      int uu = s*64 + l;
      int r = uu >> 3, jl = uu & 7;
      int j = jl ^ (r & 7);
      gl_lds16(A + (size_t)(bm+r)*K + kt + j*8, &lA[s*512]);
    }
    {
      int uu = w*64 + l;
      int r = uu >> 3, jl = uu & 7;
      int j = jl ^ (r & 7);
      gl_lds16(Bm + (size_t)(bn+r)*K + kt + j*8, &lB[w*512]);
    }
    __syncthreads();
    #pragma unroll
    for (int ks=0; ks<2; ks++){
      s16x8 af[2], bf[2];
      #pragma unroll
      for (int i=0;i<2;i++){
        int row = wr*32 + i*16 + (l&15);
        int j = ks*4 + (l>>4);
        af[i] = *(const s16x8*)&lA[row*64 + (j^(row&7))*8];
      }
      #pragma unroll
      for (int i=0;i<2;i++){
        int row = wc*32 + i*16 + (l&15);
        int j = ks*4 + (l>>4);
        bf[i] = *(const s16x8*)&lB[row*64 + (j^(row&7))*8];
      }
      #pragma unroll
      for (int i=0;i<2;i++)
        #pragma unroll
        for (int jj=0;jj<2;jj++)
          acc[i][jj] = __builtin_amdgcn_mfma_f32_16x16x32_bf16(af[i], bf[jj], acc[i][jj], 0,0,0);
    }
  }
  int col0 = bn + wc*32 + (l&15);
  int row0 = bm + wr*32 + (l>>4)*4;
  #pragma unroll
  for (int i=0;i<2;i++)
    #pragma unroll
    for (int jj=0;jj<2;jj++)
      #pragma unroll
      for (int q=0;q<4;q++)
        C[(size_t)(row0 + i*16 + q)*N + col0 + jj*16] = acc[i][jj][q];
}

// ---------------- workspace layout (bytes) ----------------
constexpr size_t OFF_PAUX  = 0;            // 6,291,456
constexpr size_t OFF_XTG   = 6291456;      // 16,777,216
constexpr size_t OFF_BNR   = 23068672;     // 2,097,152
constexpr size_t OFF_CNR   = 25165824;     // 2,097,152
constexpr size_t OFF_DT    = 27262976;     // 524,288
constexpr size_t OFF_LA    = 27787264;     // 524,288
constexpr size_t OFF_W1    = 28311552;     // 524,288
constexpr size_t OFF_W2    = 28835840;     // 524,288
constexpr size_t OFF_SPART = 29360128;     // 262,144
constexpr size_t OFF_CV    = 29622272;     // 2,162,688
constexpr size_t OFF_ACUM  = 31784960;     // 524,288
constexpr size_t OFF_CD    = 32309248;     // 8,192
constexpr size_t OFF_Y     = 32317440;     // 16,777,216 (ex-Theta region; Theta now in-kernel)
constexpr size_t OFF_BN    = 49094656;     // 33,554,432
constexpr size_t OFF_CN    = 82649088;     // 33,554,432
constexpr size_t OFF_R1    = 149757952;    // u_bf+Win_bf -> Ugb(33.55M)
constexpr size_t OFF_UBF   = OFF_R1;
constexpr size_t OFF_WINBF = OFF_R1 + 16777216;
constexpr size_t OFF_UGB   = OFF_R1;
constexpr size_t OFF_WOUTBF= 183312384;    // 4,194,304
// total = 187,506,688 bytes

extern "C" void kernel_launch(void* const* d_in, const int* in_sizes, int n_in,
                              void* d_out, int out_size, void* d_ws, size_t ws_size,
                              hipStream_t stream) {
  const float* u       = (const float*)d_in[0];
  const float* W_in    = (const float*)d_in[1];
  const float* dt_bias = (const float*)d_in[2];
  const float* B_bias  = (const float*)d_in[3];
  const float* C_bias  = (const float*)d_in[4];
  const float* Bnw     = (const float*)d_in[5];
  const float* Cnw     = (const float*)d_in[6];
  const float* Dg      = (const float*)d_in[7];
  const float* W_out   = (const float*)d_in[8];
  float* out = (float*)d_out;
  char* ws = (char*)d_ws;

  float* pAux  = (float*)(ws + OFF_PAUX);
  u16*   Xtg   = (u16*)  (ws + OFF_XTG);
  float* Bnr   = (float*)(ws + OFF_BNR);
  float* Cnr   = (float*)(ws + OFF_CNR);
  float* DTg   = (float*)(ws + OFF_DT);
  float* lag   = (float*)(ws + OFF_LA);
  float* w1g   = (float*)(ws + OFF_W1);
  float* w2g   = (float*)(ws + OFF_W2);
  float* Spart = (float*)(ws + OFF_SPART);
  float* CVp   = (float*)(ws + OFF_CV);
  float* Acumg = (float*)(ws + OFF_ACUM);
  float* cdg   = (float*)(ws + OFF_CD);
  u16*   Yb    = (u16*)  (ws + OFF_Y);
  u16*   Bn    = (u16*)  (ws + OFF_BN);
  u16*   Cn    = (u16*)  (ws + OFF_CN);
  u16*   u_bf  = (u16*)  (ws + OFF_UBF);
  u16*   Win_bf= (u16*)  (ws + OFF_WINBF);
  u16*   Ugb   = (u16*)  (ws + OFF_UGB);
  u16*   Wout_bf=(u16*)  (ws + OFF_WOUTBF);

  k_cast3<<<(CQ1+CQ2+CQ3+255)/256, 256, 0, stream>>>(u, W_in, W_out, u_bf, Win_bf, Wout_bf);
  k_gemm_in<<<dim3(DIP/128, NTOK/128), 512, 0, stream>>>(u_bf, Win_bf, pAux, Xtg);

  k_prep      <<<NTOK/2, 256, 0, stream>>>(pAux, dt_bias, Bnw, Cnw, Bnr, Cnr, DTg, lag, w1g, w2g);
  k_theta_part<<<(BB*NC*NH)/2, 64, 0, stream>>>(pAux, DTg, Spart);
  k_theta_scan<<<(BB*NH*NR)/256, 256, 0, stream>>>(Spart);
  k_acum      <<<(BB*NC*NH)/4, 256, 0, stream>>>(lag, w1g, w2g, CVp, Acumg, cdg);
  k_rope2     <<<BB*NC*NH, 256, 0, stream>>>(Bnr, Cnr, pAux, DTg, Spart, B_bias, C_bias, Bn, Cn);

  k_chunk_a<<<BB*NC*NH, 512, 0, stream>>>(Xtg, Bn, Cn, CVp, Dg, Yb, Ugb);
  k_scan   <<<(BB*NH*HD*DS)/(256*8), 256, 0, stream>>>(Ugb, cdg);
  k_state  <<<BB*NC*NH, 512, 0, stream>>>(Cn, Ugb, Acumg, Yb);

  k_mfma_nt64<DMODEL, DI><<<dim3(DMODEL/64, NTOK/128), 512, 0, stream>>>(Yb, Wout_bf, out);

  (void)in_sizes; (void)n_in; (void)out_size; (void)ws_size;
}

// Round 17
// 160.999 us; speedup vs baseline: 1.2131x; 1.0369x over previous
//
#include <hip/hip_runtime.h>
#include <hip/hip_bf16.h>
#include <math.h>

typedef unsigned short u16;
typedef __attribute__((ext_vector_type(8))) short s16x8;
typedef __attribute__((ext_vector_type(4))) float f32x4;

#define BB 2
#define LL 2048
#define DMODEL 1024
#define DI 2048
#define NH 32
#define HD 64
#define DS 128
#define NR 32
#define CH 64
#define NC 32
#define DIP 2432
#define NTOK (BB*LL)
#define PAW 384   // projAux width: cols 2048..2431 of proj
#define CVW 264   // per-chunk factor-table stride (floats)

__device__ __forceinline__ float bf2f(u16 u){ union{unsigned i; float f;} c; c.i=((unsigned)u)<<16; return c.f; }
__device__ __forceinline__ u16 f2bf(float f){ __hip_bfloat16 h=__float2bfloat16(f); return *reinterpret_cast<u16*>(&h); }
__device__ __forceinline__ float softplusf(float x){ return fmaxf(x,0.f) + log1pf(expf(-fabsf(x))); }

__device__ __forceinline__ void gl_lds16(const void* g, void* l){
  __builtin_amdgcn_global_load_lds((const __attribute__((address_space(1))) void*)g,
                                   (__attribute__((address_space(3))) void*)l, 16, 0, 0);
}

// swizzled [*][128] bf16 row (256B): 16B unit u at slot u^(r&7)
__device__ __forceinline__ s16x8 ldswz(const u16* base, int r, int kunit){
  return *(const s16x8*)&base[r*128 + ((kunit ^ (r&7))<<3)];
}
// swizzled [*][64] bf16 row (128B): unit u (0..7) at slot u^(r&7)
__device__ __forceinline__ s16x8 ldswz64(const u16* base, int r, int kunit){
  return *(const s16x8*)&base[r*64 + ((kunit ^ (r&7))<<3)];
}
__device__ __forceinline__ float ldswz64_s(const u16* base, int r, int n){
  return bf2f(base[r*64 + (((n>>3) ^ (r&7))<<3) + (n&7)]);
}
// plain stride-72 bf16 rows
__device__ __forceinline__ s16x8 ld72(const u16* base, int r, int kelem){
  return *(const s16x8*)&base[r*72 + kelem];
}

// ---------------- merged cast fp32 -> bf16 (u, W_in, W_out in one launch) ----------------
#define CQ1 ((NTOK*DMODEL)/4)
#define CQ2 ((DIP*DMODEL)/4)
#define CQ3 ((DMODEL*DI)/4)
__global__ __launch_bounds__(256) void k_cast3(const float* __restrict__ u, const float* __restrict__ Wi,
                                               const float* __restrict__ Wo,
                                               u16* __restrict__ ub, u16* __restrict__ wib,
                                               u16* __restrict__ wob){
  int i = blockIdx.x*256 + threadIdx.x;
  const float* src; u16* dst; int q;
  if (i < CQ1){ src = u; dst = ub; q = i; }
  else if (i < CQ1+CQ2){ src = Wi; dst = wib; q = i - CQ1; }
  else if (i < CQ1+CQ2+CQ3){ src = Wo; dst = wob; q = i - CQ1 - CQ2; }
  else return;
  float4 v = *(const float4*)&src[(size_t)q*4];
  ushort4 o; o.x=f2bf(v.x); o.y=f2bf(v.y); o.z=f2bf(v.z); o.w=f2bf(v.w);
  *(ushort4*)&dst[(size_t)q*4] = o;
}

// ---------------- in-proj GEMM, 8-wave (512t) 128x128 tile, split epilogue, XCD swizzle ----------------
__global__ __launch_bounds__(512) void k_gemm_in(const u16* __restrict__ A,
                                                 const u16* __restrict__ Bm,
                                                 float* __restrict__ pAux,
                                                 u16* __restrict__ Xtg){
  __shared__ u16 lA[128*64];
  __shared__ u16 lB[128*64];
  int tid = threadIdx.x;
  int l = tid & 63, w = tid >> 6;          // 8 waves
  int nwg = gridDim.x*gridDim.y;
  int flat = blockIdx.y*gridDim.x + blockIdx.x;
  int cpx = nwg >> 3;
  int swz = (flat & 7)*cpx + (flat >> 3);
  int bx = swz % gridDim.x, by = swz / gridDim.x;
  int bm = by*128, bn = bx*128;
  int wr = w >> 2, wc = w & 3;             // 2x4 wave grid: 64 rows x 32 cols per wave
  const f32x4 vzero = {0.f,0.f,0.f,0.f};
  f32x4 acc[4][2];
  #pragma unroll
  for (int i=0;i<4;i++)
    #pragma unroll
    for (int j=0;j<2;j++) acc[i][j] = vzero;

  for (int kt=0; kt<DMODEL; kt+=64){
    __syncthreads();
    #pragma unroll
    for (int cc=0; cc<2; cc++){
      int s = w*2 + cc;
      int uu = s*64 + l;
      int r = uu >> 3, jl = uu & 7;
      int j = jl ^ (r & 7);
      gl_lds16(A  + (size_t)(bm+r)*DMODEL + kt + j*8, &lA[s*512]);
      gl_lds16(Bm + (size_t)(bn+r)*DMODEL + kt + j*8, &lB[s*512]);
    }
    __syncthreads();
    #pragma unroll
    for (int ks=0; ks<2; ks++){
      s16x8 af[4], bf[2];
      #pragma unroll
      for (int i=0;i<4;i++){
        int row = wr*64 + i*16 + (l&15);
        int j = ks*4 + (l>>4);
        af[i] = *(const s16x8*)&lA[row*64 + (j^(row&7))*8];
      }
      #pragma unroll
      for (int i=0;i<2;i++){
        int row = wc*32 + i*16 + (l&15);
        int j = ks*4 + (l>>4);
        bf[i] = *(const s16x8*)&lB[row*64 + (j^(row&7))*8];
      }
      #pragma unroll
      for (int i=0;i<4;i++)
        #pragma unroll
        for (int jj=0;jj<2;jj++)
          acc[i][jj] = __builtin_amdgcn_mfma_f32_16x16x32_bf16(af[i], bf[jj], acc[i][jj], 0,0,0);
    }
  }
  int col0 = bn + wc*32 + (l&15);
  int row0 = bm + wr*64 + (l>>4)*4;
  if (bn < DI){
    int h = (bn + wc*32) >> 6;
    int pbase = (wc & 1)*32 + (l&15);
    int b = bm >> 11;
    #pragma unroll
    for (int i=0;i<4;i++){
      int lbase = (bm & (LL-1)) + wr*64 + (l>>4)*4 + i*16;
      #pragma unroll
      for (int jj=0;jj<2;jj++){
        int p = pbase + jj*16;
        ushort4 o;
        o.x = f2bf(acc[i][jj][0]); o.y = f2bf(acc[i][jj][1]);
        o.z = f2bf(acc[i][jj][2]); o.w = f2bf(acc[i][jj][3]);
        *(ushort4*)&Xtg[((size_t)(b*NH + h)*HD + p)*LL + lbase] = o;
      }
    }
  } else {
    #pragma unroll
    for (int i=0;i<4;i++)
      #pragma unroll
      for (int jj=0;jj<2;jj++)
        #pragma unroll
        for (int q=0;q<4;q++)
          pAux[(size_t)(row0 + i*16 + q)*PAW + col0 + jj*16 - DI] = acc[i][jj][q];
  }
}

// ---------------- per-token prep (2 rows/block) ----------------
__global__ __launch_bounds__(256) void k_prep(const float* __restrict__ pAux,
                                              const float* __restrict__ dt_bias,
                                              const float* __restrict__ Bnw,
                                              const float* __restrict__ Cnw,
                                              float* __restrict__ Bnr, float* __restrict__ Cnr,
                                              float* __restrict__ DTg, float* __restrict__ lag,
                                              float* __restrict__ w1g, float* __restrict__ w2g){
  int tid = threadIdx.x;
  int r = tid >> 7, t = tid & 127;
  int row = blockIdx.x*2 + r;
  const float* pr = pAux + (size_t)row*PAW;
  float bv = pr[t], cv = pr[128+t];
  float sb = bv*bv, sc = cv*cv;
  for (int o=32;o;o>>=1){ sb += __shfl_down(sb,o); sc += __shfl_down(sc,o); }
  __shared__ float red[8];
  if ((tid&63)==0){ red[(tid>>6)*2]=sb; red[(tid>>6)*2+1]=sc; }
  __syncthreads();
  float ssb = red[r*4]+red[r*4+2], ssc = red[r*4+1]+red[r*4+3];
  float rb = rsqrtf(ssb/DS + 1e-5f), rc = rsqrtf(ssc/DS + 1e-5f);
  Bnr[(size_t)row*DS+t] = bv*rb*Bnw[t];
  Cnr[(size_t)row*DS+t] = cv*rc*Cnw[t];
  if (t < NH){
    int h = t;
    float Av = -softplusf(pr[288+h]); Av = fminf(Av, -1e-4f);
    float DT = softplusf(pr[256+h] + dt_bias[h]);
    float la = Av*DT;
    float lam = 1.f/(1.f+expf(-pr[320+h]));
    DTg[row*NH+h] = DT;
    lag[row*NH+h] = la;
    w1g[row*NH+h] = DT*lam;
    w2g[row*NH+h] = DT*(1.f-lam)*expf(la);
  }
}

__global__ void k_theta_scan(float* __restrict__ Spart){
  int idx = blockIdx.x*blockDim.x + threadIdx.x;
  int j = idx % NR; int h = (idx/NR)%NH; int b = idx/(NR*NH);
  float acc = 0.f;
  for (int z=0;z<NC;z++){
    size_t o = (size_t)((b*NC+z)*NH + h)*NR + j;
    float t = Spart[o]; Spart[o] = acc; acc += t;
  }
}

// ---------------- k_acum v2: per-chunk scan factors + theta chunk sums (absorbs theta_part) ----------------
__global__ __launch_bounds__(256) void k_acum(const float* __restrict__ lag,
                                              const float* __restrict__ w1g,
                                              const float* __restrict__ w2g,
                                              const float* __restrict__ pAux,
                                              const float* __restrict__ DTg,
                                              float* __restrict__ CV,
                                              float* __restrict__ Acumg,
                                              float* __restrict__ cdg,
                                              float* __restrict__ Spart){
  __shared__ float thS[4][64][33];   // 33.8 KB
  int wv = threadIdx.x >> 6;
  int blk = blockIdx.x*4 + wv;
  int l = threadIdx.x & 63;
  int h = blk & 31, z = (blk>>5)&31, b = blk>>10;
  int row = b*LL + z*CH + l;
  float la = lag[row*NH+h], w1 = w1g[row*NH+h], w2 = w2g[row*NH+h];
  float a = la;
  #pragma unroll
  for (int o=1;o<64;o<<=1){ float t = __shfl_up(a,o); a += (l>=o) ? t : 0.f; }
  float Acm = __shfl(a, 31);
  float Alast = __shfl(a, 63);
  float eA = expf(a - Acm);
  float emA = expf(Acm - a);
  float rfac = expf(Alast - a);
  float rw1 = rfac*w1, rw2 = rfac*w2;
  float rw1p = __shfl_up(rw1, 1);
  float* cv = CV + (size_t)blk*CVW;
  cv[l] = eA;
  cv[64 + l] = emA*w1;          // G1[sp=l+1]
  cv[128 + l] = emA*w2;         // G2[sp=l]
  cv[192 + l] = (l>0 ? rw1p : 0.f) + rw2;   // vw[l]
  if (l == 63){ cv[192+64] = rw1; cdg[blk] = expf(Alast); }
  Acumg[(size_t)blk*CH + l] = a;

  // theta chunk sums: thS[wv][row][j] = DT[row]*ang[row][j]; reduce over rows -> Spart[blk][j]
  {
    float dt = DTg[row*NH + h];
    const float* ap = pAux + (size_t)row*PAW + 352;
    #pragma unroll
    for (int e4=0; e4<8; e4++){
      float4 a4 = *(const float4*)&ap[e4*4];
      thS[wv][l][e4*4+0] = dt*a4.x;
      thS[wv][l][e4*4+1] = dt*a4.y;
      thS[wv][l][e4*4+2] = dt*a4.z;
      thS[wv][l][e4*4+3] = dt*a4.w;
    }
  }
  __syncthreads();
  {
    int j = l & 31, r0 = (l>>5)*32;
    float s = 0.f;
    #pragma unroll
    for (int r=0;r<32;r++) s += thS[wv][r0+r][j];
    s += __shfl_xor(s, 32);
    if (l < 32) Spart[(size_t)blk*NR + j] = s;
  }
}

// ---------------- k_rope2 v5: fused Theta scan + rope -> Bn/Cn (+XCD chunked swizzle) ----------------
__global__ __launch_bounds__(256) void k_rope2(const float* __restrict__ Bnr,
                                               const float* __restrict__ Cnr,
                                               const float* __restrict__ pAux,
                                               const float* __restrict__ DTg,
                                               const float* __restrict__ Spart,
                                               const float* __restrict__ B_bias,
                                               const float* __restrict__ C_bias,
                                               u16* __restrict__ Bn, u16* __restrict__ Cn){
  __shared__ float thS[64][33];
  int cpx = gridDim.x >> 3;
  int blk = (blockIdx.x & 7)*cpx + (blockIdx.x >> 3);
  int h = blk&31, z=(blk>>5)&31, b=blk>>10;
  int l0 = z*CH; int tid = threadIdx.x;
  int l = tid & 63, w = tid >> 6;          // 4 waves
  {
    int row = b*LL + l0 + l;
    float dt = DTg[row*NH + h];
    int j0 = w*8;
    float4 a0 = *(const float4*)&pAux[(size_t)row*PAW + 352 + j0];
    float4 a1 = *(const float4*)&pAux[(size_t)row*PAW + 352 + j0 + 4];
    float v[8] = {dt*a0.x, dt*a0.y, dt*a0.z, dt*a0.w, dt*a1.x, dt*a1.y, dt*a1.z, dt*a1.w};
    #pragma unroll
    for (int e=0;e<8;e++){
      float s = v[e];
      #pragma unroll
      for (int o=1;o<64;o<<=1){ float t = __shfl_up(s,o); s += (l>=o) ? t : 0.f; }
      thS[l][j0+e] = s + Spart[(size_t)blk*NR + j0 + e];
    }
  }
  __syncthreads();
  const float* bb = B_bias + h*DS;
  const float* cb = C_bias + h*DS;
  #pragma unroll
  for (int it=0; it<8; it++){
    int idx = it*256 + tid;
    int r = idx>>5, j = idx&31;      // r = 0..63, j = 0..31
    int row = b*LL + l0 + r;
    const float* br = Bnr + (size_t)row*DS;
    const float* cr = Cnr + (size_t)row*DS;
    float th = thS[r][j];
    float cs = cosf(th), sn = sinf(th);
    float b0 = br[j]    + bb[j];
    float b1 = br[j+32] + bb[j+32];
    float b2 = br[j+64] + bb[j+64];
    float b3 = br[j+96] + bb[j+96];
    float c0 = cr[j]    + cb[j];
    float c1 = cr[j+32] + cb[j+32];
    float c2 = cr[j+64] + cb[j+64];
    float c3 = cr[j+96] + cb[j+96];
    float obA = b0*cs - b1*sn, obB = b0*sn + b1*cs;
    float ocA = c0*cs - c1*sn, ocB = c0*sn + c1*cs;
    u16* bnp = Bn + ((size_t)row*NH + h)*DS;
    u16* cnp = Cn + ((size_t)row*NH + h)*DS;
    bnp[j]    = f2bf(obA); bnp[j+32] = f2bf(obB);
    bnp[j+64] = f2bf(b2);  bnp[j+96] = f2bf(b3);
    cnp[j]    = f2bf(ocA); cnp[j+32] = f2bf(ocB);
    cnp[j+64] = f2bf(c2);  cnp[j+96] = f2bf(c3);
  }
}

// ---------------- k_chunk_a: 8-wave (512t) CB -> Mc + Bt(in-LDS transpose) -> Yintra, U (+XCD swizzle) ----------------
__global__ __launch_bounds__(512) void k_chunk_a(
    const u16* __restrict__ Xtg, const u16* __restrict__ Bn,
    const u16* __restrict__ Cn,
    const float* __restrict__ CV, const float* __restrict__ Dgl,
    u16* __restrict__ Yb, u16* __restrict__ Ugb){
  __shared__ u16 BsBT[65*128];     // Bs rows 0..64 (CB); rows 0..63 later overlaid by Bt [128][64] swz64
  __shared__ u16 CsMc[64*128];     // Cs swizzled -> Mc[64][72] overlay
  __shared__ u16 Xt64[64*64];      // X^T [p][k], k = s'-1
  __shared__ u16 Bp[128], Xp[64];
  __shared__ float cvS[260];
  __shared__ float mc0s[64];
  int cpx = gridDim.x >> 3;
  int blk = (blockIdx.x & 7)*cpx + (blockIdx.x >> 3);
  int h = blk&31, z=(blk>>5)&31, b=blk>>10;
  int l0 = z*CH;
  int tid = threadIdx.x; int l = tid&63, w = tid>>6;    // 8 waves
  int wA = w >> 1, wB = w & 1;
  size_t bh = (size_t)(b*NH + h);

  // ---- phase 0: staging ----
  if (tid < 128){
    u16 v = 0;
    if (z > 0) v = Bn[((size_t)(b*LL+l0-1)*NH + h)*DS + tid];
    BsBT[tid] = v; Bp[tid] = v;
  } else if (tid < 192){
    int p = tid - 128;
    u16 v = 0;
    if (z > 0) v = Xtg[(bh*HD + p)*LL + l0 - 1];
    Xp[p] = v;
  }
  if (tid < 257) cvS[tid] = CV[(size_t)blk*CVW + tid];
  #pragma unroll
  for (int cc=0; cc<2; cc++){
    int c = w*2 + cc;
    { int r = 1 + 4*c + (l>>4);
      gl_lds16(Bn + ((size_t)(b*LL+l0+r-1)*NH+h)*DS + (((l&15)^(r&7))<<3), &BsBT[(1+4*c)*128]); }
    { int r = 4*c + (l>>4);
      gl_lds16(Cn + ((size_t)(b*LL+l0+r)*NH+h)*DS + (((l&15)^(r&7))<<3), &CsMc[4*c*128]); }
  }
  {
    int uu = w*64 + l; int r = uu>>3, jl = uu&7, j = jl^(r&7);
    gl_lds16(Xtg + (bh*HD + r)*LL + l0 + j*8, &Xt64[w*512]);
  }
  __syncthreads();

  // ---- phase 1: CB GEMM over Bs rows 1..64 (2 tiles/wave); mc0 matvec ----
  const f32x4 vzero = {0.f,0.f,0.f,0.f};
  f32x4 acb[2];
  #pragma unroll
  for (int j=0;j<2;j++) acb[j] = vzero;
  #pragma unroll
  for (int ks=0; ks<4; ks++){
    s16x8 af = ldswz(CsMc, 16*wA + (l&15), ks*4 + (l>>4));
    #pragma unroll
    for (int j=0;j<2;j++){
      s16x8 bfr = ldswz(BsBT, 1 + 16*(wB*2+j) + (l&15), ks*4 + (l>>4));
      acb[j] = __builtin_amdgcn_mfma_f32_16x16x32_bf16(af, bfr, acb[j], 0,0,0);
    }
  }
  {
    int t = tid>>3, part = tid&7;
    float s = 0.f;
    #pragma unroll
    for (int uu=0; uu<2; uu++){
      int u = part*2 + uu;
      s16x8 cr = *(const s16x8*)&CsMc[t*128 + ((u^(t&7))<<3)];
      s16x8 br = *(const s16x8*)&BsBT[u<<3];   // row 0, identity swizzle
      #pragma unroll
      for (int e=0;e<8;e++) s += bf2f(cr[e])*bf2f(br[e]);
    }
    s += __shfl_xor(s, 1); s += __shfl_xor(s, 2); s += __shfl_xor(s, 4);
    if (part == 0) mc0s[t] = s * cvS[t] * cvS[128];   // CB[t][0]*eA[t]*G2[0]
  }
  __syncthreads();

  // ---- phase 2a: transpose-source reads (Bs rows 1..64 -> regs) + build Mc' ----
  u16 tv[16];
  #pragma unroll
  for (int it=0; it<16; it++){
    int i = it*512 + tid;         // 0..8191
    int n = i & 127, k = i >> 7;  // k = 0..63
    int r = k + 1;
    tv[it] = BsBT[r*128 + ((((n>>3) ^ (r&7))<<3) | (n&7))];
  }
  #pragma unroll
  for (int j=0;j<2;j++){
    #pragma unroll
    for (int q=0;q<4;q++){
      int t = 16*wA + (l>>4)*4 + q;
      int k = 16*(wB*2+j) + (l&15);
      int sp = k + 1;
      float g = 0.f;
      if (sp <= t+1) g += cvS[63+sp];
      if (sp <= t)   g += cvS[128+sp];
      g *= cvS[t];
      CsMc[t*72 + k] = f2bf(acb[j][q] * g);
    }
  }
  __syncthreads();

  // ---- phase 2b: Bt writes (overlay Bs rows 0..63): Bt[n][k] = Bs[k+1][n]*vw[k+1], swz64 layout ----
  #pragma unroll
  for (int it=0; it<16; it++){
    int i = it*512 + tid;
    int n = i & 127, k = i >> 7;
    float v = bf2f(tv[it]) * cvS[192 + k + 1];
    BsBT[n*64 + ((((k>>3) ^ (n&7))<<3) | (k&7))] = f2bf(v);
  }
  __syncthreads();

  // ---- phase 3: Yintra = Mc' @ Xt64^T + mc0 x Xp + D*x (2 tiles/wave); write Yb ----
  f32x4 ay[2];
  #pragma unroll
  for (int j=0;j<2;j++) ay[j] = vzero;
  #pragma unroll
  for (int ks=0; ks<2; ks++){
    s16x8 af = ld72(CsMc, 16*wA + (l&15), ks*32 + (l>>4)*8);
    #pragma unroll
    for (int j=0;j<2;j++){
      s16x8 bfr = ldswz64(Xt64, 16*(wB*2+j) + (l&15), ks*4 + (l>>4));
      ay[j] = __builtin_amdgcn_mfma_f32_16x16x32_bf16(af, bfr, ay[j], 0,0,0);
    }
  }
  {
    float Dh = Dgl[h];
    #pragma unroll
    for (int j=0;j<2;j++){
      #pragma unroll
      for (int q=0;q<4;q++){
        int t = 16*wA + (l>>4)*4 + q;
        int p = 16*(wB*2+j) + (l&15);
        float xval = ldswz64_s(Xt64, p, t);
        float yv = ay[j][q] + mc0s[t]*bf2f(Xp[p]) + Dh*xval;
        Yb[((size_t)(b*LL + l0 + t))*DI + h*HD + p] = f2bf(yv);
      }
    }
  }

  // ---- phase 4: U = Xt64 @ Bt^T (4 tiles/wave, + rank-1 sp=0 fixup); write Ugb ----
  f32x4 au[4];
  #pragma unroll
  for (int j=0;j<4;j++) au[j] = vzero;
  #pragma unroll
  for (int ks=0; ks<2; ks++){
    s16x8 af = ldswz64(Xt64, 16*wA + (l&15), ks*4 + (l>>4));
    #pragma unroll
    for (int j=0;j<4;j++){
      s16x8 bfr = ldswz64(BsBT, 16*(wB*4+j) + (l&15), ks*4 + (l>>4));
      au[j] = __builtin_amdgcn_mfma_f32_16x16x32_bf16(af, bfr, au[j], 0,0,0);
    }
  }
  {
    float vw0 = cvS[192];
    #pragma unroll
    for (int j=0;j<4;j++){
      #pragma unroll
      for (int q=0;q<4;q++){
        int p = 16*wA + (l>>4)*4 + q;
        int n = 16*(wB*4+j) + (l&15);
        float uv = au[j][q] + vw0*bf2f(Xp[p])*bf2f(Bp[n]);
        Ugb[(size_t)blk*(HD*DS) + p*DS + n] = f2bf(uv);
      }
    }
  }
}

// ---------------- inter-chunk state scan (bf16 in-place, vectorized s16x8, 128t blocks) ----------------
__global__ __launch_bounds__(128) void k_scan(u16* __restrict__ Ugb, const float* __restrict__ cdg){
  int idx = blockIdx.x*128 + threadIdx.x;     // 65536 threads
  int pn8 = (idx & 1023)*8;
  int h  = (idx >> 10) & 31;
  int b  = idx >> 15;
  float hs[8];
  #pragma unroll
  for (int e=0;e<8;e++) hs[e] = 0.f;
  for (int z=0;z<NC;z++){
    size_t o = ((size_t)((b*NC+z)*NH) + h)*(HD*DS) + pn8;
    s16x8 v = *(s16x8*)&Ugb[o];
    float cd = cdg[(b*NC+z)*NH + h];
    s16x8 wv;
    #pragma unroll
    for (int e=0;e<8;e++){
      float tmp = bf2f((u16)v[e]);
      wv[e] = (short)f2bf(hs[e]);
      hs[e] = cd*hs[e] + tmp;
    }
    *(s16x8*)&Ugb[o] = wv;
  }
}

// ---------------- k_state: 8-wave (512t) Ystate MFMA + Y RMW (+XCD swizzle) ----------------
__global__ __launch_bounds__(512) void k_state(
    const u16* __restrict__ Cn, const u16* __restrict__ Ugb,
    const float* __restrict__ Acumg, u16* __restrict__ Yb){
  __shared__ u16 Cs[64*128];
  __shared__ u16 Sb[64*128];
  __shared__ float eAs[64];
  int cpx = gridDim.x >> 3;
  int blk = (blockIdx.x & 7)*cpx + (blockIdx.x >> 3);
  int h = blk & 31, z = (blk>>5)&31, b = blk>>10;
  int l0 = z*CH;
  int tid = threadIdx.x;
  int l = tid & 63, w = tid >> 6;   // 8 waves
  int wA = w >> 1, wB = w & 1;

  if (tid < 64) eAs[tid] = expf(Acumg[(size_t)blk*CH + tid]);
  #pragma unroll
  for (int cc=0; cc<2; cc++){
    int c = w*2 + cc;
    int r = 4*c + (l>>4);
    gl_lds16(Cn + ((size_t)(b*LL + l0 + r)*NH + h)*DS + (((l&15)^(r&7))<<3), &Cs[4*c*128]);
    gl_lds16(Ugb + (size_t)blk*(HD*DS) + (size_t)r*DS + (((l&15)^(r&7))<<3), &Sb[4*c*128]);
  }
  __syncthreads();

  f32x4 as[2];
  const f32x4 vzero = {0.f,0.f,0.f,0.f};
  #pragma unroll
  for (int j=0;j<2;j++) as[j] = vzero;
  #pragma unroll
  for (int ks=0; ks<4; ks++){
    s16x8 af = ldswz(Cs, 16*wA + (l&15), ks*4 + (l>>4));
    #pragma unroll
    for (int j=0;j<2;j++){
      s16x8 bfr = ldswz(Sb, 16*(wB*2+j) + (l&15), ks*4 + (l>>4));
      as[j] = __builtin_amdgcn_mfma_f32_16x16x32_bf16(af, bfr, as[j], 0,0,0);
    }
  }
  #pragma unroll
  for (int j=0;j<2;j++){
    #pragma unroll
    for (int q=0;q<4;q++){
      int t = 16*wA + (l>>4)*4 + q;
      int p = 16*(wB*2+j) + (l&15);
      size_t idx = ((size_t)(b*LL + l0 + t))*DI + h*HD + p;
      Yb[idx] = f2bf(bf2f(Yb[idx]) + eAs[t]*as[j][q]);
    }
  }
}

// ---------------- out-proj GEMM: 128x64 tile, 8-wave (512t), XCD swizzle ----------------
template<int N, int K>
__global__ __launch_bounds__(512) void k_mfma_nt64(const u16* __restrict__ A,
                                                   const u16* __restrict__ Bm,
                                                   float* __restrict__ C){
  __shared__ u16 lA[128*64];
  __shared__ u16 lB[64*64];
  int tid = threadIdx.x;
  int l = tid & 63, w = tid >> 6;          // 8 waves
  int nwg = gridDim.x*gridDim.y;           // 512, divisible by 8
  int flat = blockIdx.y*gridDim.x + blockIdx.x;
  int cpx = nwg >> 3;
  int swz = (flat & 7)*cpx + (flat >> 3);
  int bx = swz % gridDim.x, by = swz / gridDim.x;
  int bm = by*128, bn = bx*64;
  int wr = w >> 1, wc = w & 1;             // 4x2 wave grid: 32 rows x 32 cols per wave
  const f32x4 vzero = {0.f,0.f,0.f,0.f};
  f32x4 acc[2][2];
  #pragma unroll
  for (int i=0;i<2;i++)
    #pragma unroll
    for (int j=0;j<2;j++) acc[i][j] = vzero;

  for (int kt=0; kt<K; kt+=64){
    __syncthreads();
    #pragma unroll
    for (int cc=0; cc<2; cc++){
      int s = w*2 + cc;
      int uu = s*64 + l;
      int r = uu >> 3, jl = uu & 7;
      int j = jl ^ (r & 7);
      gl_lds16(A + (size_t)(bm+r)*K + kt + j*8, &lA[s*512]);
    }
    {
      int uu = w*64 + l;
      int r = uu >> 3, jl = uu & 7;
      int j = jl ^ (r & 7);
      gl_lds16(Bm + (size_t)(bn+r)*K + kt + j*8, &lB[w*512]);
    }
    __syncthreads();
    #pragma unroll
    for (int ks=0; ks<2; ks++){
      s16x8 af[2], bf[2];
      #pragma unroll
      for (int i=0;i<2;i++){
        int row = wr*32 + i*16 + (l&15);
        int j = ks*4 + (l>>4);
        af[i] = *(const s16x8*)&lA[row*64 + (j^(row&7))*8];
      }
      #pragma unroll
      for (int i=0;i<2;i++){
        int row = wc*32 + i*16 + (l&15);
        int j = ks*4 + (l>>4);
        bf[i] = *(const s16x8*)&lB[row*64 + (j^(row&7))*8];
      }
      #pragma unroll
      for (int i=0;i<2;i++)
        #pragma unroll
        for (int jj=0;jj<2;jj++)
          acc[i][jj] = __builtin_amdgcn_mfma_f32_16x16x32_bf16(af[i], bf[jj], acc[i][jj], 0,0,0);
    }
  }
  int col0 = bn + wc*32 + (l&15);
  int row0 = bm + wr*32 + (l>>4)*4;
  #pragma unroll
  for (int i=0;i<2;i++)
    #pragma unroll
    for (int jj=0;jj<2;jj++)
      #pragma unroll
      for (int q=0;q<4;q++)
        C[(size_t)(row0 + i*16 + q)*N + col0 + jj*16] = acc[i][jj][q];
}

// ---------------- workspace layout (bytes) ----------------
constexpr size_t OFF_PAUX  = 0;            // 6,291,456
constexpr size_t OFF_XTG   = 6291456;      // 16,777,216
constexpr size_t OFF_BNR   = 23068672;     // 2,097,152
constexpr size_t OFF_CNR   = 25165824;     // 2,097,152
constexpr size_t OFF_DT    = 27262976;     // 524,288
constexpr size_t OFF_LA    = 27787264;     // 524,288
constexpr size_t OFF_W1    = 28311552;     // 524,288
constexpr size_t OFF_W2    = 28835840;     // 524,288
constexpr size_t OFF_SPART = 29360128;     // 262,144
constexpr size_t OFF_CV    = 29622272;     // 2,162,688
constexpr size_t OFF_ACUM  = 31784960;     // 524,288
constexpr size_t OFF_CD    = 32309248;     // 8,192
constexpr size_t OFF_Y     = 32317440;     // 16,777,216
constexpr size_t OFF_BN    = 49094656;     // 33,554,432
constexpr size_t OFF_CN    = 82649088;     // 33,554,432
constexpr size_t OFF_R1    = 149757952;    // u_bf+Win_bf -> Ugb(33.55M)
constexpr size_t OFF_UBF   = OFF_R1;
constexpr size_t OFF_WINBF = OFF_R1 + 16777216;
constexpr size_t OFF_UGB   = OFF_R1;
constexpr size_t OFF_WOUTBF= 183312384;    // 4,194,304
// total = 187,506,688 bytes

extern "C" void kernel_launch(void* const* d_in, const int* in_sizes, int n_in,
                              void* d_out, int out_size, void* d_ws, size_t ws_size,
                              hipStream_t stream) {
  const float* u       = (const float*)d_in[0];
  const float* W_in    = (const float*)d_in[1];
  const float* dt_bias = (const float*)d_in[2];
  const float* B_bias  = (const float*)d_in[3];
  const float* C_bias  = (const float*)d_in[4];
  const float* Bnw     = (const float*)d_in[5];
  const float* Cnw     = (const float*)d_in[6];
  const float* Dg      = (const float*)d_in[7];
  const float* W_out   = (const float*)d_in[8];
  float* out = (float*)d_out;
  char* ws = (char*)d_ws;

  float* pAux  = (float*)(ws + OFF_PAUX);
  u16*   Xtg   = (u16*)  (ws + OFF_XTG);
  float* Bnr   = (float*)(ws + OFF_BNR);
  float* Cnr   = (float*)(ws + OFF_CNR);
  float* DTg   = (float*)(ws + OFF_DT);
  float* lag   = (float*)(ws + OFF_LA);
  float* w1g   = (float*)(ws + OFF_W1);
  float* w2g   = (float*)(ws + OFF_W2);
  float* Spart = (float*)(ws + OFF_SPART);
  float* CVp   = (float*)(ws + OFF_CV);
  float* Acumg = (float*)(ws + OFF_ACUM);
  float* cdg   = (float*)(ws + OFF_CD);
  u16*   Yb    = (u16*)  (ws + OFF_Y);
  u16*   Bn    = (u16*)  (ws + OFF_BN);
  u16*   Cn    = (u16*)  (ws + OFF_CN);
  u16*   u_bf  = (u16*)  (ws + OFF_UBF);
  u16*   Win_bf= (u16*)  (ws + OFF_WINBF);
  u16*   Ugb   = (u16*)  (ws + OFF_UGB);
  u16*   Wout_bf=(u16*)  (ws + OFF_WOUTBF);

  k_cast3<<<(CQ1+CQ2+CQ3+255)/256, 256, 0, stream>>>(u, W_in, W_out, u_bf, Win_bf, Wout_bf);
  k_gemm_in<<<dim3(DIP/128, NTOK/128), 512, 0, stream>>>(u_bf, Win_bf, pAux, Xtg);

  k_prep      <<<NTOK/2, 256, 0, stream>>>(pAux, dt_bias, Bnw, Cnw, Bnr, Cnr, DTg, lag, w1g, w2g);
  k_acum      <<<(BB*NC*NH)/4, 256, 0, stream>>>(lag, w1g, w2g, pAux, DTg, CVp, Acumg, cdg, Spart);
  k_theta_scan<<<(BB*NH*NR)/256, 256, 0, stream>>>(Spart);
  k_rope2     <<<BB*NC*NH, 256, 0, stream>>>(Bnr, Cnr, pAux, DTg, Spart, B_bias, C_bias, Bn, Cn);

  k_chunk_a<<<BB*NC*NH, 512, 0, stream>>>(Xtg, Bn, Cn, CVp, Dg, Yb, Ugb);
  k_scan   <<<(BB*NH*HD*DS)/(128*8), 128, 0, stream>>>(Ugb, cdg);
  k_state  <<<BB*NC*NH, 512, 0, stream>>>(Cn, Ugb, Acumg, Yb);

  k_mfma_nt64<DMODEL, DI><<<dim3(DMODEL/64, NTOK/128), 512, 0, stream>>>(Yb, Wout_bf, out);

  (void)in_sizes; (void)n_in; (void)out_size; (void)ws_size;
}